// Round 8
// baseline (839.398 us; speedup 1.0000x reference)
//
#include <hip/hip_runtime.h>
#include <hip/hip_bf16.h>

using bf16 = __hip_bfloat16;
using s16x4 = __attribute__((ext_vector_type(4))) short;
using s16x8 = __attribute__((ext_vector_type(8))) short;
using f32x4 = __attribute__((ext_vector_type(4))) float;

#define DI __device__ __forceinline__
#define WAITVM(n) asm volatile("s_waitcnt vmcnt(" #n ")" ::: "memory")

DI float b2f(short s) { union { unsigned u; float f; } z; z.u = ((unsigned)(unsigned short)s) << 16; return z.f; }
DI short f2b(float f) { bf16 t = __float2bfloat16(f); return *(short*)&t; }

// fast gelu: tanh form, |err| ~1e-3 absolute, far under threshold
DI float gelu_f(float x) {
    const float t = 0.7978845608f * x * (1.f + 0.044715f * x * x);
    const float e = __expf(2.f * t);
    const float th = 1.f - 2.f / (e + 1.f);
    return 0.5f * x * (1.f + th);
}

DI void ld8(const bf16* p, float* f) {
    s16x8 x = *(const s16x8*)(const void*)p;
#pragma unroll
    for (int c = 0; c < 8; c++) f[c] = b2f(x[c]);
}
DI void ld8(const float* p, float* f) {
    float4 a = *(const float4*)p, b = *(const float4*)(p + 4);
    f[0]=a.x; f[1]=a.y; f[2]=a.z; f[3]=a.w; f[4]=b.x; f[5]=b.y; f[6]=b.z; f[7]=b.w;
}

typedef const __attribute__((address_space(1))) void* gp_t;
typedef __attribute__((address_space(3))) void* lp_t;
DI void gload_lds16(const void* g, void* l) {
    __builtin_amdgcn_global_load_lds((gp_t)g, (lp_t)l, 16, 0, 0);
}

// ---------------- diagnostic ----------------
__global__ void diag_k(float* out, float v) { out[0] = v; }

// ---------------- fp32 -> bf16 weight conversion (8/thread) ----------------
__global__ void f2bf_k(const float* __restrict__ in, bf16* __restrict__ out, int n) {
    int i = (blockIdx.x * 256 + threadIdx.x) * 8;
    if (i >= n) return;
    float f[8];
    ld8(in + i, f);
    s16x8 o;
#pragma unroll
    for (int c = 0; c < 8; c++) o[c] = f2b(f[c]);
    *(s16x8*)(void*)(out + i) = o;
}

// ---------------- depthwise 3x3 conv v4 ----------------
DI void tap10(const float* r, float w0, float w1, float w2, float* acc) {
#pragma unroll
    for (int i = 0; i < 8; i++)
        acc[i] += w0 * r[i] + w1 * r[i + 1] + w2 * r[i + 2];
}

template <typename TI, typename TO, bool RESID, int CPL>
__global__ __launch_bounds__(256) void conv4_k(
    const TI* in, long rs, long coff,
    const float* __restrict__ w, const float* __restrict__ bias,
    TO* out, long ors, int gshift)
{
    constexpr int CH = 64 * CPL;
    constexpr int ECNT = CH / 8;
    __shared__ float buf[2][CH][33];
    const int t = threadIdx.x;
    const int band = blockIdx.x & 3;
    const int cg = (blockIdx.x >> 2) & ((1 << gshift) - 1);
    const int img = blockIdx.x >> (2 + gshift);
    const int y0 = band * 8;

    const int spx = t >> 3;
    const int sce = (t & 7) * ECNT;
    const TI* gsrc = in + ((long)img << 10) * rs + coff + (long)cg * CH + sce;

    const int c = t & 63;
    const int xb = (t >> 6) * 8;

    float wv9[9][CPL], bw[CPL];
#pragma unroll
    for (int p = 0; p < CPL; p++) {
        const int gch = cg * CH + c * CPL + p;
#pragma unroll
        for (int j = 0; j < 9; j++) wv9[j][p] = w[gch * 9 + j];
        bw[p] = bias[gch];
    }

    auto stage = [&](int row) {
        float f[ECNT];
        ld8(gsrc + (long)(row * 32 + spx) * rs, f);
        if constexpr (ECNT == 16) ld8(gsrc + (long)(row * 32 + spx) * rs + 8, f + 8);
        float* d = &buf[row & 1][0][0];
#pragma unroll
        for (int k = 0; k < ECNT; k++) {
            const int ch = sce + k;
            const int rr = (CPL == 2) ? ((ch & 1) * 64 + (ch >> 1)) : ch;
            d[rr * 33 + spx] = f[k];
        }
    };
    auto slice = [&](int row, float r[CPL][10]) {
#pragma unroll
        for (int p = 0; p < CPL; p++) {
            const float* s = &buf[row & 1][c + p * 64][0];
            r[p][0] = (xb == 0) ? 0.f : s[xb - 1];
#pragma unroll
            for (int i = 0; i < 8; i++) r[p][1 + i] = s[xb + i];
            r[p][9] = (xb + 8 >= 32) ? 0.f : s[xb + 8];
        }
    };
    auto zero = [&](float r[CPL][10]) {
#pragma unroll
        for (int p = 0; p < CPL; p++)
#pragma unroll
            for (int i = 0; i < 10; i++) r[p][i] = 0.f;
    };

    float r0[CPL][10], r1[CPL][10], r2[CPL][10];
    if (y0 > 0) stage(y0 - 1);
    __syncthreads();
    if (y0 > 0) slice(y0 - 1, r0); else zero(r0);
    stage(y0);
    __syncthreads();
    slice(y0, r1);

    for (int y = y0; y < y0 + 8; ++y) {
        const int yn = y + 1;
        if (yn <= 31) stage(yn);
        __syncthreads();
        if (yn <= 31) slice(yn, r2); else zero(r2);
        float acc[CPL][8];
#pragma unroll
        for (int p = 0; p < CPL; p++) {
#pragma unroll
            for (int i = 0; i < 8; i++) acc[p][i] = bw[p];
            tap10(r0[p], wv9[0][p], wv9[1][p], wv9[2][p], acc[p]);
            tap10(r1[p], wv9[3][p], wv9[4][p], wv9[5][p], acc[p]);
            tap10(r2[p], wv9[6][p], wv9[7][p], wv9[8][p], acc[p]);
            if (RESID) {
#pragma unroll
                for (int i = 0; i < 8; i++) acc[p][i] += r1[p][i + 1];
            }
        }
        TO* o = out + ((long)(img * 1024 + y * 32 + xb)) * ors + (long)cg * CH + c * CPL;
#pragma unroll
        for (int i = 0; i < 8; i++) {
            if constexpr (CPL == 2 && sizeof(TO) == 2) {
                const unsigned u = (unsigned)(unsigned short)f2b(acc[0][i]) |
                                   ((unsigned)(unsigned short)f2b(acc[1][i]) << 16);
                *(unsigned*)(void*)(o + (long)i * ors) = u;
            } else {
                o[(long)i * ors] = (TO)acc[0][i];
            }
        }
#pragma unroll
        for (int p = 0; p < CPL; p++)
#pragma unroll
            for (int i = 0; i < 10; i++) { r0[p][i] = r1[p][i]; r1[p][i] = r2[p][i]; }
    }
}

// ---------------- LayerNorm over C=512, fp32 in -> bf16 out ----------------
// 256 threads = 4 waves, 1 row per wave.
__global__ __launch_bounds__(256) void ln_k(const float* __restrict__ x,
                                            const float* __restrict__ w,
                                            const float* __restrict__ bp,
                                            bf16* __restrict__ out)
{
    const size_t row = blockIdx.x * 4 + (threadIdx.x >> 6);
    const int t = threadIdx.x & 63;
    const float* xr = x + row * 512;
    alignas(16) float v[8];
    *(float4*)&v[0] = *(const float4*)(xr + t * 8);
    *(float4*)&v[4] = *(const float4*)(xr + t * 8 + 4);
    float s = 0.f;
#pragma unroll
    for (int j = 0; j < 8; j++) s += v[j];
#pragma unroll
    for (int mm = 32; mm; mm >>= 1) s += __shfl_xor(s, mm);
    const float mu = s * (1.f / 512.f);
    float q = 0.f;
#pragma unroll
    for (int j = 0; j < 8; j++) { v[j] -= mu; q += v[j] * v[j]; }
#pragma unroll
    for (int mm = 32; mm; mm >>= 1) q += __shfl_xor(q, mm);
    const float rstd = rsqrtf(q * (1.f / 512.f) + 1e-6f);
    alignas(16) float wv[8], bv[8];
    *(float4*)&wv[0] = *(const float4*)(w + t * 8);
    *(float4*)&wv[4] = *(const float4*)(w + t * 8 + 4);
    *(float4*)&bv[0] = *(const float4*)(bp + t * 8);
    *(float4*)&bv[4] = *(const float4*)(bp + t * 8 + 4);
    alignas(16) bf16 o[8];
#pragma unroll
    for (int j = 0; j < 8; j++) o[j] = __float2bfloat16(v[j] * rstd * wv[j] + bv[j]);
    *(uint4*)(out + row * 512 + t * 8) = *(const uint4*)o;
}

// ---------------- bf16 MFMA GEMM: C[M,N] = A[M,K] * Bw[N,K]^T ----------------
// 4-buffer LDS pipeline, 3 tiles staged ahead, counted vmcnt with descending
// tail (8/4/0 for BN=128; 6/3/0 for BN=64). One s_barrier per K-step.
// XOR swizzle on global source + ds_read side; LDS dest linear.
template <int EPI, int BN>
__global__ __launch_bounds__(256) void gemm_k(
    const bf16* __restrict__ A, const bf16* __restrict__ Bw,
    const float* __restrict__ bias, const float* resid,
    bf16* __restrict__ outb, float* outf,
    int M, int Nn, int K)
{
    constexpr int WC = (BN == 128) ? 2 : 1;
    constexpr int WR = 4 / WC;
    constexpr int MI = 128 / (16 * WR);
    constexpr int NJ = BN / (16 * WC);
    __shared__ __align__(16) short As[4][128 * 32];
    __shared__ __align__(16) short Bs[4][BN * 32];
    const int t = threadIdx.x;
    const int m0 = blockIdx.x * 128;
    const int n0 = blockIdx.y * BN;
    const int lane = t & 63;
    const int wv = t >> 6;
    const int wr = (WC == 2) ? (wv >> 1) : wv;
    const int wc = (WC == 2) ? (wv & 1) : 0;
    const int lr = lane & 15, lg = lane >> 4;

    f32x4 acc[MI][NJ] = {};

    const int sk = 8 * ((lane & 3) ^ ((lane >> 3) & 3));
    const int arow = wv * 32 + (lane >> 2);
    const bf16* Ag0 = A + (size_t)(m0 + arow) * K + sk;
    const bf16* Ag1 = Ag0 + (size_t)16 * K;
    const int brow = (BN == 128) ? arow : (wv * 16 + (lane >> 2));
    const bf16* Bg0 = Bw + (size_t)(n0 + brow) * K + sk;
    const bf16* Bg1 = Bg0 + (size_t)16 * K;

    const int rsw = (lr >> 1) & 3;

    auto STAGE = [&](int buf, int k0) {
        gload_lds16(Ag0 + k0, (char*)&As[buf][0] + wv * 2048);
        gload_lds16(Ag1 + k0, (char*)&As[buf][0] + wv * 2048 + 1024);
        if constexpr (BN == 128) {
            gload_lds16(Bg0 + k0, (char*)&Bs[buf][0] + wv * 2048);
            gload_lds16(Bg1 + k0, (char*)&Bs[buf][0] + wv * 2048 + 1024);
        } else {
            gload_lds16(Bg0 + k0, (char*)&Bs[buf][0] + wv * 1024);
        }
    };

    auto COMPUTE = [&](int buf) {
        s16x8 aF[MI], bF[NJ];
#pragma unroll
        for (int i = 0; i < MI; i++) {
            const int R = wr * (128 / WR) + i * 16 + lr;
            aF[i] = *(const s16x8*)(&As[buf][0] + R * 32 + ((lg ^ rsw) << 3));
        }
#pragma unroll
        for (int j = 0; j < NJ; j++) {
            const int R = wc * 64 + j * 16 + lr;
            bF[j] = *(const s16x8*)(&Bs[buf][0] + R * 32 + ((lg ^ rsw) << 3));
        }
#pragma unroll
        for (int i = 0; i < MI; i++)
#pragma unroll
            for (int j = 0; j < NJ; j++)
                acc[i][j] = __builtin_amdgcn_mfma_f32_16x16x32_bf16(aF[i], bF[j], acc[i][j], 0, 0, 0);
    };

    const int KT = K / 32;   // always >= 16 here
    STAGE(0, 0);
    STAGE(1, 32);
    STAGE(2, 64);
    for (int kt = 0; kt < KT - 2; ++kt) {
        if constexpr (BN == 128) WAITVM(8); else WAITVM(6);
        __builtin_amdgcn_s_barrier();
        if (kt + 3 < KT) STAGE((kt + 3) & 3, (kt + 3) * 32);
        COMPUTE(kt & 3);
    }
    if constexpr (BN == 128) WAITVM(4); else WAITVM(3);
    __builtin_amdgcn_s_barrier();
    COMPUTE((KT - 2) & 3);
    WAITVM(0);
    __builtin_amdgcn_s_barrier();
    COMPUTE((KT - 1) & 3);

#pragma unroll
    for (int i = 0; i < MI; i++) {
#pragma unroll
        for (int j = 0; j < NJ; j++) {
            const int col = n0 + wc * 64 + j * 16 + lr;
            const float bcol = (EPI > 0) ? bias[col] : 0.f;
#pragma unroll
            for (int r = 0; r < 4; r++) {
                const int row = m0 + wr * (128 / WR) + i * 16 + lg * 4 + r;
                float v = acc[i][j][r] + bcol;
                const size_t idx = (size_t)row * Nn + col;
                if (EPI == 0) outb[idx] = __float2bfloat16(v);
                else if (EPI == 1) outb[idx] = __float2bfloat16(gelu_f(v));
                else outf[idx] = v + resid[idx];
            }
        }
    }
}

// ---------------- ktv partials: no max-subtraction softmax -------------------
__global__ __launch_bounds__(256) void ktv_part_k(const bf16* __restrict__ qkv,
                                                  float* __restrict__ ktvp,
                                                  float* __restrict__ csp)
{
    const int b = blockIdx.x >> 5;
    const int hh = (blockIdx.x >> 2) & 7;
    const int sp = blockIdx.x & 3;
    const bf16* kb = qkv + (size_t)b * 1024 * 1536 + 512 + hh * 64;
    const bf16* vb = kb + 512;
    __shared__ __align__(16) bf16 Ks[16 * 64];
    __shared__ __align__(16) bf16 Vs[16 * 64];
    const int t = threadIdx.x;
    const int kk = t & 63, vg = t >> 6;
    float acc[16] = {};
    float psum = 0.f;
    const int sr = t >> 4, sc = (t & 15) * 4;
    for (int n0 = sp * 256; n0 < sp * 256 + 256; n0 += 16) {
        __syncthreads();
        *(s16x4*)(void*)(Ks + sr * 64 + sc) = *(const s16x4*)(const void*)(kb + (size_t)(n0 + sr) * 1536 + sc);
        *(s16x4*)(void*)(Vs + sr * 64 + sc) = *(const s16x4*)(const void*)(vb + (size_t)(n0 + sr) * 1536 + sc);
        __syncthreads();
#pragma unroll
        for (int i = 0; i < 16; i++) {
            const float p = __expf(b2f(*(const short*)(const void*)(Ks + i * 64 + kk)));
            psum += p;
            float vv[16];
            ld8(Vs + i * 64 + vg * 16, vv);
            ld8(Vs + i * 64 + vg * 16 + 8, vv + 8);
#pragma unroll
            for (int j = 0; j < 16; j++) acc[j] += p * vv[j];
        }
    }
    const int bh4 = (b * 8 + hh) * 4 + sp;
    float* o = ktvp + (size_t)bh4 * 4096 + kk * 64 + vg * 16;
#pragma unroll
    for (int j = 0; j < 16; j++) o[j] = acc[j];
    if (vg == 0) csp[bh4 * 64 + kk] = psum;
}

// ---------------- ktv reduce ----------
__global__ __launch_bounds__(256) void ktv_red_k(const float* __restrict__ ktvp,
                                                 const float* __restrict__ csp,
                                                 float* __restrict__ ktv)
{
    const int bh = blockIdx.x;
    const int t = threadIdx.x;
#pragma unroll
    for (int i = 0; i < 16; i++) {
        const int e = t + 256 * i;
        const int kk = e >> 6;
        float cs = 0.f, v = 0.f;
#pragma unroll
        for (int sp = 0; sp < 4; sp++) {
            cs += csp[(bh * 4 + sp) * 64 + kk];
            v += ktvp[(size_t)(bh * 4 + sp) * 4096 + e];
        }
        ktv[(size_t)bh * 4096 + e] = v * (0.125f / cs);
    }
}

// ---------------- xs += q @ ktv_scaled + q * vconv  (in place) --------------
__global__ __launch_bounds__(256) void attnout_k(
    float* xs, const bf16* __restrict__ qkv,
    const float* __restrict__ ktv, const bf16* __restrict__ vc)
{
    const int nc = blockIdx.x & 31, hh = (blockIdx.x >> 5) & 7, b = blockIdx.x >> 8;
    __shared__ __align__(16) float kt[64 * 64];
    __shared__ __align__(16) bf16 qs[32 * 64];
    const int t = threadIdx.x;
    const float4* ksrc = (const float4*)(ktv + (size_t)(b * 8 + hh) * 4096);
    for (int u = t; u < 1024; u += 256) ((float4*)kt)[u] = ksrc[u];
    const int n0 = nc * 32;
    {
        const int r = t >> 3, cc = (t & 7) * 8;
        *(uint4*)(qs + r * 64 + cc) =
            *(const uint4*)(qkv + ((size_t)b * 1024 + n0 + r) * 1536 + hh * 64 + cc);
    }
    __syncthreads();
    const int dv = t & 63, rb = (t >> 6) * 8;
    for (int r = rb; r < rb + 8; r++) {
        float fa = 0.f;
#pragma unroll
        for (int kk = 0; kk < 64; kk++)
            fa += b2f(*(const short*)(const void*)(qs + r * 64 + kk)) * kt[kk * 64 + dv];
        const size_t idx = ((size_t)b * 1024 + n0 + r) * 512 + hh * 64 + dv;
        const float qv = b2f(*(const short*)(const void*)(qs + r * 64 + dv));
        xs[idx] = xs[idx] + fa + qv * __bfloat162float(vc[idx]);
    }
}

// ---------------- workspace layout (bytes) ----------------------------------
static constexpr int    BC       = 8;
static constexpr size_t OFF_WQ   = 0;
static constexpr size_t OFF_W1   = 1572864;
static constexpr size_t OFF_W2   = 3670016;
static constexpr size_t OFF_CUR  = 5767168;
static constexpr size_t OFF_QKV  = 14155776;
static constexpr size_t OFF_KTVP = 39321600;
static constexpr size_t OFF_CSP  = 43515904;
static constexpr size_t OFF_KTV  = 43581440;
static constexpr size_t OFF_VC   = 44630016;   // ends 53018624
static constexpr size_t OFF_HG   = 14155776;   // over dead qkv region
static constexpr size_t OFF_H2S  = 47710208;   // small mode (32MB over dead vc tail)
static constexpr size_t WS_NEED  = 81264640;   // ~77.5MB
static constexpr size_t OFF_H2B  = 53018624;   // big mode: 64MB pair buffer
static constexpr size_t WS_BIG   = 120127488;  // ~114.6MB

extern "C" void kernel_launch(void* const* d_in, const int* in_sizes, int n_in,
                              void* d_out, int out_size, void* d_ws, size_t ws_size,
                              hipStream_t stream)
{
    const float* x     = (const float*)d_in[0];
    const float* cpe_w = (const float*)d_in[1];
    const float* cpe_b = (const float*)d_in[2];
    const float* ln1_w = (const float*)d_in[3];
    const float* ln1_b = (const float*)d_in[4];
    const float* qkv_w = (const float*)d_in[5];
    const float* crpe_w= (const float*)d_in[6];
    const float* crpe_b= (const float*)d_in[7];
    const float* ln2_w = (const float*)d_in[8];
    const float* ln2_b = (const float*)d_in[9];
    const float* fc1_w = (const float*)d_in[10];
    const float* fc1_b = (const float*)d_in[11];
    const float* dw_w  = (const float*)d_in[12];
    const float* dw_b  = (const float*)d_in[13];
    const float* fc2_w = (const float*)d_in[14];
    const float* fc2_b = (const float*)d_in[15];
    float* spine = (float*)d_out;
    char* ws = (char*)d_ws;

    if (ws_size < WS_NEED) {
        diag_k<<<1, 1, 0, stream>>>(spine, (float)ws_size);
        return;
    }
    const bool big = ws_size >= WS_BIG;

    bf16*  wq   = (bf16*)(ws + OFF_WQ);
    bf16*  w1   = (bf16*)(ws + OFF_W1);
    bf16*  w2   = (bf16*)(ws + OFF_W2);
    bf16*  cur  = (bf16*)(ws + OFF_CUR);
    bf16*  qkv  = (bf16*)(ws + OFF_QKV);
    float* ktvp = (float*)(ws + OFF_KTVP);
    float* csp  = (float*)(ws + OFF_CSP);
    float* ktv  = (float*)(ws + OFF_KTV);
    bf16*  vc   = (bf16*)(ws + OFF_VC);
    bf16*  hg   = (bf16*)(ws + OFF_HG);
    bf16*  h2   = (bf16*)(ws + (big ? OFF_H2B : OFF_H2S));

    // weights -> bf16
    f2bf_k<<<(1536 * 512 / 8 + 255) / 256, 256, 0, stream>>>(qkv_w, wq, 1536 * 512);
    f2bf_k<<<(2048 * 512 / 8 + 255) / 256, 256, 0, stream>>>(fc1_w, w1, 2048 * 512);
    f2bf_k<<<(2048 * 512 / 8 + 255) / 256, 256, 0, stream>>>(fc2_w, w2, 2048 * 512);

    // CPE (full batch, fp32, 64-ch groups): spine = x + dwconv(x) + cpe_b
    conv4_k<float, float, true, 1><<<32 * 8 * 4, 256, 0, stream>>>(x, 512, 0, cpe_w, cpe_b, spine, 512, 3);

    const int Mc = BC * 1024;  // 8192 rows per chunk
    for (int pair = 0; pair < 2; pair++) {
        for (int ci = 0; ci < 2; ci++) {
            const int c = pair * 2 + ci;
            float* xs = spine + (size_t)c * Mc * 512;
            bf16* h2c = big ? (h2 + (size_t)ci * Mc * 2048) : h2;
            ln_k<<<Mc / 4, 256, 0, stream>>>(xs, ln1_w, ln1_b, cur);
            gemm_k<0, 128><<<dim3(Mc / 128, 12), 256, 0, stream>>>(cur, wq, nullptr, nullptr, qkv, nullptr, Mc, 1536, 512);
            ktv_part_k<<<BC * 8 * 4, 256, 0, stream>>>(qkv, ktvp, csp);
            ktv_red_k<<<BC * 8, 256, 0, stream>>>(ktvp, csp, ktv);
            conv4_k<bf16, bf16, false, 2><<<BC * 4 * 4, 256, 0, stream>>>(qkv, 1536, 1024, crpe_w, crpe_b, vc, 512, 2);
            attnout_k<<<BC * 8 * 32, 256, 0, stream>>>(xs, qkv, ktv, vc);
            ln_k<<<Mc / 4, 256, 0, stream>>>(xs, ln2_w, ln2_b, cur);
            gemm_k<1, 128><<<dim3(Mc / 128, 16), 256, 0, stream>>>(cur, w1, fc1_b, nullptr, hg, nullptr, Mc, 2048, 512);
            conv4_k<bf16, bf16, true, 2><<<BC * 16 * 4, 256, 0, stream>>>(hg, 2048, 0, dw_w, dw_b, h2c, 2048, 4);
            if (!big) {
                gemm_k<2, 64><<<dim3(Mc / 128, 8), 256, 0, stream>>>(h2, w2, fc2_b, xs, nullptr, xs, Mc, 512, 2048);
            }
        }
        if (big) {
            float* xsp = spine + (size_t)pair * 2 * Mc * 512;
            gemm_k<2, 128><<<dim3(2 * Mc / 128, 4), 256, 0, stream>>>(h2, w2, fc2_b, xsp, nullptr, xsp, 2 * Mc, 512, 2048);
        }
    }
}

// Round 9
// 837.968 us; speedup vs baseline: 1.0017x; 1.0017x over previous
//
#include <hip/hip_runtime.h>
#include <hip/hip_bf16.h>

using bf16 = __hip_bfloat16;
using s16x4 = __attribute__((ext_vector_type(4))) short;
using s16x8 = __attribute__((ext_vector_type(8))) short;
using f32x4 = __attribute__((ext_vector_type(4))) float;

#define DI __device__ __forceinline__
#define WAITVM0 asm volatile("s_waitcnt vmcnt(0)" ::: "memory")

DI float b2f(short s) { union { unsigned u; float f; } z; z.u = ((unsigned)(unsigned short)s) << 16; return z.f; }
DI short f2b(float f) { bf16 t = __float2bfloat16(f); return *(short*)&t; }

// fast gelu: tanh form, |err| ~1e-3 absolute, far under threshold
DI float gelu_f(float x) {
    const float t = 0.7978845608f * x * (1.f + 0.044715f * x * x);
    const float e = __expf(2.f * t);
    const float th = 1.f - 2.f / (e + 1.f);
    return 0.5f * x * (1.f + th);
}

DI void ld8(const bf16* p, float* f) {
    s16x8 x = *(const s16x8*)(const void*)p;
#pragma unroll
    for (int c = 0; c < 8; c++) f[c] = b2f(x[c]);
}
DI void ld8(const float* p, float* f) {
    float4 a = *(const float4*)p, b = *(const float4*)(p + 4);
    f[0]=a.x; f[1]=a.y; f[2]=a.z; f[3]=a.w; f[4]=b.x; f[5]=b.y; f[6]=b.z; f[7]=b.w;
}

typedef const __attribute__((address_space(1))) void* gp_t;
typedef __attribute__((address_space(3))) void* lp_t;
DI void gload_lds16(const void* g, void* l) {
    __builtin_amdgcn_global_load_lds((gp_t)g, (lp_t)l, 16, 0, 0);
}

// ---------------- diagnostic ----------------
__global__ void diag_k(float* out, float v) { out[0] = v; }

// ---------------- fp32 -> bf16 weight conversion (8/thread) ----------------
__global__ void f2bf_k(const float* __restrict__ in, bf16* __restrict__ out, int n) {
    int i = (blockIdx.x * 256 + threadIdx.x) * 8;
    if (i >= n) return;
    float f[8];
    ld8(in + i, f);
    s16x8 o;
#pragma unroll
    for (int c = 0; c < 8; c++) o[c] = f2b(f[c]);
    *(s16x8*)(void*)(out + i) = o;
}

// ---------------- depthwise 3x3 conv v4 ----------------
DI void tap10(const float* r, float w0, float w1, float w2, float* acc) {
#pragma unroll
    for (int i = 0; i < 8; i++)
        acc[i] += w0 * r[i] + w1 * r[i + 1] + w2 * r[i + 2];
}

template <typename TI, typename TO, bool RESID, int CPL>
__global__ __launch_bounds__(256) void conv4_k(
    const TI* in, long rs, long coff,
    const float* __restrict__ w, const float* __restrict__ bias,
    TO* out, long ors, int gshift)
{
    constexpr int CH = 64 * CPL;
    constexpr int ECNT = CH / 8;
    __shared__ float buf[2][CH][33];
    const int t = threadIdx.x;
    const int band = blockIdx.x & 3;
    const int cg = (blockIdx.x >> 2) & ((1 << gshift) - 1);
    const int img = blockIdx.x >> (2 + gshift);
    const int y0 = band * 8;

    const int spx = t >> 3;
    const int sce = (t & 7) * ECNT;
    const TI* gsrc = in + ((long)img << 10) * rs + coff + (long)cg * CH + sce;

    const int c = t & 63;
    const int xb = (t >> 6) * 8;

    float wv9[9][CPL], bw[CPL];
#pragma unroll
    for (int p = 0; p < CPL; p++) {
        const int gch = cg * CH + c * CPL + p;
#pragma unroll
        for (int j = 0; j < 9; j++) wv9[j][p] = w[gch * 9 + j];
        bw[p] = bias[gch];
    }

    auto stage = [&](int row) {
        float f[ECNT];
        ld8(gsrc + (long)(row * 32 + spx) * rs, f);
        if constexpr (ECNT == 16) ld8(gsrc + (long)(row * 32 + spx) * rs + 8, f + 8);
        float* d = &buf[row & 1][0][0];
#pragma unroll
        for (int k = 0; k < ECNT; k++) {
            const int ch = sce + k;
            const int rr = (CPL == 2) ? ((ch & 1) * 64 + (ch >> 1)) : ch;
            d[rr * 33 + spx] = f[k];
        }
    };
    auto slice = [&](int row, float r[CPL][10]) {
#pragma unroll
        for (int p = 0; p < CPL; p++) {
            const float* s = &buf[row & 1][c + p * 64][0];
            r[p][0] = (xb == 0) ? 0.f : s[xb - 1];
#pragma unroll
            for (int i = 0; i < 8; i++) r[p][1 + i] = s[xb + i];
            r[p][9] = (xb + 8 >= 32) ? 0.f : s[xb + 8];
        }
    };
    auto zero = [&](float r[CPL][10]) {
#pragma unroll
        for (int p = 0; p < CPL; p++)
#pragma unroll
            for (int i = 0; i < 10; i++) r[p][i] = 0.f;
    };

    float r0[CPL][10], r1[CPL][10], r2[CPL][10];
    if (y0 > 0) stage(y0 - 1);
    __syncthreads();
    if (y0 > 0) slice(y0 - 1, r0); else zero(r0);
    stage(y0);
    __syncthreads();
    slice(y0, r1);

    for (int y = y0; y < y0 + 8; ++y) {
        const int yn = y + 1;
        if (yn <= 31) stage(yn);
        __syncthreads();
        if (yn <= 31) slice(yn, r2); else zero(r2);
        float acc[CPL][8];
#pragma unroll
        for (int p = 0; p < CPL; p++) {
#pragma unroll
            for (int i = 0; i < 8; i++) acc[p][i] = bw[p];
            tap10(r0[p], wv9[0][p], wv9[1][p], wv9[2][p], acc[p]);
            tap10(r1[p], wv9[3][p], wv9[4][p], wv9[5][p], acc[p]);
            tap10(r2[p], wv9[6][p], wv9[7][p], wv9[8][p], acc[p]);
            if (RESID) {
#pragma unroll
                for (int i = 0; i < 8; i++) acc[p][i] += r1[p][i + 1];
            }
        }
        TO* o = out + ((long)(img * 1024 + y * 32 + xb)) * ors + (long)cg * CH + c * CPL;
#pragma unroll
        for (int i = 0; i < 8; i++) {
            if constexpr (CPL == 2 && sizeof(TO) == 2) {
                const unsigned u = (unsigned)(unsigned short)f2b(acc[0][i]) |
                                   ((unsigned)(unsigned short)f2b(acc[1][i]) << 16);
                *(unsigned*)(void*)(o + (long)i * ors) = u;
            } else {
                o[(long)i * ors] = (TO)acc[0][i];
            }
        }
#pragma unroll
        for (int p = 0; p < CPL; p++)
#pragma unroll
            for (int i = 0; i < 10; i++) { r0[p][i] = r1[p][i]; r1[p][i] = r2[p][i]; }
    }
}

// ---------------- LayerNorm over C=512, fp32 in -> bf16 out ----------------
__global__ __launch_bounds__(256) void ln_k(const float* __restrict__ x,
                                            const float* __restrict__ w,
                                            const float* __restrict__ bp,
                                            bf16* __restrict__ out)
{
    const size_t row = blockIdx.x * 4 + (threadIdx.x >> 6);
    const int t = threadIdx.x & 63;
    const float* xr = x + row * 512;
    alignas(16) float v[8];
    *(float4*)&v[0] = *(const float4*)(xr + t * 8);
    *(float4*)&v[4] = *(const float4*)(xr + t * 8 + 4);
    float s = 0.f;
#pragma unroll
    for (int j = 0; j < 8; j++) s += v[j];
#pragma unroll
    for (int mm = 32; mm; mm >>= 1) s += __shfl_xor(s, mm);
    const float mu = s * (1.f / 512.f);
    float q = 0.f;
#pragma unroll
    for (int j = 0; j < 8; j++) { v[j] -= mu; q += v[j] * v[j]; }
#pragma unroll
    for (int mm = 32; mm; mm >>= 1) q += __shfl_xor(q, mm);
    const float rstd = rsqrtf(q * (1.f / 512.f) + 1e-6f);
    alignas(16) float wv[8], bv[8];
    *(float4*)&wv[0] = *(const float4*)(w + t * 8);
    *(float4*)&wv[4] = *(const float4*)(w + t * 8 + 4);
    *(float4*)&bv[0] = *(const float4*)(bp + t * 8);
    *(float4*)&bv[4] = *(const float4*)(bp + t * 8 + 4);
    alignas(16) bf16 o[8];
#pragma unroll
    for (int j = 0; j < 8; j++) o[j] = __float2bfloat16(v[j] * rstd * wv[j] + bv[j]);
    *(uint4*)(out + row * 512 + t * 8) = *(const uint4*)o;
}

// ---------------- 256-wide bf16 MFMA GEMM: C = A[M,K] * Bw[N,K]^T -----------
// BM=256, BK=64, 512 threads (8 waves). BN=256: waves 2x4 (out 128x64/wave),
// LDS 128KB, 1 block/CU. BN=64: waves 8x1 (out 32x64/wave), LDS 80KB, 2/CU.
// Double-buffered; per K-tile: STAGE(next) -> COMPUTE(cur) -> vmcnt(0) -> barrier.
// Swizzle: LDS[row][slot16B] = global slot (slot ^ (row&7)); read side same XOR
// -> fragment reads 2 lanes/bank (free), staging coalesced 128B/row.
template <int EPI, int BN>
__global__ __launch_bounds__(512) void gemm256_k(
    const bf16* __restrict__ A, const bf16* __restrict__ Bw,
    const float* __restrict__ bias, const float* resid,
    bf16* __restrict__ outb, float* outf,
    int M, int Nn, int K)
{
    constexpr int MI = (BN == 256) ? 8 : 2;   // A-frag rows per wave
    constexpr int NJ = 4;                     // B-frag cols per wave (64/16)
    constexpr int WH = (BN == 256) ? 128 : 32;
    __shared__ __align__(16) short As[2][256 * 64];
    __shared__ __align__(16) short Bs[2][BN * 64];
    const int t = threadIdx.x;
    const int lane = t & 63;
    const int w = t >> 6;                     // wave 0..7
    const int wr = (BN == 256) ? (w >> 2) : w;
    const int wc = (BN == 256) ? (w & 3) : 0;
    const int m0 = blockIdx.x * 256;
    const int n0 = blockIdx.y * BN;
    const int lr = lane & 15, lg = lane >> 4;

    f32x4 acc[MI][NJ] = {};

    // staging: instr = 1024B = 8 rows x 8 slots; lane l -> row l>>3, slot l&7.
    // source elem = 8*(slot ^ row&7)  (row base multiple of 8 -> row&7 = l>>3)
    const int srow = lane >> 3, sslot = lane & 7;
    const int ssrc = 8 * (sslot ^ srow);
    const bf16* Ag[4];
#pragma unroll
    for (int i = 0; i < 4; i++)
        Ag[i] = A + (size_t)(m0 + w * 32 + i * 8 + srow) * K + ssrc;
    const bf16* Bg[4];
#pragma unroll
    for (int i = 0; i < 4; i++)
        Bg[i] = (BN == 256) ? (Bw + (size_t)(n0 + w * 32 + i * 8 + srow) * K + ssrc)
                            : (Bw + (size_t)(n0 + w * 8 + srow) * K + ssrc);

    auto STAGE = [&](int buf, int kt) {
        const int k0 = kt * 64;
#pragma unroll
        for (int i = 0; i < 4; i++)
            gload_lds16(Ag[i] + k0, (char*)&As[buf][0] + (w * 32 + i * 8) * 128);
        if constexpr (BN == 256) {
#pragma unroll
            for (int i = 0; i < 4; i++)
                gload_lds16(Bg[i] + k0, (char*)&Bs[buf][0] + (w * 32 + i * 8) * 128);
        } else {
            gload_lds16(Bg[0] + k0, (char*)&Bs[buf][0] + (w * 8) * 128);
        }
    };

    auto COMPUTE = [&](int buf) {
#pragma unroll
        for (int ks = 0; ks < 2; ks++) {
            s16x8 aF[MI], bF[NJ];
            const int xo = (ks * 4 + lg) ^ (lr & 7);   // swizzled slot (per-lane const)
#pragma unroll
            for (int i = 0; i < MI; i++) {
                const int row = wr * WH + i * 16 + lr;
                aF[i] = *(const s16x8*)((const char*)&As[buf][0] + row * 128 + xo * 16);
            }
#pragma unroll
            for (int j = 0; j < NJ; j++) {
                const int row = wc * 64 + j * 16 + lr;
                bF[j] = *(const s16x8*)((const char*)&Bs[buf][0] + row * 128 + xo * 16);
            }
#pragma unroll
            for (int i = 0; i < MI; i++)
#pragma unroll
                for (int j = 0; j < NJ; j++)
                    acc[i][j] = __builtin_amdgcn_mfma_f32_16x16x32_bf16(aF[i], bF[j], acc[i][j], 0, 0, 0);
        }
    };

    const int KT = K / 64;
    STAGE(0, 0);
    WAITVM0;
    __builtin_amdgcn_s_barrier();
    for (int kt = 0; kt < KT; ++kt) {
        if (kt + 1 < KT) STAGE((kt + 1) & 1, kt + 1);
        COMPUTE(kt & 1);
        WAITVM0;                       // next tile's loads (flew under COMPUTE)
        __builtin_amdgcn_s_barrier();  // frees buffer cur for overwrite next iter
    }

#pragma unroll
    for (int i = 0; i < MI; i++) {
#pragma unroll
        for (int j = 0; j < NJ; j++) {
            const int col = n0 + wc * 64 + j * 16 + lr;
            const float bcol = (EPI > 0) ? bias[col] : 0.f;
#pragma unroll
            for (int r = 0; r < 4; r++) {
                const int row = m0 + wr * WH + i * 16 + lg * 4 + r;
                float v = acc[i][j][r] + bcol;
                const size_t idx = (size_t)row * Nn + col;
                if (EPI == 0) outb[idx] = __float2bfloat16(v);
                else if (EPI == 1) outb[idx] = __float2bfloat16(gelu_f(v));
                else outf[idx] = v + resid[idx];
            }
        }
    }
}

// ---------------- ktv partials: no max-subtraction softmax -------------------
__global__ __launch_bounds__(256) void ktv_part_k(const bf16* __restrict__ qkv,
                                                  float* __restrict__ ktvp,
                                                  float* __restrict__ csp)
{
    const int b = blockIdx.x >> 5;
    const int hh = (blockIdx.x >> 2) & 7;
    const int sp = blockIdx.x & 3;
    const bf16* kb = qkv + (size_t)b * 1024 * 1536 + 512 + hh * 64;
    const bf16* vb = kb + 512;
    __shared__ __align__(16) bf16 Ks[16 * 64];
    __shared__ __align__(16) bf16 Vs[16 * 64];
    const int t = threadIdx.x;
    const int kk = t & 63, vg = t >> 6;
    float acc[16] = {};
    float psum = 0.f;
    const int sr = t >> 4, sc = (t & 15) * 4;
    for (int n0 = sp * 256; n0 < sp * 256 + 256; n0 += 16) {
        __syncthreads();
        *(s16x4*)(void*)(Ks + sr * 64 + sc) = *(const s16x4*)(const void*)(kb + (size_t)(n0 + sr) * 1536 + sc);
        *(s16x4*)(void*)(Vs + sr * 64 + sc) = *(const s16x4*)(const void*)(vb + (size_t)(n0 + sr) * 1536 + sc);
        __syncthreads();
#pragma unroll
        for (int i = 0; i < 16; i++) {
            const float p = __expf(b2f(*(const short*)(const void*)(Ks + i * 64 + kk)));
            psum += p;
            float vv[16];
            ld8(Vs + i * 64 + vg * 16, vv);
            ld8(Vs + i * 64 + vg * 16 + 8, vv + 8);
#pragma unroll
            for (int j = 0; j < 16; j++) acc[j] += p * vv[j];
        }
    }
    const int bh4 = (b * 8 + hh) * 4 + sp;
    float* o = ktvp + (size_t)bh4 * 4096 + kk * 64 + vg * 16;
#pragma unroll
    for (int j = 0; j < 16; j++) o[j] = acc[j];
    if (vg == 0) csp[bh4 * 64 + kk] = psum;
}

// ---------------- ktv reduce ----------
__global__ __launch_bounds__(256) void ktv_red_k(const float* __restrict__ ktvp,
                                                 const float* __restrict__ csp,
                                                 float* __restrict__ ktv)
{
    const int bh = blockIdx.x;
    const int t = threadIdx.x;
#pragma unroll
    for (int i = 0; i < 16; i++) {
        const int e = t + 256 * i;
        const int kk = e >> 6;
        float cs = 0.f, v = 0.f;
#pragma unroll
        for (int sp = 0; sp < 4; sp++) {
            cs += csp[(bh * 4 + sp) * 64 + kk];
            v += ktvp[(size_t)(bh * 4 + sp) * 4096 + e];
        }
        ktv[(size_t)bh * 4096 + e] = v * (0.125f / cs);
    }
}

// ---------------- xs += q @ ktv_scaled + q * vconv  (in place) --------------
__global__ __launch_bounds__(256) void attnout_k(
    float* xs, const bf16* __restrict__ qkv,
    const float* __restrict__ ktv, const bf16* __restrict__ vc)
{
    const int nc = blockIdx.x & 31, hh = (blockIdx.x >> 5) & 7, b = blockIdx.x >> 8;
    __shared__ __align__(16) float kt[64 * 64];
    __shared__ __align__(16) bf16 qs[32 * 64];
    const int t = threadIdx.x;
    const float4* ksrc = (const float4*)(ktv + (size_t)(b * 8 + hh) * 4096);
    for (int u = t; u < 1024; u += 256) ((float4*)kt)[u] = ksrc[u];
    const int n0 = nc * 32;
    {
        const int r = t >> 3, cc = (t & 7) * 8;
        *(uint4*)(qs + r * 64 + cc) =
            *(const uint4*)(qkv + ((size_t)b * 1024 + n0 + r) * 1536 + hh * 64 + cc);
    }
    __syncthreads();
    const int dv = t & 63, rb = (t >> 6) * 8;
    for (int r = rb; r < rb + 8; r++) {
        float fa = 0.f;
#pragma unroll
        for (int kk = 0; kk < 64; kk++)
            fa += b2f(*(const short*)(const void*)(qs + r * 64 + kk)) * kt[kk * 64 + dv];
        const size_t idx = ((size_t)b * 1024 + n0 + r) * 512 + hh * 64 + dv;
        const float qv = b2f(*(const short*)(const void*)(qs + r * 64 + dv));
        xs[idx] = xs[idx] + fa + qv * __bfloat162float(vc[idx]);
    }
}

// ---------------- workspace layout (bytes) ----------------------------------
static constexpr int    BC       = 8;
static constexpr int    NCHUNK   = 4;
static constexpr size_t OFF_WQ   = 0;
static constexpr size_t OFF_W1   = 1572864;
static constexpr size_t OFF_W2   = 3670016;
static constexpr size_t OFF_CUR  = 5767168;
static constexpr size_t OFF_QKV  = 14155776;
static constexpr size_t OFF_KTVP = 39321600;
static constexpr size_t OFF_CSP  = 43515904;
static constexpr size_t OFF_KTV  = 43581440;
static constexpr size_t OFF_VC   = 44630016;
static constexpr size_t OFF_HG   = 14155776;   // over dead qkv region
static constexpr size_t OFF_H2   = 47710208;   // over dead vc tail
static constexpr size_t WS_NEED  = 81264640;   // ~77.5MB

extern "C" void kernel_launch(void* const* d_in, const int* in_sizes, int n_in,
                              void* d_out, int out_size, void* d_ws, size_t ws_size,
                              hipStream_t stream)
{
    const float* x     = (const float*)d_in[0];
    const float* cpe_w = (const float*)d_in[1];
    const float* cpe_b = (const float*)d_in[2];
    const float* ln1_w = (const float*)d_in[3];
    const float* ln1_b = (const float*)d_in[4];
    const float* qkv_w = (const float*)d_in[5];
    const float* crpe_w= (const float*)d_in[6];
    const float* crpe_b= (const float*)d_in[7];
    const float* ln2_w = (const float*)d_in[8];
    const float* ln2_b = (const float*)d_in[9];
    const float* fc1_w = (const float*)d_in[10];
    const float* fc1_b = (const float*)d_in[11];
    const float* dw_w  = (const float*)d_in[12];
    const float* dw_b  = (const float*)d_in[13];
    const float* fc2_w = (const float*)d_in[14];
    const float* fc2_b = (const float*)d_in[15];
    float* spine = (float*)d_out;
    char* ws = (char*)d_ws;

    if (ws_size < WS_NEED) {
        diag_k<<<1, 1, 0, stream>>>(spine, (float)ws_size);
        return;
    }

    bf16*  wq   = (bf16*)(ws + OFF_WQ);
    bf16*  w1   = (bf16*)(ws + OFF_W1);
    bf16*  w2   = (bf16*)(ws + OFF_W2);
    bf16*  cur  = (bf16*)(ws + OFF_CUR);
    bf16*  qkv  = (bf16*)(ws + OFF_QKV);
    float* ktvp = (float*)(ws + OFF_KTVP);
    float* csp  = (float*)(ws + OFF_CSP);
    float* ktv  = (float*)(ws + OFF_KTV);
    bf16*  vc   = (bf16*)(ws + OFF_VC);
    bf16*  hg   = (bf16*)(ws + OFF_HG);
    bf16*  h2   = (bf16*)(ws + OFF_H2);

    // weights -> bf16
    f2bf_k<<<(1536 * 512 / 8 + 255) / 256, 256, 0, stream>>>(qkv_w, wq, 1536 * 512);
    f2bf_k<<<(2048 * 512 / 8 + 255) / 256, 256, 0, stream>>>(fc1_w, w1, 2048 * 512);
    f2bf_k<<<(2048 * 512 / 8 + 255) / 256, 256, 0, stream>>>(fc2_w, w2, 2048 * 512);

    // CPE (full batch, fp32, 64-ch groups): spine = x + dwconv(x) + cpe_b
    conv4_k<float, float, true, 1><<<32 * 8 * 4, 256, 0, stream>>>(x, 512, 0, cpe_w, cpe_b, spine, 512, 3);

    const int Mc = BC * 1024;  // 8192 rows per chunk
    for (int c = 0; c < NCHUNK; c++) {
        float* xs = spine + (size_t)c * Mc * 512;
        ln_k<<<Mc / 4, 256, 0, stream>>>(xs, ln1_w, ln1_b, cur);
        // qkv = cur @ qkv_w^T   (grid 32x6, 1 block/CU)
        gemm256_k<0, 256><<<dim3(Mc / 256, 6), 512, 0, stream>>>(cur, wq, nullptr, nullptr, qkv, nullptr, Mc, 1536, 512);
        ktv_part_k<<<BC * 8 * 4, 256, 0, stream>>>(qkv, ktvp, csp);
        ktv_red_k<<<BC * 8, 256, 0, stream>>>(ktvp, csp, ktv);
        conv4_k<bf16, bf16, false, 2><<<BC * 4 * 4, 256, 0, stream>>>(qkv, 1536, 1024, crpe_w, crpe_b, vc, 512, 2);
        attnout_k<<<BC * 8 * 32, 256, 0, stream>>>(xs, qkv, ktv, vc);
        ln_k<<<Mc / 4, 256, 0, stream>>>(xs, ln2_w, ln2_b, cur);
        // fc1 + gelu   (grid 32x8 = 256 blocks, 1/CU)
        gemm256_k<1, 256><<<dim3(Mc / 256, 8), 512, 0, stream>>>(cur, w1, fc1_b, nullptr, hg, nullptr, Mc, 2048, 512);
        conv4_k<bf16, bf16, true, 2><<<BC * 16 * 4, 256, 0, stream>>>(hg, 2048, 0, dw_w, dw_b, h2, 2048, 4);
        // fc2: BN=64 variant (grid 32x8 = 256 blocks, 2/CU)
        gemm256_k<2, 64><<<dim3(Mc / 256, 8), 512, 0, stream>>>(h2, w2, fc2_b, xs, nullptr, xs, Mc, 512, 2048);
    }
}

// Round 10
// 822.741 us; speedup vs baseline: 1.0202x; 1.0185x over previous
//
#include <hip/hip_runtime.h>
#include <hip/hip_bf16.h>

using bf16 = __hip_bfloat16;
using s16x4 = __attribute__((ext_vector_type(4))) short;
using s16x8 = __attribute__((ext_vector_type(8))) short;
using f32x4 = __attribute__((ext_vector_type(4))) float;

#define DI __device__ __forceinline__

template <int N> DI void wvm() {
    if constexpr (N == 8) asm volatile("s_waitcnt vmcnt(8)" ::: "memory");
    else if constexpr (N == 4) asm volatile("s_waitcnt vmcnt(4)" ::: "memory");
    else if constexpr (N == 2) asm volatile("s_waitcnt vmcnt(2)" ::: "memory");
    else asm volatile("s_waitcnt vmcnt(0)" ::: "memory");
}

DI float b2f(short s) { union { unsigned u; float f; } z; z.u = ((unsigned)(unsigned short)s) << 16; return z.f; }
DI short f2b(float f) { bf16 t = __float2bfloat16(f); return *(short*)&t; }

// fast gelu: tanh form, |err| ~1e-3 absolute, far under threshold
DI float gelu_f(float x) {
    const float t = 0.7978845608f * x * (1.f + 0.044715f * x * x);
    const float e = __expf(2.f * t);
    const float th = 1.f - 2.f / (e + 1.f);
    return 0.5f * x * (1.f + th);
}

DI void ld8(const bf16* p, float* f) {
    s16x8 x = *(const s16x8*)(const void*)p;
#pragma unroll
    for (int c = 0; c < 8; c++) f[c] = b2f(x[c]);
}
DI void ld8(const float* p, float* f) {
    float4 a = *(const float4*)p, b = *(const float4*)(p + 4);
    f[0]=a.x; f[1]=a.y; f[2]=a.z; f[3]=a.w; f[4]=b.x; f[5]=b.y; f[6]=b.z; f[7]=b.w;
}

typedef const __attribute__((address_space(1))) void* gp_t;
typedef __attribute__((address_space(3))) void* lp_t;
DI void gload_lds16(const void* g, void* l) {
    __builtin_amdgcn_global_load_lds((gp_t)g, (lp_t)l, 16, 0, 0);
}

// ---------------- diagnostic ----------------
__global__ void diag_k(float* out, float v) { out[0] = v; }

// ---------------- fp32 -> bf16 weight conversion (8/thread) ----------------
__global__ void f2bf_k(const float* __restrict__ in, bf16* __restrict__ out, int n) {
    int i = (blockIdx.x * 256 + threadIdx.x) * 8;
    if (i >= n) return;
    float f[8];
    ld8(in + i, f);
    s16x8 o;
#pragma unroll
    for (int c = 0; c < 8; c++) o[c] = f2b(f[c]);
    *(s16x8*)(void*)(out + i) = o;
}

// ---------------- depthwise 3x3 conv v4 ----------------
DI void tap10(const float* r, float w0, float w1, float w2, float* acc) {
#pragma unroll
    for (int i = 0; i < 8; i++)
        acc[i] += w0 * r[i] + w1 * r[i + 1] + w2 * r[i + 2];
}

template <typename TI, typename TO, bool RESID, int CPL>
__global__ __launch_bounds__(256) void conv4_k(
    const TI* in, long rs, long coff,
    const float* __restrict__ w, const float* __restrict__ bias,
    TO* out, long ors, int gshift)
{
    constexpr int CH = 64 * CPL;
    constexpr int ECNT = CH / 8;
    __shared__ float buf[2][CH][33];
    const int t = threadIdx.x;
    const int band = blockIdx.x & 3;
    const int cg = (blockIdx.x >> 2) & ((1 << gshift) - 1);
    const int img = blockIdx.x >> (2 + gshift);
    const int y0 = band * 8;

    const int spx = t >> 3;
    const int sce = (t & 7) * ECNT;
    const TI* gsrc = in + ((long)img << 10) * rs + coff + (long)cg * CH + sce;

    const int c = t & 63;
    const int xb = (t >> 6) * 8;

    float wv9[9][CPL], bw[CPL];
#pragma unroll
    for (int p = 0; p < CPL; p++) {
        const int gch = cg * CH + c * CPL + p;
#pragma unroll
        for (int j = 0; j < 9; j++) wv9[j][p] = w[gch * 9 + j];
        bw[p] = bias[gch];
    }

    auto stage = [&](int row) {
        float f[ECNT];
        ld8(gsrc + (long)(row * 32 + spx) * rs, f);
        if constexpr (ECNT == 16) ld8(gsrc + (long)(row * 32 + spx) * rs + 8, f + 8);
        float* d = &buf[row & 1][0][0];
#pragma unroll
        for (int k = 0; k < ECNT; k++) {
            const int ch = sce + k;
            const int rr = (CPL == 2) ? ((ch & 1) * 64 + (ch >> 1)) : ch;
            d[rr * 33 + spx] = f[k];
        }
    };
    auto slice = [&](int row, float r[CPL][10]) {
#pragma unroll
        for (int p = 0; p < CPL; p++) {
            const float* s = &buf[row & 1][c + p * 64][0];
            r[p][0] = (xb == 0) ? 0.f : s[xb - 1];
#pragma unroll
            for (int i = 0; i < 8; i++) r[p][1 + i] = s[xb + i];
            r[p][9] = (xb + 8 >= 32) ? 0.f : s[xb + 8];
        }
    };
    auto zero = [&](float r[CPL][10]) {
#pragma unroll
        for (int p = 0; p < CPL; p++)
#pragma unroll
            for (int i = 0; i < 10; i++) r[p][i] = 0.f;
    };

    float r0[CPL][10], r1[CPL][10], r2[CPL][10];
    if (y0 > 0) stage(y0 - 1);
    __syncthreads();
    if (y0 > 0) slice(y0 - 1, r0); else zero(r0);
    stage(y0);
    __syncthreads();
    slice(y0, r1);

    for (int y = y0; y < y0 + 8; ++y) {
        const int yn = y + 1;
        if (yn <= 31) stage(yn);
        __syncthreads();
        if (yn <= 31) slice(yn, r2); else zero(r2);
        float acc[CPL][8];
#pragma unroll
        for (int p = 0; p < CPL; p++) {
#pragma unroll
            for (int i = 0; i < 8; i++) acc[p][i] = bw[p];
            tap10(r0[p], wv9[0][p], wv9[1][p], wv9[2][p], acc[p]);
            tap10(r1[p], wv9[3][p], wv9[4][p], wv9[5][p], acc[p]);
            tap10(r2[p], wv9[6][p], wv9[7][p], wv9[8][p], acc[p]);
            if (RESID) {
#pragma unroll
                for (int i = 0; i < 8; i++) acc[p][i] += r1[p][i + 1];
            }
        }
        TO* o = out + ((long)(img * 1024 + y * 32 + xb)) * ors + (long)cg * CH + c * CPL;
#pragma unroll
        for (int i = 0; i < 8; i++) {
            if constexpr (CPL == 2 && sizeof(TO) == 2) {
                const unsigned u = (unsigned)(unsigned short)f2b(acc[0][i]) |
                                   ((unsigned)(unsigned short)f2b(acc[1][i]) << 16);
                *(unsigned*)(void*)(o + (long)i * ors) = u;
            } else {
                o[(long)i * ors] = (TO)acc[0][i];
            }
        }
#pragma unroll
        for (int p = 0; p < CPL; p++)
#pragma unroll
            for (int i = 0; i < 10; i++) { r0[p][i] = r1[p][i]; r1[p][i] = r2[p][i]; }
    }
}

// ---------------- LayerNorm over C=512, fp32 in -> bf16 out ----------------
__global__ __launch_bounds__(256) void ln_k(const float* __restrict__ x,
                                            const float* __restrict__ w,
                                            const float* __restrict__ bp,
                                            bf16* __restrict__ out)
{
    const size_t row = blockIdx.x * 4 + (threadIdx.x >> 6);
    const int t = threadIdx.x & 63;
    const float* xr = x + row * 512;
    alignas(16) float v[8];
    *(float4*)&v[0] = *(const float4*)(xr + t * 8);
    *(float4*)&v[4] = *(const float4*)(xr + t * 8 + 4);
    float s = 0.f;
#pragma unroll
    for (int j = 0; j < 8; j++) s += v[j];
#pragma unroll
    for (int mm = 32; mm; mm >>= 1) s += __shfl_xor(s, mm);
    const float mu = s * (1.f / 512.f);
    float q = 0.f;
#pragma unroll
    for (int j = 0; j < 8; j++) { v[j] -= mu; q += v[j] * v[j]; }
#pragma unroll
    for (int mm = 32; mm; mm >>= 1) q += __shfl_xor(q, mm);
    const float rstd = rsqrtf(q * (1.f / 512.f) + 1e-6f);
    alignas(16) float wv[8], bv[8];
    *(float4*)&wv[0] = *(const float4*)(w + t * 8);
    *(float4*)&wv[4] = *(const float4*)(w + t * 8 + 4);
    *(float4*)&bv[0] = *(const float4*)(bp + t * 8);
    *(float4*)&bv[4] = *(const float4*)(bp + t * 8 + 4);
    alignas(16) bf16 o[8];
#pragma unroll
    for (int j = 0; j < 8; j++) o[j] = __float2bfloat16(v[j] * rstd * wv[j] + bv[j]);
    *(uint4*)(out + row * 512 + t * 8) = *(const uint4*)o;
}

// ---------------- 8-phase 256x256 bf16 MFMA GEMM (K compile-time) -----------
// m201-template port: BK=64, 8 waves 2Mx4N, 128KB LDS (2buf x 2half x A,B).
// Per K-tile 4 phases (C-quadrants); per phase: ds_read subtile -> stage one
// half-tile -> barrier -> setprio(1) 16 MFMA setprio(0) -> counted vmcnt -> barrier.
// Steady-state flight depth = 4 half-tiles (vmcnt(8)); tail 8/4/2/0.
// Halves: A by quadrant parity (row>>6)&1; B by (row>>5)&1 (per-wave n-halves).
// Swizzle: LDS[row][slot]=global slot^(row&7), pre-swizzled global source.
template <int EPI, int K>
__global__ __launch_bounds__(512) void gemm8p_k(
    const bf16* __restrict__ A, const bf16* __restrict__ Bw,
    const float* __restrict__ bias, bf16* __restrict__ outb, int M, int Nn)
{
    constexpr int KT = K / 64;
    __shared__ __align__(16) char lds[131072];
    char* ldsA = lds;
    char* ldsB = lds + 65536;
    const int t = threadIdx.x;
    const int lane = t & 63;
    const int w = t >> 6;                 // wave 0..7
    const int wr = w >> 2, wc = w & 3;    // 2M x 4N
    const int m0 = blockIdx.x * 256;
    const int n0 = blockIdx.y * 256;
    const int lr = lane & 15, lg = lane >> 4;

    f32x4 acc[8][4] = {};

    const int srow = lane >> 3;                 // 0..7
    const int ssrc = 8 * ((lane & 7) ^ srow);   // pre-swizzled k-slot (elems)

    auto SA = [&](int b, int kt, int h) {       // stage A-half h of tile kt
#pragma unroll
        for (int j = 0; j < 2; j++) {
            const int lrow0 = j * 64 + w * 8;
            const int R0 = j * 128 + h * 64 + (lrow0 & 63);
            gload_lds16(A + (size_t)(m0 + R0 + srow) * K + kt * 64 + ssrc,
                        ldsA + ((b * 2 + h) * 128 + lrow0) * 128);
        }
    };
    auto SB = [&](int b, int kt, int h) {       // stage B-half h of tile kt
#pragma unroll
        for (int j = 0; j < 2; j++) {
            const int lrow0 = j * 64 + w * 8;
            const int R0 = (lrow0 >> 5) * 64 + h * 32 + (lrow0 & 31);
            gload_lds16(Bw + (size_t)(n0 + R0 + srow) * K + kt * 64 + ssrc,
                        ldsB + ((b * 2 + h) * 128 + lrow0) * 128);
        }
    };
    auto RA = [&](int b, int h, int m, int ks) -> s16x8 {  // m local 0..3
        return *(const s16x8*)(ldsA + ((b * 2 + h) * 128 + wr * 64 + m * 16 + lr) * 128
                               + (((ks * 4 + lg) ^ (lr & 7)) << 4));
    };
    auto RB = [&](int b, int h, int n, int ks) -> s16x8 {  // n local 0..1
        return *(const s16x8*)(ldsB + ((b * 2 + h) * 128 + wc * 32 + n * 16 + lr) * 128
                               + (((ks * 4 + lg) ^ (lr & 7)) << 4));
    };
    auto MM = [&](int mb, int nb, s16x8 (&a)[2][4], s16x8 (&b)[2][2]) {
#pragma unroll
        for (int ks = 0; ks < 2; ks++)
#pragma unroll
            for (int m = 0; m < 4; m++)
#pragma unroll
                for (int n = 0; n < 2; n++)
                    acc[mb + m][nb + n] =
                        __builtin_amdgcn_mfma_f32_16x16x32_bf16(a[ks][m], b[ks][n], acc[mb + m][nb + n], 0, 0, 0);
    };

    // prologue: A-lo(0), B-lo(0), A-hi(0), B-hi(0), A-lo(1), B-lo(1)
    SA(0, 0, 0); SB(0, 0, 0); SA(0, 0, 1); SB(0, 0, 1);
    SA(1, 1, 0); SB(1, 1, 0);
    wvm<8>();
    __builtin_amdgcn_s_barrier();

    s16x8 aLo[2][4], aHi[2][4], bLo[2][2], bHi[2][2];
#pragma unroll
    for (int kt = 0; kt < KT; ++kt) {
        const int b = kt & 1;
        // ---- phase 0: (M-lo x N-lo); stage A-hi(kt+1)
#pragma unroll
        for (int ks = 0; ks < 2; ks++) {
#pragma unroll
            for (int m = 0; m < 4; m++) aLo[ks][m] = RA(b, 0, m, ks);
#pragma unroll
            for (int n = 0; n < 2; n++) bLo[ks][n] = RB(b, 0, n, ks);
        }
        if (kt + 1 < KT) SA(b ^ 1, kt + 1, 1);
        __builtin_amdgcn_s_barrier();
        __builtin_amdgcn_s_setprio(1);
        MM(0, 0, aLo, bLo);
        __builtin_amdgcn_s_setprio(0);
        if (kt + 1 < KT) wvm<8>(); else wvm<2>();
        __builtin_amdgcn_s_barrier();
        // ---- phase 1: (M-hi x N-lo); stage B-hi(kt+1)
#pragma unroll
        for (int ks = 0; ks < 2; ks++)
#pragma unroll
            for (int m = 0; m < 4; m++) aHi[ks][m] = RA(b, 1, m, ks);
        if (kt + 1 < KT) SB(b ^ 1, kt + 1, 1);
        __builtin_amdgcn_s_barrier();
        __builtin_amdgcn_s_setprio(1);
        MM(4, 0, aHi, bLo);
        __builtin_amdgcn_s_setprio(0);
        if (kt + 1 < KT) wvm<8>(); else wvm<0>();
        __builtin_amdgcn_s_barrier();
        // ---- phase 2: (M-hi x N-hi); stage A-lo(kt+2)
#pragma unroll
        for (int ks = 0; ks < 2; ks++)
#pragma unroll
            for (int n = 0; n < 2; n++) bHi[ks][n] = RB(b, 1, n, ks);
        if (kt + 2 < KT) SA(b, kt + 2, 0);
        __builtin_amdgcn_s_barrier();
        __builtin_amdgcn_s_setprio(1);
        MM(4, 2, aHi, bHi);
        __builtin_amdgcn_s_setprio(0);
        __builtin_amdgcn_s_barrier();
        // ---- phase 3: (M-lo x N-hi); stage B-lo(kt+2)
        if (kt + 2 < KT) SB(b, kt + 2, 0);
        __builtin_amdgcn_s_barrier();
        __builtin_amdgcn_s_setprio(1);
        MM(0, 2, aLo, bHi);
        __builtin_amdgcn_s_setprio(0);
        if (kt + 2 < KT) { wvm<8>(); __builtin_amdgcn_s_barrier(); }
        else if (kt + 1 < KT) { wvm<4>(); __builtin_amdgcn_s_barrier(); }
    }

#pragma unroll
    for (int i = 0; i < 8; i++) {
#pragma unroll
        for (int j = 0; j < 4; j++) {
            const int col = n0 + wc * 64 + j * 16 + lr;
            const float bcol = (EPI > 0) ? bias[col] : 0.f;
#pragma unroll
            for (int r = 0; r < 4; r++) {
                const int row = m0 + wr * 128 + i * 16 + lg * 4 + r;
                float v = acc[i][j][r] + bcol;
                const size_t idx = (size_t)row * Nn + col;
                outb[idx] = __float2bfloat16(EPI == 1 ? gelu_f(v) : v);
            }
        }
    }
}

// ---------------- fc2 GEMM (BN=64, r9 structure) ----------------------------
__global__ __launch_bounds__(512) void gemmfc2_k(
    const bf16* __restrict__ A, const bf16* __restrict__ Bw,
    const float* __restrict__ bias, const float* resid, float* outf,
    int M, int Nn, int K)
{
    constexpr int MI = 2, NJ = 4;
    __shared__ __align__(16) short As[2][256 * 64];
    __shared__ __align__(16) short Bs[2][64 * 64];
    const int t = threadIdx.x;
    const int lane = t & 63;
    const int w = t >> 6;
    const int m0 = blockIdx.x * 256;
    const int n0 = blockIdx.y * 64;
    const int lr = lane & 15, lg = lane >> 4;

    f32x4 acc[MI][NJ] = {};

    const int srow = lane >> 3, sslot = lane & 7;
    const int ssrc = 8 * (sslot ^ srow);
    const bf16* Ag[4];
#pragma unroll
    for (int i = 0; i < 4; i++)
        Ag[i] = A + (size_t)(m0 + w * 32 + i * 8 + srow) * K + ssrc;
    const bf16* Bg = Bw + (size_t)(n0 + w * 8 + srow) * K + ssrc;

    auto STAGE = [&](int buf, int kt) {
        const int k0 = kt * 64;
#pragma unroll
        for (int i = 0; i < 4; i++)
            gload_lds16(Ag[i] + k0, (char*)&As[buf][0] + (w * 32 + i * 8) * 128);
        gload_lds16(Bg + k0, (char*)&Bs[buf][0] + (w * 8) * 128);
    };

    auto COMPUTE = [&](int buf) {
#pragma unroll
        for (int ks = 0; ks < 2; ks++) {
            s16x8 aF[MI], bF[NJ];
            const int xo = (ks * 4 + lg) ^ (lr & 7);
#pragma unroll
            for (int i = 0; i < MI; i++) {
                const int row = w * 32 + i * 16 + lr;
                aF[i] = *(const s16x8*)((const char*)&As[buf][0] + row * 128 + xo * 16);
            }
#pragma unroll
            for (int j = 0; j < NJ; j++) {
                const int row = j * 16 + lr;
                bF[j] = *(const s16x8*)((const char*)&Bs[buf][0] + row * 128 + xo * 16);
            }
#pragma unroll
            for (int i = 0; i < MI; i++)
#pragma unroll
                for (int j = 0; j < NJ; j++)
                    acc[i][j] = __builtin_amdgcn_mfma_f32_16x16x32_bf16(aF[i], bF[j], acc[i][j], 0, 0, 0);
        }
    };

    const int KT = K / 64;
    STAGE(0, 0);
    wvm<0>();
    __builtin_amdgcn_s_barrier();
    for (int kt = 0; kt < KT; ++kt) {
        if (kt + 1 < KT) STAGE((kt + 1) & 1, kt + 1);
        COMPUTE(kt & 1);
        wvm<0>();
        __builtin_amdgcn_s_barrier();
    }

#pragma unroll
    for (int i = 0; i < MI; i++) {
#pragma unroll
        for (int j = 0; j < NJ; j++) {
            const int col = n0 + j * 16 + lr;
            const float bcol = bias[col];
#pragma unroll
            for (int r = 0; r < 4; r++) {
                const int row = m0 + w * 32 + i * 16 + lg * 4 + r;
                const size_t idx = (size_t)row * Nn + col;
                outf[idx] = acc[i][j][r] + bcol + resid[idx];
            }
        }
    }
}

// ---------------- ktv partials: no max-subtraction softmax -------------------
__global__ __launch_bounds__(256) void ktv_part_k(const bf16* __restrict__ qkv,
                                                  float* __restrict__ ktvp,
                                                  float* __restrict__ csp)
{
    const int b = blockIdx.x >> 5;
    const int hh = (blockIdx.x >> 2) & 7;
    const int sp = blockIdx.x & 3;
    const bf16* kb = qkv + (size_t)b * 1024 * 1536 + 512 + hh * 64;
    const bf16* vb = kb + 512;
    __shared__ __align__(16) bf16 Ks[16 * 64];
    __shared__ __align__(16) bf16 Vs[16 * 64];
    const int t = threadIdx.x;
    const int kk = t & 63, vg = t >> 6;
    float acc[16] = {};
    float psum = 0.f;
    const int sr = t >> 4, sc = (t & 15) * 4;
    for (int n0 = sp * 256; n0 < sp * 256 + 256; n0 += 16) {
        __syncthreads();
        *(s16x4*)(void*)(Ks + sr * 64 + sc) = *(const s16x4*)(const void*)(kb + (size_t)(n0 + sr) * 1536 + sc);
        *(s16x4*)(void*)(Vs + sr * 64 + sc) = *(const s16x4*)(const void*)(vb + (size_t)(n0 + sr) * 1536 + sc);
        __syncthreads();
#pragma unroll
        for (int i = 0; i < 16; i++) {
            const float p = __expf(b2f(*(const short*)(const void*)(Ks + i * 64 + kk)));
            psum += p;
            float vv[16];
            ld8(Vs + i * 64 + vg * 16, vv);
            ld8(Vs + i * 64 + vg * 16 + 8, vv + 8);
#pragma unroll
            for (int j = 0; j < 16; j++) acc[j] += p * vv[j];
        }
    }
    const int bh4 = (b * 8 + hh) * 4 + sp;
    float* o = ktvp + (size_t)bh4 * 4096 + kk * 64 + vg * 16;
#pragma unroll
    for (int j = 0; j < 16; j++) o[j] = acc[j];
    if (vg == 0) csp[bh4 * 64 + kk] = psum;
}

// ---------------- ktv reduce ----------
__global__ __launch_bounds__(256) void ktv_red_k(const float* __restrict__ ktvp,
                                                 const float* __restrict__ csp,
                                                 float* __restrict__ ktv)
{
    const int bh = blockIdx.x;
    const int t = threadIdx.x;
#pragma unroll
    for (int i = 0; i < 16; i++) {
        const int e = t + 256 * i;
        const int kk = e >> 6;
        float cs = 0.f, v = 0.f;
#pragma unroll
        for (int sp = 0; sp < 4; sp++) {
            cs += csp[(bh * 4 + sp) * 64 + kk];
            v += ktvp[(size_t)(bh * 4 + sp) * 4096 + e];
        }
        ktv[(size_t)bh * 4096 + e] = v * (0.125f / cs);
    }
}

// ---------------- xs += q @ ktv_scaled + q * vconv  (in place) --------------
__global__ __launch_bounds__(256) void attnout_k(
    float* xs, const bf16* __restrict__ qkv,
    const float* __restrict__ ktv, const bf16* __restrict__ vc)
{
    const int nc = blockIdx.x & 31, hh = (blockIdx.x >> 5) & 7, b = blockIdx.x >> 8;
    __shared__ __align__(16) float kt[64 * 64];
    __shared__ __align__(16) bf16 qs[32 * 64];
    const int t = threadIdx.x;
    const float4* ksrc = (const float4*)(ktv + (size_t)(b * 8 + hh) * 4096);
    for (int u = t; u < 1024; u += 256) ((float4*)kt)[u] = ksrc[u];
    const int n0 = nc * 32;
    {
        const int r = t >> 3, cc = (t & 7) * 8;
        *(uint4*)(qs + r * 64 + cc) =
            *(const uint4*)(qkv + ((size_t)b * 1024 + n0 + r) * 1536 + hh * 64 + cc);
    }
    __syncthreads();
    const int dv = t & 63, rb = (t >> 6) * 8;
    for (int r = rb; r < rb + 8; r++) {
        float fa = 0.f;
#pragma unroll
        for (int kk = 0; kk < 64; kk++)
            fa += b2f(*(const short*)(const void*)(qs + r * 64 + kk)) * kt[kk * 64 + dv];
        const size_t idx = ((size_t)b * 1024 + n0 + r) * 512 + hh * 64 + dv;
        const float qv = b2f(*(const short*)(const void*)(qs + r * 64 + dv));
        xs[idx] = xs[idx] + fa + qv * __bfloat162float(vc[idx]);
    }
}

// ---------------- workspace layout (bytes) ----------------------------------
static constexpr int    BC       = 8;
static constexpr int    NCHUNK   = 4;
static constexpr size_t OFF_WQ   = 0;
static constexpr size_t OFF_W1   = 1572864;
static constexpr size_t OFF_W2   = 3670016;
static constexpr size_t OFF_CUR  = 5767168;
static constexpr size_t OFF_QKV  = 14155776;
static constexpr size_t OFF_KTVP = 39321600;
static constexpr size_t OFF_CSP  = 43515904;
static constexpr size_t OFF_KTV  = 43581440;
static constexpr size_t OFF_VC   = 44630016;
static constexpr size_t OFF_HG   = 14155776;   // over dead qkv region
static constexpr size_t OFF_H2   = 47710208;   // over dead vc tail
static constexpr size_t WS_NEED  = 81264640;   // ~77.5MB

extern "C" void kernel_launch(void* const* d_in, const int* in_sizes, int n_in,
                              void* d_out, int out_size, void* d_ws, size_t ws_size,
                              hipStream_t stream)
{
    const float* x     = (const float*)d_in[0];
    const float* cpe_w = (const float*)d_in[1];
    const float* cpe_b = (const float*)d_in[2];
    const float* ln1_w = (const float*)d_in[3];
    const float* ln1_b = (const float*)d_in[4];
    const float* qkv_w = (const float*)d_in[5];
    const float* crpe_w= (const float*)d_in[6];
    const float* crpe_b= (const float*)d_in[7];
    const float* ln2_w = (const float*)d_in[8];
    const float* ln2_b = (const float*)d_in[9];
    const float* fc1_w = (const float*)d_in[10];
    const float* fc1_b = (const float*)d_in[11];
    const float* dw_w  = (const float*)d_in[12];
    const float* dw_b  = (const float*)d_in[13];
    const float* fc2_w = (const float*)d_in[14];
    const float* fc2_b = (const float*)d_in[15];
    float* spine = (float*)d_out;
    char* ws = (char*)d_ws;

    if (ws_size < WS_NEED) {
        diag_k<<<1, 1, 0, stream>>>(spine, (float)ws_size);
        return;
    }

    bf16*  wq   = (bf16*)(ws + OFF_WQ);
    bf16*  w1   = (bf16*)(ws + OFF_W1);
    bf16*  w2   = (bf16*)(ws + OFF_W2);
    bf16*  cur  = (bf16*)(ws + OFF_CUR);
    bf16*  qkv  = (bf16*)(ws + OFF_QKV);
    float* ktvp = (float*)(ws + OFF_KTVP);
    float* csp  = (float*)(ws + OFF_CSP);
    float* ktv  = (float*)(ws + OFF_KTV);
    bf16*  vc   = (bf16*)(ws + OFF_VC);
    bf16*  hg   = (bf16*)(ws + OFF_HG);
    bf16*  h2   = (bf16*)(ws + OFF_H2);

    // weights -> bf16
    f2bf_k<<<(1536 * 512 / 8 + 255) / 256, 256, 0, stream>>>(qkv_w, wq, 1536 * 512);
    f2bf_k<<<(2048 * 512 / 8 + 255) / 256, 256, 0, stream>>>(fc1_w, w1, 2048 * 512);
    f2bf_k<<<(2048 * 512 / 8 + 255) / 256, 256, 0, stream>>>(fc2_w, w2, 2048 * 512);

    // CPE (full batch, fp32, 64-ch groups): spine = x + dwconv(x) + cpe_b
    conv4_k<float, float, true, 1><<<32 * 8 * 4, 256, 0, stream>>>(x, 512, 0, cpe_w, cpe_b, spine, 512, 3);

    const int Mc = BC * 1024;  // 8192 rows per chunk
    for (int c = 0; c < NCHUNK; c++) {
        float* xs = spine + (size_t)c * Mc * 512;
        ln_k<<<Mc / 4, 256, 0, stream>>>(xs, ln1_w, ln1_b, cur);
        // qkv = cur @ qkv_w^T   (8-phase, grid 32x6)
        gemm8p_k<0, 512><<<dim3(Mc / 256, 6), 512, 0, stream>>>(cur, wq, nullptr, qkv, Mc, 1536);
        ktv_part_k<<<BC * 8 * 4, 256, 0, stream>>>(qkv, ktvp, csp);
        ktv_red_k<<<BC * 8, 256, 0, stream>>>(ktvp, csp, ktv);
        conv4_k<bf16, bf16, false, 2><<<BC * 4 * 4, 256, 0, stream>>>(qkv, 1536, 1024, crpe_w, crpe_b, vc, 512, 2);
        attnout_k<<<BC * 8 * 32, 256, 0, stream>>>(xs, qkv, ktv, vc);
        ln_k<<<Mc / 4, 256, 0, stream>>>(xs, ln2_w, ln2_b, cur);
        // fc1 + gelu   (8-phase, grid 32x8)
        gemm8p_k<1, 512><<<dim3(Mc / 256, 8), 512, 0, stream>>>(cur, w1, fc1_b, hg, Mc, 2048);
        conv4_k<bf16, bf16, true, 2><<<BC * 16 * 4, 256, 0, stream>>>(hg, 2048, 0, dw_w, dw_b, h2, 2048, 4);
        // fc2 (BN=64, grid 32x8)
        gemmfc2_k<<<dim3(Mc / 256, 8), 512, 0, stream>>>(h2, w2, fc2_b, xs, xs, Mc, 512, 2048);
    }
}

// Round 11
// 778.314 us; speedup vs baseline: 1.0785x; 1.0571x over previous
//
#include <hip/hip_runtime.h>
#include <hip/hip_bf16.h>

using bf16 = __hip_bfloat16;
using s16x4 = __attribute__((ext_vector_type(4))) short;
using s16x8 = __attribute__((ext_vector_type(8))) short;
using f32x4 = __attribute__((ext_vector_type(4))) float;

#define DI __device__ __forceinline__

template <int N> DI void wvm() {
    if constexpr (N == 8) asm volatile("s_waitcnt vmcnt(8)" ::: "memory");
    else if constexpr (N == 4) asm volatile("s_waitcnt vmcnt(4)" ::: "memory");
    else if constexpr (N == 2) asm volatile("s_waitcnt vmcnt(2)" ::: "memory");
    else asm volatile("s_waitcnt vmcnt(0)" ::: "memory");
}

DI float b2f(short s) { union { unsigned u; float f; } z; z.u = ((unsigned)(unsigned short)s) << 16; return z.f; }
DI short f2b(float f) { bf16 t = __float2bfloat16(f); return *(short*)&t; }

// fast gelu: tanh form, |err| ~1e-3 absolute, far under threshold
DI float gelu_f(float x) {
    const float t = 0.7978845608f * x * (1.f + 0.044715f * x * x);
    const float e = __expf(2.f * t);
    const float th = 1.f - 2.f / (e + 1.f);
    return 0.5f * x * (1.f + th);
}

DI void ld8(const bf16* p, float* f) {
    s16x8 x = *(const s16x8*)(const void*)p;
#pragma unroll
    for (int c = 0; c < 8; c++) f[c] = b2f(x[c]);
}
DI void ld8(const float* p, float* f) {
    float4 a = *(const float4*)p, b = *(const float4*)(p + 4);
    f[0]=a.x; f[1]=a.y; f[2]=a.z; f[3]=a.w; f[4]=b.x; f[5]=b.y; f[6]=b.z; f[7]=b.w;
}

typedef const __attribute__((address_space(1))) void* gp_t;
typedef __attribute__((address_space(3))) void* lp_t;
DI void gload_lds16(const void* g, void* l) {
    __builtin_amdgcn_global_load_lds((gp_t)g, (lp_t)l, 16, 0, 0);
}

// ---------------- diagnostic ----------------
__global__ void diag_k(float* out, float v) { out[0] = v; }

// ---------------- fp32 -> bf16 weight conversion (8/thread) ----------------
__global__ void f2bf_k(const float* __restrict__ in, bf16* __restrict__ out, int n) {
    int i = (blockIdx.x * 256 + threadIdx.x) * 8;
    if (i >= n) return;
    float f[8];
    ld8(in + i, f);
    s16x8 o;
#pragma unroll
    for (int c = 0; c < 8; c++) o[c] = f2b(f[c]);
    *(s16x8*)(void*)(out + i) = o;
}

// ---------------- depthwise 3x3 conv v4 ----------------
DI void tap10(const float* r, float w0, float w1, float w2, float* acc) {
#pragma unroll
    for (int i = 0; i < 8; i++)
        acc[i] += w0 * r[i] + w1 * r[i + 1] + w2 * r[i + 2];
}

template <typename TI, typename TO, bool RESID, int CPL>
__global__ __launch_bounds__(256) void conv4_k(
    const TI* in, long rs, long coff,
    const float* __restrict__ w, const float* __restrict__ bias,
    TO* out, long ors, int gshift)
{
    constexpr int CH = 64 * CPL;
    constexpr int ECNT = CH / 8;
    __shared__ float buf[2][CH][33];
    const int t = threadIdx.x;
    const int band = blockIdx.x & 3;
    const int cg = (blockIdx.x >> 2) & ((1 << gshift) - 1);
    const int img = blockIdx.x >> (2 + gshift);
    const int y0 = band * 8;

    const int spx = t >> 3;
    const int sce = (t & 7) * ECNT;
    const TI* gsrc = in + ((long)img << 10) * rs + coff + (long)cg * CH + sce;

    const int c = t & 63;
    const int xb = (t >> 6) * 8;

    float wv9[9][CPL], bw[CPL];
#pragma unroll
    for (int p = 0; p < CPL; p++) {
        const int gch = cg * CH + c * CPL + p;
#pragma unroll
        for (int j = 0; j < 9; j++) wv9[j][p] = w[gch * 9 + j];
        bw[p] = bias[gch];
    }

    auto stage = [&](int row) {
        float f[ECNT];
        ld8(gsrc + (long)(row * 32 + spx) * rs, f);
        if constexpr (ECNT == 16) ld8(gsrc + (long)(row * 32 + spx) * rs + 8, f + 8);
        float* d = &buf[row & 1][0][0];
#pragma unroll
        for (int k = 0; k < ECNT; k++) {
            const int ch = sce + k;
            const int rr = (CPL == 2) ? ((ch & 1) * 64 + (ch >> 1)) : ch;
            d[rr * 33 + spx] = f[k];
        }
    };
    auto slice = [&](int row, float r[CPL][10]) {
#pragma unroll
        for (int p = 0; p < CPL; p++) {
            const float* s = &buf[row & 1][c + p * 64][0];
            r[p][0] = (xb == 0) ? 0.f : s[xb - 1];
#pragma unroll
            for (int i = 0; i < 8; i++) r[p][1 + i] = s[xb + i];
            r[p][9] = (xb + 8 >= 32) ? 0.f : s[xb + 8];
        }
    };
    auto zero = [&](float r[CPL][10]) {
#pragma unroll
        for (int p = 0; p < CPL; p++)
#pragma unroll
            for (int i = 0; i < 10; i++) r[p][i] = 0.f;
    };

    float r0[CPL][10], r1[CPL][10], r2[CPL][10];
    if (y0 > 0) stage(y0 - 1);
    __syncthreads();
    if (y0 > 0) slice(y0 - 1, r0); else zero(r0);
    stage(y0);
    __syncthreads();
    slice(y0, r1);

    for (int y = y0; y < y0 + 8; ++y) {
        const int yn = y + 1;
        if (yn <= 31) stage(yn);
        __syncthreads();
        if (yn <= 31) slice(yn, r2); else zero(r2);
        float acc[CPL][8];
#pragma unroll
        for (int p = 0; p < CPL; p++) {
#pragma unroll
            for (int i = 0; i < 8; i++) acc[p][i] = bw[p];
            tap10(r0[p], wv9[0][p], wv9[1][p], wv9[2][p], acc[p]);
            tap10(r1[p], wv9[3][p], wv9[4][p], wv9[5][p], acc[p]);
            tap10(r2[p], wv9[6][p], wv9[7][p], wv9[8][p], acc[p]);
            if (RESID) {
#pragma unroll
                for (int i = 0; i < 8; i++) acc[p][i] += r1[p][i + 1];
            }
        }
        TO* o = out + ((long)(img * 1024 + y * 32 + xb)) * ors + (long)cg * CH + c * CPL;
#pragma unroll
        for (int i = 0; i < 8; i++) {
            if constexpr (CPL == 2 && sizeof(TO) == 2) {
                const unsigned u = (unsigned)(unsigned short)f2b(acc[0][i]) |
                                   ((unsigned)(unsigned short)f2b(acc[1][i]) << 16);
                *(unsigned*)(void*)(o + (long)i * ors) = u;
            } else {
                o[(long)i * ors] = (TO)acc[0][i];
            }
        }
#pragma unroll
        for (int p = 0; p < CPL; p++)
#pragma unroll
            for (int i = 0; i < 10; i++) { r0[p][i] = r1[p][i]; r1[p][i] = r2[p][i]; }
    }
}

// ---------------- LayerNorm over C=512, fp32 in -> bf16 out ----------------
__global__ __launch_bounds__(256) void ln_k(const float* __restrict__ x,
                                            const float* __restrict__ w,
                                            const float* __restrict__ bp,
                                            bf16* __restrict__ out)
{
    const size_t row = blockIdx.x * 4 + (threadIdx.x >> 6);
    const int t = threadIdx.x & 63;
    const float* xr = x + row * 512;
    alignas(16) float v[8];
    *(float4*)&v[0] = *(const float4*)(xr + t * 8);
    *(float4*)&v[4] = *(const float4*)(xr + t * 8 + 4);
    float s = 0.f;
#pragma unroll
    for (int j = 0; j < 8; j++) s += v[j];
#pragma unroll
    for (int mm = 32; mm; mm >>= 1) s += __shfl_xor(s, mm);
    const float mu = s * (1.f / 512.f);
    float q = 0.f;
#pragma unroll
    for (int j = 0; j < 8; j++) { v[j] -= mu; q += v[j] * v[j]; }
#pragma unroll
    for (int mm = 32; mm; mm >>= 1) q += __shfl_xor(q, mm);
    const float rstd = rsqrtf(q * (1.f / 512.f) + 1e-6f);
    alignas(16) float wv[8], bv[8];
    *(float4*)&wv[0] = *(const float4*)(w + t * 8);
    *(float4*)&wv[4] = *(const float4*)(w + t * 8 + 4);
    *(float4*)&bv[0] = *(const float4*)(bp + t * 8);
    *(float4*)&bv[4] = *(const float4*)(bp + t * 8 + 4);
    alignas(16) bf16 o[8];
#pragma unroll
    for (int j = 0; j < 8; j++) o[j] = __float2bfloat16(v[j] * rstd * wv[j] + bv[j]);
    *(uint4*)(out + row * 512 + t * 8) = *(const uint4*)o;
}

// ---------------- 8-phase 256x256 bf16 MFMA GEMM (K compile-time) -----------
// m201-template port: BK=64, 8 waves 2Mx4N, 128KB LDS (2buf x 2half x A,B).
// Per K-tile 4 phases (C-quadrants); per phase: ds_read subtile -> stage one
// half-tile -> barrier -> setprio(1) 16 MFMA setprio(0) -> counted vmcnt -> barrier.
// EPI 0: bf16 out. 1: +bias, gelu, bf16. 2: +bias +resid, fp32 (in-place ok).
template <int EPI, int K>
__global__ __launch_bounds__(512) void gemm8p_k(
    const bf16* __restrict__ A, const bf16* __restrict__ Bw,
    const float* __restrict__ bias, const float* resid,
    bf16* __restrict__ outb, float* outf, int M, int Nn)
{
    constexpr int KT = K / 64;
    __shared__ __align__(16) char lds[131072];
    char* ldsA = lds;
    char* ldsB = lds + 65536;
    const int t = threadIdx.x;
    const int lane = t & 63;
    const int w = t >> 6;                 // wave 0..7
    const int wr = w >> 2, wc = w & 3;    // 2M x 4N
    const int m0 = blockIdx.x * 256;
    const int n0 = blockIdx.y * 256;
    const int lr = lane & 15, lg = lane >> 4;

    f32x4 acc[8][4] = {};

    const int srow = lane >> 3;                 // 0..7
    const int ssrc = 8 * ((lane & 7) ^ srow);   // pre-swizzled k-slot (elems)

    auto SA = [&](int b, int kt, int h) {
#pragma unroll
        for (int j = 0; j < 2; j++) {
            const int lrow0 = j * 64 + w * 8;
            const int R0 = j * 128 + h * 64 + (lrow0 & 63);
            gload_lds16(A + (size_t)(m0 + R0 + srow) * K + kt * 64 + ssrc,
                        ldsA + ((b * 2 + h) * 128 + lrow0) * 128);
        }
    };
    auto SB = [&](int b, int kt, int h) {
#pragma unroll
        for (int j = 0; j < 2; j++) {
            const int lrow0 = j * 64 + w * 8;
            const int R0 = (lrow0 >> 5) * 64 + h * 32 + (lrow0 & 31);
            gload_lds16(Bw + (size_t)(n0 + R0 + srow) * K + kt * 64 + ssrc,
                        ldsB + ((b * 2 + h) * 128 + lrow0) * 128);
        }
    };
    auto RA = [&](int b, int h, int m, int ks) -> s16x8 {
        return *(const s16x8*)(ldsA + ((b * 2 + h) * 128 + wr * 64 + m * 16 + lr) * 128
                               + (((ks * 4 + lg) ^ (lr & 7)) << 4));
    };
    auto RB = [&](int b, int h, int n, int ks) -> s16x8 {
        return *(const s16x8*)(ldsB + ((b * 2 + h) * 128 + wc * 32 + n * 16 + lr) * 128
                               + (((ks * 4 + lg) ^ (lr & 7)) << 4));
    };
    auto MM = [&](int mb, int nb, s16x8 (&a)[2][4], s16x8 (&b)[2][2]) {
#pragma unroll
        for (int ks = 0; ks < 2; ks++)
#pragma unroll
            for (int m = 0; m < 4; m++)
#pragma unroll
                for (int n = 0; n < 2; n++)
                    acc[mb + m][nb + n] =
                        __builtin_amdgcn_mfma_f32_16x16x32_bf16(a[ks][m], b[ks][n], acc[mb + m][nb + n], 0, 0, 0);
    };

    // prologue
    SA(0, 0, 0); SB(0, 0, 0); SA(0, 0, 1); SB(0, 0, 1);
    SA(1, 1, 0); SB(1, 1, 0);
    wvm<8>();
    __builtin_amdgcn_s_barrier();

    s16x8 aLo[2][4], aHi[2][4], bLo[2][2], bHi[2][2];
    auto TILE = [&](int kt) {
        const int b = kt & 1;
        // phase 0: (M-lo x N-lo); stage A-hi(kt+1)
#pragma unroll
        for (int ks = 0; ks < 2; ks++) {
#pragma unroll
            for (int m = 0; m < 4; m++) aLo[ks][m] = RA(b, 0, m, ks);
#pragma unroll
            for (int n = 0; n < 2; n++) bLo[ks][n] = RB(b, 0, n, ks);
        }
        if (kt + 1 < KT) SA(b ^ 1, kt + 1, 1);
        __builtin_amdgcn_s_barrier();
        __builtin_amdgcn_s_setprio(1);
        MM(0, 0, aLo, bLo);
        __builtin_amdgcn_s_setprio(0);
        if (kt + 1 < KT) wvm<8>(); else wvm<2>();
        __builtin_amdgcn_s_barrier();
        // phase 1: (M-hi x N-lo); stage B-hi(kt+1)
#pragma unroll
        for (int ks = 0; ks < 2; ks++)
#pragma unroll
            for (int m = 0; m < 4; m++) aHi[ks][m] = RA(b, 1, m, ks);
        if (kt + 1 < KT) SB(b ^ 1, kt + 1, 1);
        __builtin_amdgcn_s_barrier();
        __builtin_amdgcn_s_setprio(1);
        MM(4, 0, aHi, bLo);
        __builtin_amdgcn_s_setprio(0);
        if (kt + 1 < KT) wvm<8>(); else wvm<0>();
        __builtin_amdgcn_s_barrier();
        // phase 2: (M-hi x N-hi); stage A-lo(kt+2)
#pragma unroll
        for (int ks = 0; ks < 2; ks++)
#pragma unroll
            for (int n = 0; n < 2; n++) bHi[ks][n] = RB(b, 1, n, ks);
        if (kt + 2 < KT) SA(b, kt + 2, 0);
        __builtin_amdgcn_s_barrier();
        __builtin_amdgcn_s_setprio(1);
        MM(4, 2, aHi, bHi);
        __builtin_amdgcn_s_setprio(0);
        __builtin_amdgcn_s_barrier();
        // phase 3: (M-lo x N-hi); stage B-lo(kt+2)
        if (kt + 2 < KT) SB(b, kt + 2, 0);
        __builtin_amdgcn_s_barrier();
        __builtin_amdgcn_s_setprio(1);
        MM(0, 2, aLo, bHi);
        __builtin_amdgcn_s_setprio(0);
        if (kt + 2 < KT) { wvm<8>(); __builtin_amdgcn_s_barrier(); }
        else if (kt + 1 < KT) { wvm<4>(); __builtin_amdgcn_s_barrier(); }
    };

    if constexpr (KT <= 8) {
#pragma unroll
        for (int kt = 0; kt < KT; ++kt) TILE(kt);
    } else {
#pragma unroll 2
        for (int kt = 0; kt < KT; ++kt) TILE(kt);
    }

#pragma unroll
    for (int i = 0; i < 8; i++) {
#pragma unroll
        for (int j = 0; j < 4; j++) {
            const int col = n0 + wc * 64 + j * 16 + lr;
            const float bcol = (EPI > 0) ? bias[col] : 0.f;
#pragma unroll
            for (int r = 0; r < 4; r++) {
                const int row = m0 + wr * 128 + i * 16 + lg * 4 + r;
                float v = acc[i][j][r] + bcol;
                const size_t idx = (size_t)row * Nn + col;
                if (EPI == 2) outf[idx] = v + resid[idx];
                else outb[idx] = __float2bfloat16(EPI == 1 ? gelu_f(v) : v);
            }
        }
    }
}

// ---------------- fc2 GEMM fallback (BN=64, 2-phase) ------------------------
__global__ __launch_bounds__(512) void gemmfc2_k(
    const bf16* __restrict__ A, const bf16* __restrict__ Bw,
    const float* __restrict__ bias, const float* resid, float* outf,
    int M, int Nn, int K)
{
    constexpr int MI = 2, NJ = 4;
    __shared__ __align__(16) short As[2][256 * 64];
    __shared__ __align__(16) short Bs[2][64 * 64];
    const int t = threadIdx.x;
    const int lane = t & 63;
    const int w = t >> 6;
    const int m0 = blockIdx.x * 256;
    const int n0 = blockIdx.y * 64;
    const int lr = lane & 15, lg = lane >> 4;

    f32x4 acc[MI][NJ] = {};

    const int srow = lane >> 3, sslot = lane & 7;
    const int ssrc = 8 * (sslot ^ srow);
    const bf16* Ag[4];
#pragma unroll
    for (int i = 0; i < 4; i++)
        Ag[i] = A + (size_t)(m0 + w * 32 + i * 8 + srow) * K + ssrc;
    const bf16* Bg = Bw + (size_t)(n0 + w * 8 + srow) * K + ssrc;

    auto STAGE = [&](int buf, int kt) {
        const int k0 = kt * 64;
#pragma unroll
        for (int i = 0; i < 4; i++)
            gload_lds16(Ag[i] + k0, (char*)&As[buf][0] + (w * 32 + i * 8) * 128);
        gload_lds16(Bg + k0, (char*)&Bs[buf][0] + (w * 8) * 128);
    };

    auto COMPUTE = [&](int buf) {
#pragma unroll
        for (int ks = 0; ks < 2; ks++) {
            s16x8 aF[MI], bF[NJ];
            const int xo = (ks * 4 + lg) ^ (lr & 7);
#pragma unroll
            for (int i = 0; i < MI; i++) {
                const int row = w * 32 + i * 16 + lr;
                aF[i] = *(const s16x8*)((const char*)&As[buf][0] + row * 128 + xo * 16);
            }
#pragma unroll
            for (int j = 0; j < NJ; j++) {
                const int row = j * 16 + lr;
                bF[j] = *(const s16x8*)((const char*)&Bs[buf][0] + row * 128 + xo * 16);
            }
#pragma unroll
            for (int i = 0; i < MI; i++)
#pragma unroll
                for (int j = 0; j < NJ; j++)
                    acc[i][j] = __builtin_amdgcn_mfma_f32_16x16x32_bf16(aF[i], bF[j], acc[i][j], 0, 0, 0);
        }
    };

    const int KT = K / 64;
    STAGE(0, 0);
    wvm<0>();
    __builtin_amdgcn_s_barrier();
    for (int kt = 0; kt < KT; ++kt) {
        if (kt + 1 < KT) STAGE((kt + 1) & 1, kt + 1);
        COMPUTE(kt & 1);
        wvm<0>();
        __builtin_amdgcn_s_barrier();
    }

#pragma unroll
    for (int i = 0; i < MI; i++) {
#pragma unroll
        for (int j = 0; j < NJ; j++) {
            const int col = n0 + j * 16 + lr;
            const float bcol = bias[col];
#pragma unroll
            for (int r = 0; r < 4; r++) {
                const int row = m0 + w * 32 + i * 16 + lg * 4 + r;
                const size_t idx = (size_t)row * Nn + col;
                outf[idx] = acc[i][j][r] + bcol + resid[idx];
            }
        }
    }
}

// ---------------- ktv partials: no max-subtraction softmax -------------------
__global__ __launch_bounds__(256) void ktv_part_k(const bf16* __restrict__ qkv,
                                                  float* __restrict__ ktvp,
                                                  float* __restrict__ csp)
{
    const int b = blockIdx.x >> 5;
    const int hh = (blockIdx.x >> 2) & 7;
    const int sp = blockIdx.x & 3;
    const bf16* kb = qkv + (size_t)b * 1024 * 1536 + 512 + hh * 64;
    const bf16* vb = kb + 512;
    __shared__ __align__(16) bf16 Ks[16 * 64];
    __shared__ __align__(16) bf16 Vs[16 * 64];
    const int t = threadIdx.x;
    const int kk = t & 63, vg = t >> 6;
    float acc[16] = {};
    float psum = 0.f;
    const int sr = t >> 4, sc = (t & 15) * 4;
    for (int n0 = sp * 256; n0 < sp * 256 + 256; n0 += 16) {
        __syncthreads();
        *(s16x4*)(void*)(Ks + sr * 64 + sc) = *(const s16x4*)(const void*)(kb + (size_t)(n0 + sr) * 1536 + sc);
        *(s16x4*)(void*)(Vs + sr * 64 + sc) = *(const s16x4*)(const void*)(vb + (size_t)(n0 + sr) * 1536 + sc);
        __syncthreads();
#pragma unroll
        for (int i = 0; i < 16; i++) {
            const float p = __expf(b2f(*(const short*)(const void*)(Ks + i * 64 + kk)));
            psum += p;
            float vv[16];
            ld8(Vs + i * 64 + vg * 16, vv);
            ld8(Vs + i * 64 + vg * 16 + 8, vv + 8);
#pragma unroll
            for (int j = 0; j < 16; j++) acc[j] += p * vv[j];
        }
    }
    const int bh4 = (b * 8 + hh) * 4 + sp;
    float* o = ktvp + (size_t)bh4 * 4096 + kk * 64 + vg * 16;
#pragma unroll
    for (int j = 0; j < 16; j++) o[j] = acc[j];
    if (vg == 0) csp[bh4 * 64 + kk] = psum;
}

// ---------------- ktv reduce ----------
__global__ __launch_bounds__(256) void ktv_red_k(const float* __restrict__ ktvp,
                                                 const float* __restrict__ csp,
                                                 float* __restrict__ ktv)
{
    const int bh = blockIdx.x;
    const int t = threadIdx.x;
#pragma unroll
    for (int i = 0; i < 16; i++) {
        const int e = t + 256 * i;
        const int kk = e >> 6;
        float cs = 0.f, v = 0.f;
#pragma unroll
        for (int sp = 0; sp < 4; sp++) {
            cs += csp[(bh * 4 + sp) * 64 + kk];
            v += ktvp[(size_t)(bh * 4 + sp) * 4096 + e];
        }
        ktv[(size_t)bh * 4096 + e] = v * (0.125f / cs);
    }
}

// ---------------- xs += q @ ktv_scaled + q * vconv  (in place) --------------
__global__ __launch_bounds__(256) void attnout_k(
    float* xs, const bf16* __restrict__ qkv,
    const float* __restrict__ ktv, const bf16* __restrict__ vc)
{
    const int nc = blockIdx.x & 31, hh = (blockIdx.x >> 5) & 7, b = blockIdx.x >> 8;
    __shared__ __align__(16) float kt[64 * 64];
    __shared__ __align__(16) bf16 qs[32 * 64];
    const int t = threadIdx.x;
    const float4* ksrc = (const float4*)(ktv + (size_t)(b * 8 + hh) * 4096);
    for (int u = t; u < 1024; u += 256) ((float4*)kt)[u] = ksrc[u];
    const int n0 = nc * 32;
    {
        const int r = t >> 3, cc = (t & 7) * 8;
        *(uint4*)(qs + r * 64 + cc) =
            *(const uint4*)(qkv + ((size_t)b * 1024 + n0 + r) * 1536 + hh * 64 + cc);
    }
    __syncthreads();
    const int dv = t & 63, rb = (t >> 6) * 8;
    for (int r = rb; r < rb + 8; r++) {
        float fa = 0.f;
#pragma unroll
        for (int kk = 0; kk < 64; kk++)
            fa += b2f(*(const short*)(const void*)(qs + r * 64 + kk)) * kt[kk * 64 + dv];
        const size_t idx = ((size_t)b * 1024 + n0 + r) * 512 + hh * 64 + dv;
        const float qv = b2f(*(const short*)(const void*)(qs + r * 64 + dv));
        xs[idx] = xs[idx] + fa + qv * __bfloat162float(vc[idx]);
    }
}

// ---------------- workspace layout (bytes) ----------------------------------
static constexpr int    BC       = 8;
static constexpr int    NCHUNK   = 4;
static constexpr size_t OFF_WQ   = 0;
static constexpr size_t OFF_W1   = 1572864;
static constexpr size_t OFF_W2   = 3670016;
static constexpr size_t OFF_CUR  = 5767168;
static constexpr size_t OFF_QKV  = 14155776;
static constexpr size_t OFF_KTVP = 39321600;
static constexpr size_t OFF_CSP  = 43515904;
static constexpr size_t OFF_KTV  = 43581440;
static constexpr size_t OFF_VC   = 44630016;
static constexpr size_t OFF_HG   = 14155776;   // over dead qkv region
static constexpr size_t OFF_H2   = 47710208;   // small mode per-chunk (32MB)
static constexpr size_t WS_NEED  = 81264640;   // ~77.5MB
static constexpr size_t OFF_H2XL = 81264640;   // XL: full-batch h2, 128MB
static constexpr size_t WS_XL    = 215482368;  // ~205.5MB

extern "C" void kernel_launch(void* const* d_in, const int* in_sizes, int n_in,
                              void* d_out, int out_size, void* d_ws, size_t ws_size,
                              hipStream_t stream)
{
    const float* x     = (const float*)d_in[0];
    const float* cpe_w = (const float*)d_in[1];
    const float* cpe_b = (const float*)d_in[2];
    const float* ln1_w = (const float*)d_in[3];
    const float* ln1_b = (const float*)d_in[4];
    const float* qkv_w = (const float*)d_in[5];
    const float* crpe_w= (const float*)d_in[6];
    const float* crpe_b= (const float*)d_in[7];
    const float* ln2_w = (const float*)d_in[8];
    const float* ln2_b = (const float*)d_in[9];
    const float* fc1_w = (const float*)d_in[10];
    const float* fc1_b = (const float*)d_in[11];
    const float* dw_w  = (const float*)d_in[12];
    const float* dw_b  = (const float*)d_in[13];
    const float* fc2_w = (const float*)d_in[14];
    const float* fc2_b = (const float*)d_in[15];
    float* spine = (float*)d_out;
    char* ws = (char*)d_ws;

    if (ws_size < WS_NEED) {
        diag_k<<<1, 1, 0, stream>>>(spine, (float)ws_size);
        return;
    }
    const bool xl = ws_size >= WS_XL;

    bf16*  wq   = (bf16*)(ws + OFF_WQ);
    bf16*  w1   = (bf16*)(ws + OFF_W1);
    bf16*  w2   = (bf16*)(ws + OFF_W2);
    bf16*  cur  = (bf16*)(ws + OFF_CUR);
    bf16*  qkv  = (bf16*)(ws + OFF_QKV);
    float* ktvp = (float*)(ws + OFF_KTVP);
    float* csp  = (float*)(ws + OFF_CSP);
    float* ktv  = (float*)(ws + OFF_KTV);
    bf16*  vc   = (bf16*)(ws + OFF_VC);
    bf16*  hg   = (bf16*)(ws + OFF_HG);
    bf16*  h2   = (bf16*)(ws + OFF_H2);
    bf16*  h2xl = (bf16*)(ws + OFF_H2XL);

    // weights -> bf16
    f2bf_k<<<(1536 * 512 / 8 + 255) / 256, 256, 0, stream>>>(qkv_w, wq, 1536 * 512);
    f2bf_k<<<(2048 * 512 / 8 + 255) / 256, 256, 0, stream>>>(fc1_w, w1, 2048 * 512);
    f2bf_k<<<(2048 * 512 / 8 + 255) / 256, 256, 0, stream>>>(fc2_w, w2, 2048 * 512);

    // CPE (full batch, fp32, 64-ch groups): spine = x + dwconv(x) + cpe_b
    conv4_k<float, float, true, 1><<<32 * 8 * 4, 256, 0, stream>>>(x, 512, 0, cpe_w, cpe_b, spine, 512, 3);

    const int Mc = BC * 1024;  // 8192 rows per chunk
    for (int c = 0; c < NCHUNK; c++) {
        float* xs = spine + (size_t)c * Mc * 512;
        bf16* h2c = xl ? (h2xl + (size_t)c * Mc * 2048) : h2;
        ln_k<<<Mc / 4, 256, 0, stream>>>(xs, ln1_w, ln1_b, cur);
        gemm8p_k<0, 512><<<dim3(Mc / 256, 6), 512, 0, stream>>>(cur, wq, nullptr, nullptr, qkv, nullptr, Mc, 1536);
        ktv_part_k<<<BC * 8 * 4, 256, 0, stream>>>(qkv, ktvp, csp);
        ktv_red_k<<<BC * 8, 256, 0, stream>>>(ktvp, csp, ktv);
        conv4_k<bf16, bf16, false, 2><<<BC * 4 * 4, 256, 0, stream>>>(qkv, 1536, 1024, crpe_w, crpe_b, vc, 512, 2);
        attnout_k<<<BC * 8 * 32, 256, 0, stream>>>(xs, qkv, ktv, vc);
        ln_k<<<Mc / 4, 256, 0, stream>>>(xs, ln2_w, ln2_b, cur);
        gemm8p_k<1, 512><<<dim3(Mc / 256, 8), 512, 0, stream>>>(cur, w1, fc1_b, nullptr, hg, nullptr, Mc, 2048);
        conv4_k<bf16, bf16, true, 2><<<BC * 16 * 4, 256, 0, stream>>>(hg, 2048, 0, dw_w, dw_b, h2c, 2048, 4);
        if (!xl) {
            gemmfc2_k<<<dim3(Mc / 256, 8), 512, 0, stream>>>(h2, w2, fc2_b, xs, xs, Mc, 512, 2048);
        }
    }
    if (xl) {
        // fc2 full-batch: M=32768, N=512 -> grid (128,2) = 256 blocks, 8-phase
        gemm8p_k<2, 2048><<<dim3(128, 2), 512, 0, stream>>>(h2xl, w2, fc2_b, spine, nullptr, spine, 32768, 512);
    }
}

// Round 12
// 639.251 us; speedup vs baseline: 1.3131x; 1.2175x over previous
//
#include <hip/hip_runtime.h>
#include <hip/hip_bf16.h>

using bf16 = __hip_bfloat16;
using s16x4 = __attribute__((ext_vector_type(4))) short;
using s16x8 = __attribute__((ext_vector_type(8))) short;
using f32x4 = __attribute__((ext_vector_type(4))) float;

#define DI __device__ __forceinline__

template <int N> DI void wvm() {
    if constexpr (N == 8) asm volatile("s_waitcnt vmcnt(8)" ::: "memory");
    else if constexpr (N == 4) asm volatile("s_waitcnt vmcnt(4)" ::: "memory");
    else if constexpr (N == 2) asm volatile("s_waitcnt vmcnt(2)" ::: "memory");
    else asm volatile("s_waitcnt vmcnt(0)" ::: "memory");
}

DI float b2f(short s) { union { unsigned u; float f; } z; z.u = ((unsigned)(unsigned short)s) << 16; return z.f; }
DI short f2b(float f) { bf16 t = __float2bfloat16(f); return *(short*)&t; }

// fast gelu: tanh form, |err| ~1e-3 absolute, far under threshold
DI float gelu_f(float x) {
    const float t = 0.7978845608f * x * (1.f + 0.044715f * x * x);
    const float e = __expf(2.f * t);
    const float th = 1.f - 2.f / (e + 1.f);
    return 0.5f * x * (1.f + th);
}

DI void ld8(const bf16* p, float* f) {
    s16x8 x = *(const s16x8*)(const void*)p;
#pragma unroll
    for (int c = 0; c < 8; c++) f[c] = b2f(x[c]);
}
DI void ld8(const float* p, float* f) {
    float4 a = *(const float4*)p, b = *(const float4*)(p + 4);
    f[0]=a.x; f[1]=a.y; f[2]=a.z; f[3]=a.w; f[4]=b.x; f[5]=b.y; f[6]=b.z; f[7]=b.w;
}

typedef const __attribute__((address_space(1))) void* gp_t;
typedef __attribute__((address_space(3))) void* lp_t;
DI void gload_lds16(const void* g, void* l) {
    __builtin_amdgcn_global_load_lds((gp_t)g, (lp_t)l, 16, 0, 0);
}

// ---------------- diagnostic ----------------
__global__ void diag_k(float* out, float v) { out[0] = v; }

// ---------------- fp32 -> bf16 weight conversion (8/thread) ----------------
__global__ void f2bf_k(const float* __restrict__ in, bf16* __restrict__ out, int n) {
    int i = (blockIdx.x * 256 + threadIdx.x) * 8;
    if (i >= n) return;
    float f[8];
    ld8(in + i, f);
    s16x8 o;
#pragma unroll
    for (int c = 0; c < 8; c++) o[c] = f2b(f[c]);
    *(s16x8*)(void*)(out + i) = o;
}

// w2 [512,2048] -> half-major bf16 [2][512][1024]
__global__ void f2bf_w2_k(const float* __restrict__ in, bf16* __restrict__ out) {
    const int i = (blockIdx.x * 256 + threadIdx.x) * 8;   // over 512*2048
    const int n = i >> 11, c = i & 2047;
    const int h = c >> 10, k = c & 1023;
    float f[8];
    ld8(in + i, f);
    s16x8 o;
#pragma unroll
    for (int e = 0; e < 8; e++) o[e] = f2b(f[e]);
    *(s16x8*)(void*)(out + (size_t)h * 524288 + n * 1024 + k) = o;
}

// ---------------- depthwise 3x3 conv v4 ----------------
DI void tap10(const float* r, float w0, float w1, float w2, float* acc) {
#pragma unroll
    for (int i = 0; i < 8; i++)
        acc[i] += w0 * r[i] + w1 * r[i + 1] + w2 * r[i + 2];
}

template <typename TI, typename TO, bool RESID, int CPL>
__global__ __launch_bounds__(256) void conv4_k(
    const TI* in, long rs, long coff,
    const float* __restrict__ w, const float* __restrict__ bias,
    TO* out, long ors, int gshift)
{
    constexpr int CH = 64 * CPL;
    constexpr int ECNT = CH / 8;
    __shared__ float buf[2][CH][33];
    const int t = threadIdx.x;
    const int band = blockIdx.x & 3;
    const int cg = (blockIdx.x >> 2) & ((1 << gshift) - 1);
    const int img = blockIdx.x >> (2 + gshift);
    const int y0 = band * 8;

    const int spx = t >> 3;
    const int sce = (t & 7) * ECNT;
    const TI* gsrc = in + ((long)img << 10) * rs + coff + (long)cg * CH + sce;

    const int c = t & 63;
    const int xb = (t >> 6) * 8;

    float wv9[9][CPL], bw[CPL];
#pragma unroll
    for (int p = 0; p < CPL; p++) {
        const int gch = cg * CH + c * CPL + p;
#pragma unroll
        for (int j = 0; j < 9; j++) wv9[j][p] = w[gch * 9 + j];
        bw[p] = bias[gch];
    }

    auto stage = [&](int row) {
        float f[ECNT];
        ld8(gsrc + (long)(row * 32 + spx) * rs, f);
        if constexpr (ECNT == 16) ld8(gsrc + (long)(row * 32 + spx) * rs + 8, f + 8);
        float* d = &buf[row & 1][0][0];
#pragma unroll
        for (int k = 0; k < ECNT; k++) {
            const int ch = sce + k;
            const int rr = (CPL == 2) ? ((ch & 1) * 64 + (ch >> 1)) : ch;
            d[rr * 33 + spx] = f[k];
        }
    };
    auto slice = [&](int row, float r[CPL][10]) {
#pragma unroll
        for (int p = 0; p < CPL; p++) {
            const float* s = &buf[row & 1][c + p * 64][0];
            r[p][0] = (xb == 0) ? 0.f : s[xb - 1];
#pragma unroll
            for (int i = 0; i < 8; i++) r[p][1 + i] = s[xb + i];
            r[p][9] = (xb + 8 >= 32) ? 0.f : s[xb + 8];
        }
    };
    auto zero = [&](float r[CPL][10]) {
#pragma unroll
        for (int p = 0; p < CPL; p++)
#pragma unroll
            for (int i = 0; i < 10; i++) r[p][i] = 0.f;
    };

    float r0[CPL][10], r1[CPL][10], r2[CPL][10];
    if (y0 > 0) stage(y0 - 1);
    __syncthreads();
    if (y0 > 0) slice(y0 - 1, r0); else zero(r0);
    stage(y0);
    __syncthreads();
    slice(y0, r1);

    for (int y = y0; y < y0 + 8; ++y) {
        const int yn = y + 1;
        if (yn <= 31) stage(yn);
        __syncthreads();
        if (yn <= 31) slice(yn, r2); else zero(r2);
        float acc[CPL][8];
#pragma unroll
        for (int p = 0; p < CPL; p++) {
#pragma unroll
            for (int i = 0; i < 8; i++) acc[p][i] = bw[p];
            tap10(r0[p], wv9[0][p], wv9[1][p], wv9[2][p], acc[p]);
            tap10(r1[p], wv9[3][p], wv9[4][p], wv9[5][p], acc[p]);
            tap10(r2[p], wv9[6][p], wv9[7][p], wv9[8][p], acc[p]);
            if (RESID) {
#pragma unroll
                for (int i = 0; i < 8; i++) acc[p][i] += r1[p][i + 1];
            }
        }
        TO* o = out + ((long)(img * 1024 + y * 32 + xb)) * ors + (long)cg * CH + c * CPL;
#pragma unroll
        for (int i = 0; i < 8; i++) {
            if constexpr (CPL == 2 && sizeof(TO) == 2) {
                const unsigned u = (unsigned)(unsigned short)f2b(acc[0][i]) |
                                   ((unsigned)(unsigned short)f2b(acc[1][i]) << 16);
                *(unsigned*)(void*)(o + (long)i * ors) = u;
            } else {
                o[(long)i * ors] = (TO)acc[0][i];
            }
        }
#pragma unroll
        for (int p = 0; p < CPL; p++)
#pragma unroll
            for (int i = 0; i < 10; i++) { r0[p][i] = r1[p][i]; r1[p][i] = r2[p][i]; }
    }
}

// ---------------- LayerNorm over C=512, fp32 in -> bf16 out ----------------
__global__ __launch_bounds__(256) void ln_k(const float* __restrict__ x,
                                            const float* __restrict__ w,
                                            const float* __restrict__ bp,
                                            bf16* __restrict__ out)
{
    const size_t row = blockIdx.x * 4 + (threadIdx.x >> 6);
    const int t = threadIdx.x & 63;
    const float* xr = x + row * 512;
    alignas(16) float v[8];
    *(float4*)&v[0] = *(const float4*)(xr + t * 8);
    *(float4*)&v[4] = *(const float4*)(xr + t * 8 + 4);
    float s = 0.f;
#pragma unroll
    for (int j = 0; j < 8; j++) s += v[j];
#pragma unroll
    for (int mm = 32; mm; mm >>= 1) s += __shfl_xor(s, mm);
    const float mu = s * (1.f / 512.f);
    float q = 0.f;
#pragma unroll
    for (int j = 0; j < 8; j++) { v[j] -= mu; q += v[j] * v[j]; }
#pragma unroll
    for (int mm = 32; mm; mm >>= 1) q += __shfl_xor(q, mm);
    const float rstd = rsqrtf(q * (1.f / 512.f) + 1e-6f);
    alignas(16) float wv[8], bv[8];
    *(float4*)&wv[0] = *(const float4*)(w + t * 8);
    *(float4*)&wv[4] = *(const float4*)(w + t * 8 + 4);
    *(float4*)&bv[0] = *(const float4*)(bp + t * 8);
    *(float4*)&bv[4] = *(const float4*)(bp + t * 8 + 4);
    alignas(16) bf16 o[8];
#pragma unroll
    for (int j = 0; j < 8; j++) o[j] = __float2bfloat16(v[j] * rstd * wv[j] + bv[j]);
    *(uint4*)(out + row * 512 + t * 8) = *(const uint4*)o;
}

// ---------------- 8-phase 256x256 bf16 MFMA GEMM (K compile-time) -----------
// BK=64, 8 waves 2Mx4N, 128KB LDS. EPI 0: bf16. 1: +bias gelu bf16.
// 2: +bias +resid fp32. 3: +resid fp32 (accumulate pass, no bias).
template <int EPI, int K>
__global__ __launch_bounds__(512) void gemm8p_k(
    const bf16* __restrict__ A, const bf16* __restrict__ Bw,
    const float* __restrict__ bias, const float* resid,
    bf16* __restrict__ outb, float* outf, int M, int Nn)
{
    constexpr int KT = K / 64;
    __shared__ __align__(16) char lds[131072];
    char* ldsA = lds;
    char* ldsB = lds + 65536;
    const int t = threadIdx.x;
    const int lane = t & 63;
    const int w = t >> 6;
    const int wr = w >> 2, wc = w & 3;
    const int m0 = blockIdx.x * 256;
    const int n0 = blockIdx.y * 256;
    const int lr = lane & 15, lg = lane >> 4;

    f32x4 acc[8][4] = {};

    const int srow = lane >> 3;
    const int ssrc = 8 * ((lane & 7) ^ srow);

    auto SA = [&](int b, int kt, int h) {
#pragma unroll
        for (int j = 0; j < 2; j++) {
            const int lrow0 = j * 64 + w * 8;
            const int R0 = j * 128 + h * 64 + (lrow0 & 63);
            gload_lds16(A + (size_t)(m0 + R0 + srow) * K + kt * 64 + ssrc,
                        ldsA + ((b * 2 + h) * 128 + lrow0) * 128);
        }
    };
    auto SB = [&](int b, int kt, int h) {
#pragma unroll
        for (int j = 0; j < 2; j++) {
            const int lrow0 = j * 64 + w * 8;
            const int R0 = (lrow0 >> 5) * 64 + h * 32 + (lrow0 & 31);
            gload_lds16(Bw + (size_t)(n0 + R0 + srow) * K + kt * 64 + ssrc,
                        ldsB + ((b * 2 + h) * 128 + lrow0) * 128);
        }
    };
    auto RA = [&](int b, int h, int m, int ks) -> s16x8 {
        return *(const s16x8*)(ldsA + ((b * 2 + h) * 128 + wr * 64 + m * 16 + lr) * 128
                               + (((ks * 4 + lg) ^ (lr & 7)) << 4));
    };
    auto RB = [&](int b, int h, int n, int ks) -> s16x8 {
        return *(const s16x8*)(ldsB + ((b * 2 + h) * 128 + wc * 32 + n * 16 + lr) * 128
                               + (((ks * 4 + lg) ^ (lr & 7)) << 4));
    };
    auto MM = [&](int mb, int nb, s16x8 (&a)[2][4], s16x8 (&b)[2][2]) {
#pragma unroll
        for (int ks = 0; ks < 2; ks++)
#pragma unroll
            for (int m = 0; m < 4; m++)
#pragma unroll
                for (int n = 0; n < 2; n++)
                    acc[mb + m][nb + n] =
                        __builtin_amdgcn_mfma_f32_16x16x32_bf16(a[ks][m], b[ks][n], acc[mb + m][nb + n], 0, 0, 0);
    };

    SA(0, 0, 0); SB(0, 0, 0); SA(0, 0, 1); SB(0, 0, 1);
    SA(1, 1, 0); SB(1, 1, 0);
    wvm<8>();
    __builtin_amdgcn_s_barrier();

    s16x8 aLo[2][4], aHi[2][4], bLo[2][2], bHi[2][2];
    auto TILE = [&](int kt) {
        const int b = kt & 1;
        // phase 0: (M-lo x N-lo); stage A-hi(kt+1)
#pragma unroll
        for (int ks = 0; ks < 2; ks++) {
#pragma unroll
            for (int m = 0; m < 4; m++) aLo[ks][m] = RA(b, 0, m, ks);
#pragma unroll
            for (int n = 0; n < 2; n++) bLo[ks][n] = RB(b, 0, n, ks);
        }
        if (kt + 1 < KT) SA(b ^ 1, kt + 1, 1);
        __builtin_amdgcn_s_barrier();
        __builtin_amdgcn_s_setprio(1);
        MM(0, 0, aLo, bLo);
        __builtin_amdgcn_s_setprio(0);
        if (kt + 1 < KT) wvm<8>(); else wvm<2>();
        __builtin_amdgcn_s_barrier();
        // phase 1: (M-hi x N-lo); stage B-hi(kt+1)
#pragma unroll
        for (int ks = 0; ks < 2; ks++)
#pragma unroll
            for (int m = 0; m < 4; m++) aHi[ks][m] = RA(b, 1, m, ks);
        if (kt + 1 < KT) SB(b ^ 1, kt + 1, 1);
        __builtin_amdgcn_s_barrier();
        __builtin_amdgcn_s_setprio(1);
        MM(4, 0, aHi, bLo);
        __builtin_amdgcn_s_setprio(0);
        if (kt + 1 < KT) wvm<8>(); else wvm<0>();
        __builtin_amdgcn_s_barrier();
        // phase 2: (M-hi x N-hi); stage A-lo(kt+2)
#pragma unroll
        for (int ks = 0; ks < 2; ks++)
#pragma unroll
            for (int n = 0; n < 2; n++) bHi[ks][n] = RB(b, 1, n, ks);
        if (kt + 2 < KT) SA(b, kt + 2, 0);
        __builtin_amdgcn_s_barrier();
        __builtin_amdgcn_s_setprio(1);
        MM(4, 2, aHi, bHi);
        __builtin_amdgcn_s_setprio(0);
        __builtin_amdgcn_s_barrier();
        // phase 3: (M-lo x N-hi); stage B-lo(kt+2)
        if (kt + 2 < KT) SB(b, kt + 2, 0);
        __builtin_amdgcn_s_barrier();
        __builtin_amdgcn_s_setprio(1);
        MM(0, 2, aLo, bHi);
        __builtin_amdgcn_s_setprio(0);
        if (kt + 2 < KT) { wvm<8>(); __builtin_amdgcn_s_barrier(); }
        else if (kt + 1 < KT) { wvm<4>(); __builtin_amdgcn_s_barrier(); }
    };

    if constexpr (KT <= 8) {
#pragma unroll
        for (int kt = 0; kt < KT; ++kt) TILE(kt);
    } else {
#pragma unroll 2
        for (int kt = 0; kt < KT; ++kt) TILE(kt);
    }

#pragma unroll
    for (int i = 0; i < 8; i++) {
#pragma unroll
        for (int j = 0; j < 4; j++) {
            const int col = n0 + wc * 64 + j * 16 + lr;
            float bcol = 0.f;
            if constexpr (EPI == 1 || EPI == 2) bcol = bias[col];
#pragma unroll
            for (int r = 0; r < 4; r++) {
                const int row = m0 + wr * 128 + i * 16 + lg * 4 + r;
                float v = acc[i][j][r] + bcol;
                const size_t idx = (size_t)row * Nn + col;
                if (EPI >= 2) outf[idx] = v + resid[idx];
                else outb[idx] = __float2bfloat16(EPI == 1 ? gelu_f(v) : v);
            }
        }
    }
}

// ---------------- ktv partials: no max-subtraction softmax -------------------
__global__ __launch_bounds__(256) void ktv_part_k(const bf16* __restrict__ qkv,
                                                  float* __restrict__ ktvp,
                                                  float* __restrict__ csp)
{
    const int b = blockIdx.x >> 5;
    const int hh = (blockIdx.x >> 2) & 7;
    const int sp = blockIdx.x & 3;
    const bf16* kb = qkv + (size_t)b * 1024 * 1536 + 512 + hh * 64;
    const bf16* vb = kb + 512;
    __shared__ __align__(16) bf16 Ks[16 * 64];
    __shared__ __align__(16) bf16 Vs[16 * 64];
    const int t = threadIdx.x;
    const int kk = t & 63, vg = t >> 6;
    float acc[16] = {};
    float psum = 0.f;
    const int sr = t >> 4, sc = (t & 15) * 4;
    for (int n0 = sp * 256; n0 < sp * 256 + 256; n0 += 16) {
        __syncthreads();
        *(s16x4*)(void*)(Ks + sr * 64 + sc) = *(const s16x4*)(const void*)(kb + (size_t)(n0 + sr) * 1536 + sc);
        *(s16x4*)(void*)(Vs + sr * 64 + sc) = *(const s16x4*)(const void*)(vb + (size_t)(n0 + sr) * 1536 + sc);
        __syncthreads();
#pragma unroll
        for (int i = 0; i < 16; i++) {
            const float p = __expf(b2f(*(const short*)(const void*)(Ks + i * 64 + kk)));
            psum += p;
            float vv[16];
            ld8(Vs + i * 64 + vg * 16, vv);
            ld8(Vs + i * 64 + vg * 16 + 8, vv + 8);
#pragma unroll
            for (int j = 0; j < 16; j++) acc[j] += p * vv[j];
        }
    }
    const int bh4 = (b * 8 + hh) * 4 + sp;
    float* o = ktvp + (size_t)bh4 * 4096 + kk * 64 + vg * 16;
#pragma unroll
    for (int j = 0; j < 16; j++) o[j] = acc[j];
    if (vg == 0) csp[bh4 * 64 + kk] = psum;
}

// ---------------- ktv reduce ----------
__global__ __launch_bounds__(256) void ktv_red_k(const float* __restrict__ ktvp,
                                                 const float* __restrict__ csp,
                                                 float* __restrict__ ktv)
{
    const int bh = blockIdx.x;
    const int t = threadIdx.x;
#pragma unroll
    for (int i = 0; i < 16; i++) {
        const int e = t + 256 * i;
        const int kk = e >> 6;
        float cs = 0.f, v = 0.f;
#pragma unroll
        for (int sp = 0; sp < 4; sp++) {
            cs += csp[(bh * 4 + sp) * 64 + kk];
            v += ktvp[(size_t)(bh * 4 + sp) * 4096 + e];
        }
        ktv[(size_t)bh * 4096 + e] = v * (0.125f / cs);
    }
}

// ---------------- xs += q @ ktv_scaled + q * vconv  (in place) --------------
__global__ __launch_bounds__(256) void attnout_k(
    float* xs, const bf16* __restrict__ qkv,
    const float* __restrict__ ktv, const bf16* __restrict__ vc)
{
    const int nc = blockIdx.x & 31, hh = (blockIdx.x >> 5) & 7, b = blockIdx.x >> 8;
    __shared__ __align__(16) float kt[64 * 64];
    __shared__ __align__(16) bf16 qs[32 * 64];
    const int t = threadIdx.x;
    const float4* ksrc = (const float4*)(ktv + (size_t)(b * 8 + hh) * 4096);
    for (int u = t; u < 1024; u += 256) ((float4*)kt)[u] = ksrc[u];
    const int n0 = nc * 32;
    {
        const int r = t >> 3, cc = (t & 7) * 8;
        *(uint4*)(qs + r * 64 + cc) =
            *(const uint4*)(qkv + ((size_t)b * 1024 + n0 + r) * 1536 + hh * 64 + cc);
    }
    __syncthreads();
    const int dv = t & 63, rb = (t >> 6) * 8;
    for (int r = rb; r < rb + 8; r++) {
        float fa = 0.f;
#pragma unroll
        for (int kk = 0; kk < 64; kk++)
            fa += b2f(*(const short*)(const void*)(qs + r * 64 + kk)) * kt[kk * 64 + dv];
        const size_t idx = ((size_t)b * 1024 + n0 + r) * 512 + hh * 64 + dv;
        const float qv = b2f(*(const short*)(const void*)(qs + r * 64 + dv));
        xs[idx] = xs[idx] + fa + qv * __bfloat162float(vc[idx]);
    }
}

// ---------------- workspace layout (bytes), full-batch ----------------------
static constexpr size_t OFF_WQ   = 0;           // 1.5MB
static constexpr size_t OFF_W1   = 1572864;     // 2MB
static constexpr size_t OFF_W2   = 3670016;     // 2MB (half-major repack)
static constexpr size_t OFF_CUR  = 5767168;     // bf16 (32,1024,512) 32MB
static constexpr size_t OFF_QKV  = 39321600;    // bf16 (32,1024,1536) 96MB
static constexpr size_t OFF_VC   = 139984896;   // bf16 (32,1024,512) 32MB
static constexpr size_t OFF_KTVP = 173539328;   // fp32 1024x4096 16MB
static constexpr size_t OFF_CSP  = 190316544;   // 256KB
static constexpr size_t OFF_KTV  = 190578688;   // 4MB
static constexpr size_t WS_NEED  = 194772992;   // ~185.7MB (ws >= 215.5MB confirmed)
static constexpr size_t OFF_HG   = OFF_QKV;             // 64MB over dead qkv[0:64]
static constexpr size_t OFF_H2   = OFF_QKV + 67108864;  // 64MB over qkv[64:96]+vc

extern "C" void kernel_launch(void* const* d_in, const int* in_sizes, int n_in,
                              void* d_out, int out_size, void* d_ws, size_t ws_size,
                              hipStream_t stream)
{
    const float* x     = (const float*)d_in[0];
    const float* cpe_w = (const float*)d_in[1];
    const float* cpe_b = (const float*)d_in[2];
    const float* ln1_w = (const float*)d_in[3];
    const float* ln1_b = (const float*)d_in[4];
    const float* qkv_w = (const float*)d_in[5];
    const float* crpe_w= (const float*)d_in[6];
    const float* crpe_b= (const float*)d_in[7];
    const float* ln2_w = (const float*)d_in[8];
    const float* ln2_b = (const float*)d_in[9];
    const float* fc1_w = (const float*)d_in[10];
    const float* fc1_b = (const float*)d_in[11];
    const float* dw_w  = (const float*)d_in[12];
    const float* dw_b  = (const float*)d_in[13];
    const float* fc2_w = (const float*)d_in[14];
    const float* fc2_b = (const float*)d_in[15];
    float* spine = (float*)d_out;
    char* ws = (char*)d_ws;

    if (ws_size < WS_NEED) {
        diag_k<<<1, 1, 0, stream>>>(spine, (float)ws_size);
        return;
    }

    bf16*  wq   = (bf16*)(ws + OFF_WQ);
    bf16*  w1   = (bf16*)(ws + OFF_W1);
    bf16*  w2r  = (bf16*)(ws + OFF_W2);
    bf16*  cur  = (bf16*)(ws + OFF_CUR);
    bf16*  qkv  = (bf16*)(ws + OFF_QKV);
    bf16*  vc   = (bf16*)(ws + OFF_VC);
    float* ktvp = (float*)(ws + OFF_KTVP);
    float* csp  = (float*)(ws + OFF_CSP);
    float* ktv  = (float*)(ws + OFF_KTV);
    bf16*  hg   = (bf16*)(ws + OFF_HG);
    bf16*  h2   = (bf16*)(ws + OFF_H2);

    // weights -> bf16 (w2 repacked half-major)
    f2bf_k<<<(1536 * 512 / 8 + 255) / 256, 256, 0, stream>>>(qkv_w, wq, 1536 * 512);
    f2bf_k<<<(2048 * 512 / 8 + 255) / 256, 256, 0, stream>>>(fc1_w, w1, 2048 * 512);
    f2bf_w2_k<<<512 * 2048 / 8 / 256, 256, 0, stream>>>(fc2_w, w2r);

    // CPE (fp32, 64-ch groups): spine = x + dwconv(x) + cpe_b
    conv4_k<float, float, true, 1><<<32 * 8 * 4, 256, 0, stream>>>(x, 512, 0, cpe_w, cpe_b, spine, 512, 3);

    const int M = 32768;
    // LN1 (full batch)
    ln_k<<<M / 4, 256, 0, stream>>>(spine, ln1_w, ln1_b, cur);
    // qkv: grid (128,6) = 768 blocks
    gemm8p_k<0, 512><<<dim3(128, 6), 512, 0, stream>>>(cur, wq, nullptr, nullptr, qkv, nullptr, M, 1536);
    // ktv partials (1024 blocks) + reduce (256)
    ktv_part_k<<<32 * 8 * 4, 256, 0, stream>>>(qkv, ktvp, csp);
    ktv_red_k<<<32 * 8, 256, 0, stream>>>(ktvp, csp, ktv);
    // crpe conv on v (512 blocks)
    conv4_k<bf16, bf16, false, 2><<<32 * 4 * 4, 256, 0, stream>>>(qkv, 1536, 1024, crpe_w, crpe_b, vc, 512, 2);
    // attention output (8192 blocks), in place on spine
    attnout_k<<<32 * 8 * 32, 256, 0, stream>>>(spine, qkv, ktv, vc);
    // LN2
    ln_k<<<M / 4, 256, 0, stream>>>(spine, ln2_w, ln2_b, cur);

    // MLP in two hidden halves of 1024
    for (int h = 0; h < 2; h++) {
        // fc1-half + gelu: grid (128,4) = 512 blocks
        gemm8p_k<1, 512><<<dim3(128, 4), 512, 0, stream>>>(
            cur, w1 + (size_t)h * 1024 * 512, fc1_b + h * 1024, nullptr, hg, nullptr, M, 1024);
        // hidden dwconv residual on the half (1024 blocks, 128-ch groups)
        conv4_k<bf16, bf16, true, 2><<<32 * 8 * 4, 256, 0, stream>>>(
            hg, 1024, 0, dw_w + (size_t)h * 1024 * 9, dw_b + h * 1024, h2, 1024, 3);
        // fc2-half: K=1024, grid (128,2) = 256 blocks; h0: +bias+resid, h1: accumulate
        if (h == 0)
            gemm8p_k<2, 1024><<<dim3(128, 2), 512, 0, stream>>>(
                h2, w2r, fc2_b, spine, nullptr, spine, M, 512);
        else
            gemm8p_k<3, 1024><<<dim3(128, 2), 512, 0, stream>>>(
                h2, w2r + (size_t)1 * 524288, nullptr, spine, nullptr, spine, M, 512);
    }
}

// Round 13
// 563.747 us; speedup vs baseline: 1.4890x; 1.1339x over previous
//
#include <hip/hip_runtime.h>
#include <hip/hip_bf16.h>

using bf16 = __hip_bfloat16;
using s16x4 = __attribute__((ext_vector_type(4))) short;
using s16x8 = __attribute__((ext_vector_type(8))) short;
using f32x4 = __attribute__((ext_vector_type(4))) float;

#define DI __device__ __forceinline__

template <int N> DI void wvm() {
    if constexpr (N == 8) asm volatile("s_waitcnt vmcnt(8)" ::: "memory");
    else if constexpr (N == 4) asm volatile("s_waitcnt vmcnt(4)" ::: "memory");
    else if constexpr (N == 2) asm volatile("s_waitcnt vmcnt(2)" ::: "memory");
    else asm volatile("s_waitcnt vmcnt(0)" ::: "memory");
}

DI float b2f(short s) { union { unsigned u; float f; } z; z.u = ((unsigned)(unsigned short)s) << 16; return z.f; }
DI short f2b(float f) { bf16 t = __float2bfloat16(f); return *(short*)&t; }

// fast gelu: tanh form, |err| ~1e-3 absolute, far under threshold
DI float gelu_f(float x) {
    const float t = 0.7978845608f * x * (1.f + 0.044715f * x * x);
    const float e = __expf(2.f * t);
    const float th = 1.f - 2.f / (e + 1.f);
    return 0.5f * x * (1.f + th);
}

DI void ld8(const bf16* p, float* f) {
    s16x8 x = *(const s16x8*)(const void*)p;
#pragma unroll
    for (int c = 0; c < 8; c++) f[c] = b2f(x[c]);
}
DI void ld8(const float* p, float* f) {
    float4 a = *(const float4*)p, b = *(const float4*)(p + 4);
    f[0]=a.x; f[1]=a.y; f[2]=a.z; f[3]=a.w; f[4]=b.x; f[5]=b.y; f[6]=b.z; f[7]=b.w;
}

typedef const __attribute__((address_space(1))) void* gp_t;
typedef __attribute__((address_space(3))) void* lp_t;
DI void gload_lds16(const void* g, void* l) {
    __builtin_amdgcn_global_load_lds((gp_t)g, (lp_t)l, 16, 0, 0);
}

// ---------------- diagnostic ----------------
__global__ void diag_k(float* out, float v) { out[0] = v; }

// ---------------- fp32 -> bf16 weight conversion (8/thread) ----------------
__global__ void f2bf_k(const float* __restrict__ in, bf16* __restrict__ out, int n) {
    int i = (blockIdx.x * 256 + threadIdx.x) * 8;
    if (i >= n) return;
    float f[8];
    ld8(in + i, f);
    s16x8 o;
#pragma unroll
    for (int c = 0; c < 8; c++) o[c] = f2b(f[c]);
    *(s16x8*)(void*)(out + i) = o;
}

// w2 [512,2048] -> half-major bf16 [2][512][1024]
__global__ void f2bf_w2_k(const float* __restrict__ in, bf16* __restrict__ out) {
    const int i = (blockIdx.x * 256 + threadIdx.x) * 8;   // over 512*2048
    const int n = i >> 11, c = i & 2047;
    const int h = c >> 10, k = c & 1023;
    float f[8];
    ld8(in + i, f);
    s16x8 o;
#pragma unroll
    for (int e = 0; e < 8; e++) o[e] = f2b(f[e]);
    *(s16x8*)(void*)(out + (size_t)h * 524288 + n * 1024 + k) = o;
}

// ---------------- depthwise 3x3 conv v4 ----------------
DI void tap10(const float* r, float w0, float w1, float w2, float* acc) {
#pragma unroll
    for (int i = 0; i < 8; i++)
        acc[i] += w0 * r[i] + w1 * r[i + 1] + w2 * r[i + 2];
}

template <typename TI, typename TO, bool RESID, int CPL>
__global__ __launch_bounds__(256) void conv4_k(
    const TI* in, long rs, long coff,
    const float* __restrict__ w, const float* __restrict__ bias,
    TO* out, long ors, int gshift)
{
    constexpr int CH = 64 * CPL;
    constexpr int ECNT = CH / 8;
    __shared__ float buf[2][CH][33];
    const int t = threadIdx.x;
    const int band = blockIdx.x & 3;
    const int cg = (blockIdx.x >> 2) & ((1 << gshift) - 1);
    const int img = blockIdx.x >> (2 + gshift);
    const int y0 = band * 8;

    const int spx = t >> 3;
    const int sce = (t & 7) * ECNT;
    const TI* gsrc = in + ((long)img << 10) * rs + coff + (long)cg * CH + sce;

    const int c = t & 63;
    const int xb = (t >> 6) * 8;

    float wv9[9][CPL], bw[CPL];
#pragma unroll
    for (int p = 0; p < CPL; p++) {
        const int gch = cg * CH + c * CPL + p;
#pragma unroll
        for (int j = 0; j < 9; j++) wv9[j][p] = w[gch * 9 + j];
        bw[p] = bias[gch];
    }

    auto stage = [&](int row) {
        float f[ECNT];
        ld8(gsrc + (long)(row * 32 + spx) * rs, f);
        if constexpr (ECNT == 16) ld8(gsrc + (long)(row * 32 + spx) * rs + 8, f + 8);
        float* d = &buf[row & 1][0][0];
#pragma unroll
        for (int k = 0; k < ECNT; k++) {
            const int ch = sce + k;
            const int rr = (CPL == 2) ? ((ch & 1) * 64 + (ch >> 1)) : ch;
            d[rr * 33 + spx] = f[k];
        }
    };
    auto slice = [&](int row, float r[CPL][10]) {
#pragma unroll
        for (int p = 0; p < CPL; p++) {
            const float* s = &buf[row & 1][c + p * 64][0];
            r[p][0] = (xb == 0) ? 0.f : s[xb - 1];
#pragma unroll
            for (int i = 0; i < 8; i++) r[p][1 + i] = s[xb + i];
            r[p][9] = (xb + 8 >= 32) ? 0.f : s[xb + 8];
        }
    };
    auto zero = [&](float r[CPL][10]) {
#pragma unroll
        for (int p = 0; p < CPL; p++)
#pragma unroll
            for (int i = 0; i < 10; i++) r[p][i] = 0.f;
    };

    float r0[CPL][10], r1[CPL][10], r2[CPL][10];
    if (y0 > 0) stage(y0 - 1);
    __syncthreads();
    if (y0 > 0) slice(y0 - 1, r0); else zero(r0);
    stage(y0);
    __syncthreads();
    slice(y0, r1);

    for (int y = y0; y < y0 + 8; ++y) {
        const int yn = y + 1;
        if (yn <= 31) stage(yn);
        __syncthreads();
        if (yn <= 31) slice(yn, r2); else zero(r2);
        float acc[CPL][8];
#pragma unroll
        for (int p = 0; p < CPL; p++) {
#pragma unroll
            for (int i = 0; i < 8; i++) acc[p][i] = bw[p];
            tap10(r0[p], wv9[0][p], wv9[1][p], wv9[2][p], acc[p]);
            tap10(r1[p], wv9[3][p], wv9[4][p], wv9[5][p], acc[p]);
            tap10(r2[p], wv9[6][p], wv9[7][p], wv9[8][p], acc[p]);
            if (RESID) {
#pragma unroll
                for (int i = 0; i < 8; i++) acc[p][i] += r1[p][i + 1];
            }
        }
        TO* o = out + ((long)(img * 1024 + y * 32 + xb)) * ors + (long)cg * CH + c * CPL;
#pragma unroll
        for (int i = 0; i < 8; i++) {
            if constexpr (CPL == 2 && sizeof(TO) == 2) {
                const unsigned u = (unsigned)(unsigned short)f2b(acc[0][i]) |
                                   ((unsigned)(unsigned short)f2b(acc[1][i]) << 16);
                *(unsigned*)(void*)(o + (long)i * ors) = u;
            } else {
                o[(long)i * ors] = (TO)acc[0][i];
            }
        }
#pragma unroll
        for (int p = 0; p < CPL; p++)
#pragma unroll
            for (int i = 0; i < 10; i++) { r0[p][i] = r1[p][i]; r1[p][i] = r2[p][i]; }
    }
}

// ---------------- LayerNorm over C=512, fp32 in -> bf16 out ----------------
__global__ __launch_bounds__(256) void ln_k(const float* __restrict__ x,
                                            const float* __restrict__ w,
                                            const float* __restrict__ bp,
                                            bf16* __restrict__ out)
{
    const size_t row = blockIdx.x * 4 + (threadIdx.x >> 6);
    const int t = threadIdx.x & 63;
    const float* xr = x + row * 512;
    alignas(16) float v[8];
    *(float4*)&v[0] = *(const float4*)(xr + t * 8);
    *(float4*)&v[4] = *(const float4*)(xr + t * 8 + 4);
    float s = 0.f;
#pragma unroll
    for (int j = 0; j < 8; j++) s += v[j];
#pragma unroll
    for (int mm = 32; mm; mm >>= 1) s += __shfl_xor(s, mm);
    const float mu = s * (1.f / 512.f);
    float q = 0.f;
#pragma unroll
    for (int j = 0; j < 8; j++) { v[j] -= mu; q += v[j] * v[j]; }
#pragma unroll
    for (int mm = 32; mm; mm >>= 1) q += __shfl_xor(q, mm);
    const float rstd = rsqrtf(q * (1.f / 512.f) + 1e-6f);
    alignas(16) float wv[8], bv[8];
    *(float4*)&wv[0] = *(const float4*)(w + t * 8);
    *(float4*)&wv[4] = *(const float4*)(w + t * 8 + 4);
    *(float4*)&bv[0] = *(const float4*)(bp + t * 8);
    *(float4*)&bv[4] = *(const float4*)(bp + t * 8 + 4);
    alignas(16) bf16 o[8];
#pragma unroll
    for (int j = 0; j < 8; j++) o[j] = __float2bfloat16(v[j] * rstd * wv[j] + bv[j]);
    *(uint4*)(out + row * 512 + t * 8) = *(const uint4*)o;
}

// ---------------- 8-phase 256x256 bf16 MFMA GEMM (K compile-time) -----------
// BK=64, 8 waves 2Mx4N, 128KB LDS. EPI 0: bf16. 1: +bias gelu bf16.
// 2: +bias +resid fp32. 3: +resid fp32 (accumulate pass, no bias).
template <int EPI, int K>
__global__ __launch_bounds__(512) void gemm8p_k(
    const bf16* __restrict__ A, const bf16* __restrict__ Bw,
    const float* __restrict__ bias, const float* resid,
    bf16* __restrict__ outb, float* outf, int M, int Nn)
{
    constexpr int KT = K / 64;
    __shared__ __align__(16) char lds[131072];
    char* ldsA = lds;
    char* ldsB = lds + 65536;
    const int t = threadIdx.x;
    const int lane = t & 63;
    const int w = t >> 6;
    const int wr = w >> 2, wc = w & 3;
    const int m0 = blockIdx.x * 256;
    const int n0 = blockIdx.y * 256;
    const int lr = lane & 15, lg = lane >> 4;

    f32x4 acc[8][4] = {};

    const int srow = lane >> 3;
    const int ssrc = 8 * ((lane & 7) ^ srow);

    auto SA = [&](int b, int kt, int h) {
#pragma unroll
        for (int j = 0; j < 2; j++) {
            const int lrow0 = j * 64 + w * 8;
            const int R0 = j * 128 + h * 64 + (lrow0 & 63);
            gload_lds16(A + (size_t)(m0 + R0 + srow) * K + kt * 64 + ssrc,
                        ldsA + ((b * 2 + h) * 128 + lrow0) * 128);
        }
    };
    auto SB = [&](int b, int kt, int h) {
#pragma unroll
        for (int j = 0; j < 2; j++) {
            const int lrow0 = j * 64 + w * 8;
            const int R0 = (lrow0 >> 5) * 64 + h * 32 + (lrow0 & 31);
            gload_lds16(Bw + (size_t)(n0 + R0 + srow) * K + kt * 64 + ssrc,
                        ldsB + ((b * 2 + h) * 128 + lrow0) * 128);
        }
    };
    auto RA = [&](int b, int h, int m, int ks) -> s16x8 {
        return *(const s16x8*)(ldsA + ((b * 2 + h) * 128 + wr * 64 + m * 16 + lr) * 128
                               + (((ks * 4 + lg) ^ (lr & 7)) << 4));
    };
    auto RB = [&](int b, int h, int n, int ks) -> s16x8 {
        return *(const s16x8*)(ldsB + ((b * 2 + h) * 128 + wc * 32 + n * 16 + lr) * 128
                               + (((ks * 4 + lg) ^ (lr & 7)) << 4));
    };
    auto MM = [&](int mb, int nb, s16x8 (&a)[2][4], s16x8 (&b)[2][2]) {
#pragma unroll
        for (int ks = 0; ks < 2; ks++)
#pragma unroll
            for (int m = 0; m < 4; m++)
#pragma unroll
                for (int n = 0; n < 2; n++)
                    acc[mb + m][nb + n] =
                        __builtin_amdgcn_mfma_f32_16x16x32_bf16(a[ks][m], b[ks][n], acc[mb + m][nb + n], 0, 0, 0);
    };

    SA(0, 0, 0); SB(0, 0, 0); SA(0, 0, 1); SB(0, 0, 1);
    SA(1, 1, 0); SB(1, 1, 0);
    wvm<8>();
    __builtin_amdgcn_s_barrier();

    s16x8 aLo[2][4], aHi[2][4], bLo[2][2], bHi[2][2];
    auto TILE = [&](int kt) {
        const int b = kt & 1;
        // phase 0: (M-lo x N-lo); stage A-hi(kt+1)
#pragma unroll
        for (int ks = 0; ks < 2; ks++) {
#pragma unroll
            for (int m = 0; m < 4; m++) aLo[ks][m] = RA(b, 0, m, ks);
#pragma unroll
            for (int n = 0; n < 2; n++) bLo[ks][n] = RB(b, 0, n, ks);
        }
        if (kt + 1 < KT) SA(b ^ 1, kt + 1, 1);
        __builtin_amdgcn_s_barrier();
        __builtin_amdgcn_s_setprio(1);
        MM(0, 0, aLo, bLo);
        __builtin_amdgcn_s_setprio(0);
        if (kt + 1 < KT) wvm<8>(); else wvm<2>();
        __builtin_amdgcn_s_barrier();
        // phase 1: (M-hi x N-lo); stage B-hi(kt+1)
#pragma unroll
        for (int ks = 0; ks < 2; ks++)
#pragma unroll
            for (int m = 0; m < 4; m++) aHi[ks][m] = RA(b, 1, m, ks);
        if (kt + 1 < KT) SB(b ^ 1, kt + 1, 1);
        __builtin_amdgcn_s_barrier();
        __builtin_amdgcn_s_setprio(1);
        MM(4, 0, aHi, bLo);
        __builtin_amdgcn_s_setprio(0);
        if (kt + 1 < KT) wvm<8>(); else wvm<0>();
        __builtin_amdgcn_s_barrier();
        // phase 2: (M-hi x N-hi); stage A-lo(kt+2)
#pragma unroll
        for (int ks = 0; ks < 2; ks++)
#pragma unroll
            for (int n = 0; n < 2; n++) bHi[ks][n] = RB(b, 1, n, ks);
        if (kt + 2 < KT) SA(b, kt + 2, 0);
        __builtin_amdgcn_s_barrier();
        __builtin_amdgcn_s_setprio(1);
        MM(4, 2, aHi, bHi);
        __builtin_amdgcn_s_setprio(0);
        __builtin_amdgcn_s_barrier();
        // phase 3: (M-lo x N-hi); stage B-lo(kt+2)
        if (kt + 2 < KT) SB(b, kt + 2, 0);
        __builtin_amdgcn_s_barrier();
        __builtin_amdgcn_s_setprio(1);
        MM(0, 2, aLo, bHi);
        __builtin_amdgcn_s_setprio(0);
        if (kt + 2 < KT) { wvm<8>(); __builtin_amdgcn_s_barrier(); }
        else if (kt + 1 < KT) { wvm<4>(); __builtin_amdgcn_s_barrier(); }
    };

    if constexpr (KT <= 8) {
#pragma unroll
        for (int kt = 0; kt < KT; ++kt) TILE(kt);
    } else {
#pragma unroll 2
        for (int kt = 0; kt < KT; ++kt) TILE(kt);
    }

#pragma unroll
    for (int i = 0; i < 8; i++) {
#pragma unroll
        for (int j = 0; j < 4; j++) {
            const int col = n0 + wc * 64 + j * 16 + lr;
            float bcol = 0.f;
            if constexpr (EPI == 1 || EPI == 2) bcol = bias[col];
#pragma unroll
            for (int r = 0; r < 4; r++) {
                const int row = m0 + wr * 128 + i * 16 + lg * 4 + r;
                float v = acc[i][j][r] + bcol;
                const size_t idx = (size_t)row * Nn + col;
                if (EPI >= 2) outf[idx] = v + resid[idx];
                else outb[idx] = __float2bfloat16(EPI == 1 ? gelu_f(v) : v);
            }
        }
    }
}

// ---------------- ktv partials: no max-subtraction softmax -------------------
__global__ __launch_bounds__(256) void ktv_part_k(const bf16* __restrict__ qkv,
                                                  float* __restrict__ ktvp,
                                                  float* __restrict__ csp)
{
    const int b = blockIdx.x >> 5;
    const int hh = (blockIdx.x >> 2) & 7;
    const int sp = blockIdx.x & 3;
    const bf16* kb = qkv + (size_t)b * 1024 * 1536 + 512 + hh * 64;
    const bf16* vb = kb + 512;
    __shared__ __align__(16) bf16 Ks[16 * 64];
    __shared__ __align__(16) bf16 Vs[16 * 64];
    const int t = threadIdx.x;
    const int kk = t & 63, vg = t >> 6;
    float acc[16] = {};
    float psum = 0.f;
    const int sr = t >> 4, sc = (t & 15) * 4;
    for (int n0 = sp * 256; n0 < sp * 256 + 256; n0 += 16) {
        __syncthreads();
        *(s16x4*)(void*)(Ks + sr * 64 + sc) = *(const s16x4*)(const void*)(kb + (size_t)(n0 + sr) * 1536 + sc);
        *(s16x4*)(void*)(Vs + sr * 64 + sc) = *(const s16x4*)(const void*)(vb + (size_t)(n0 + sr) * 1536 + sc);
        __syncthreads();
#pragma unroll
        for (int i = 0; i < 16; i++) {
            const float p = __expf(b2f(*(const short*)(const void*)(Ks + i * 64 + kk)));
            psum += p;
            float vv[16];
            ld8(Vs + i * 64 + vg * 16, vv);
            ld8(Vs + i * 64 + vg * 16 + 8, vv + 8);
#pragma unroll
            for (int j = 0; j < 16; j++) acc[j] += p * vv[j];
        }
    }
    const int bh4 = (b * 8 + hh) * 4 + sp;
    float* o = ktvp + (size_t)bh4 * 4096 + kk * 64 + vg * 16;
#pragma unroll
    for (int j = 0; j < 16; j++) o[j] = acc[j];
    if (vg == 0) csp[bh4 * 64 + kk] = psum;
}

// ---------------- ktv reduce -> bf16 transposed [v][k] ----------------------
__global__ __launch_bounds__(256) void ktv_red_k(const float* __restrict__ ktvp,
                                                 const float* __restrict__ csp,
                                                 bf16* __restrict__ ktvT)
{
    const int bh = blockIdx.x;
    const int t = threadIdx.x;
#pragma unroll
    for (int i = 0; i < 16; i++) {
        const int e = t + 256 * i;
        const int kk = e >> 6, v = e & 63;
        float cs = 0.f, val = 0.f;
#pragma unroll
        for (int sp = 0; sp < 4; sp++) {
            cs += csp[(bh * 4 + sp) * 64 + kk];
            val += ktvp[(size_t)(bh * 4 + sp) * 4096 + e];
        }
        ktvT[(size_t)bh * 4096 + v * 64 + kk] = __float2bfloat16(val * (0.125f / cs));
    }
}

// ---------------- attnout v2: MFMA q@ktvT + fused crpe + residual -----------
// block = (b, h, 256-row chunk), 4 waves. qs 32KB + ks 8KB LDS, XOR-swizzled
// on the ds_write side (regular writes -> swizzle both sides directly).
__global__ __launch_bounds__(256) void attnout2_k(
    float* xs, const bf16* __restrict__ qkv,
    const bf16* __restrict__ ktvT, const bf16* __restrict__ vc)
{
    __shared__ __align__(16) char qs[256 * 128];
    __shared__ __align__(16) char ks[64 * 128];
    const int t = threadIdx.x;
    const int bid = blockIdx.x;
    const int b = bid >> 5, hh = (bid >> 2) & 7, nc = bid & 3;
    const int n0 = nc * 256;
    const int lane = t & 63, w = t >> 6;
    const int lr = lane & 15, lg = lane >> 4;

    {
        const int r0 = t >> 3, sl = t & 7;
#pragma unroll
        for (int it = 0; it < 8; it++) {
            const int row = it * 32 + r0;
            const uint4 v = *(const uint4*)(qkv + ((size_t)(b * 1024 + n0 + row)) * 1536 + hh * 64 + sl * 8);
            *(uint4*)(qs + row * 128 + ((sl ^ (row & 7)) << 4)) = v;
        }
#pragma unroll
        for (int it = 0; it < 2; it++) {
            const int u = it * 256 + t;
            const int vr = u >> 3, sl2 = u & 7;
            const uint4 vv = *(const uint4*)(ktvT + (size_t)(b * 8 + hh) * 4096 + vr * 64 + sl2 * 8);
            *(uint4*)(ks + vr * 128 + ((sl2 ^ (vr & 7)) << 4)) = vv;
        }
    }
    __syncthreads();

    f32x4 acc[4][4] = {};
    s16x8 aF[2][4], bF[2][4];
#pragma unroll
    for (int ksi = 0; ksi < 2; ksi++) {
#pragma unroll
        for (int m = 0; m < 4; m++) {
            const int row = w * 64 + m * 16 + lr;
            aF[ksi][m] = *(const s16x8*)(qs + row * 128 + (((ksi * 4 + lg) ^ (lr & 7)) << 4));
        }
#pragma unroll
        for (int j = 0; j < 4; j++) {
            const int vr = j * 16 + lr;
            bF[ksi][j] = *(const s16x8*)(ks + vr * 128 + (((ksi * 4 + lg) ^ (lr & 7)) << 4));
        }
    }
#pragma unroll
    for (int ksi = 0; ksi < 2; ksi++)
#pragma unroll
        for (int m = 0; m < 4; m++)
#pragma unroll
            for (int j = 0; j < 4; j++)
                acc[m][j] = __builtin_amdgcn_mfma_f32_16x16x32_bf16(aF[ksi][m], bF[ksi][j], acc[m][j], 0, 0, 0);

#pragma unroll
    for (int m = 0; m < 4; m++) {
#pragma unroll
        for (int j = 0; j < 4; j++) {
#pragma unroll
            for (int r = 0; r < 4; r++) {
                const int lrow = w * 64 + m * 16 + lg * 4 + r;
                const int col = j * 16 + lr;
                const size_t idx = ((size_t)(b * 1024 + n0 + lrow)) * 512 + hh * 64 + col;
                const short qv = *(const short*)(qs + lrow * 128 + ((((col >> 3) ^ (lrow & 7)) << 4)) + (col & 7) * 2);
                xs[idx] = xs[idx] + acc[m][j][r] + b2f(qv) * __bfloat162float(vc[idx]);
            }
        }
    }
}

// ---------------- workspace layout (bytes), full-batch ----------------------
static constexpr size_t OFF_WQ   = 0;           // 1.5MB
static constexpr size_t OFF_W1   = 1572864;     // 2MB
static constexpr size_t OFF_W2   = 3670016;     // 2MB (half-major repack)
static constexpr size_t OFF_CUR  = 5767168;     // bf16 (32,1024,512) 32MB
static constexpr size_t OFF_QKV  = 39321600;    // bf16 (32,1024,1536) 96MB
static constexpr size_t OFF_VC   = 139984896;   // bf16 (32,1024,512) 32MB
static constexpr size_t OFF_KTVP = 173539328;   // fp32 1024x4096 16MB
static constexpr size_t OFF_CSP  = 190316544;   // 256KB
static constexpr size_t OFF_KTV  = 190578688;   // bf16 ktvT 512KB
static constexpr size_t WS_NEED  = 194772992;   // ~185.7MB (ws >= 215.5MB confirmed)
static constexpr size_t OFF_HG   = OFF_QKV;             // 64MB over dead qkv[0:64]
static constexpr size_t OFF_H2   = OFF_QKV + 67108864;  // 64MB over qkv[64:96]+vc

extern "C" void kernel_launch(void* const* d_in, const int* in_sizes, int n_in,
                              void* d_out, int out_size, void* d_ws, size_t ws_size,
                              hipStream_t stream)
{
    const float* x     = (const float*)d_in[0];
    const float* cpe_w = (const float*)d_in[1];
    const float* cpe_b = (const float*)d_in[2];
    const float* ln1_w = (const float*)d_in[3];
    const float* ln1_b = (const float*)d_in[4];
    const float* qkv_w = (const float*)d_in[5];
    const float* crpe_w= (const float*)d_in[6];
    const float* crpe_b= (const float*)d_in[7];
    const float* ln2_w = (const float*)d_in[8];
    const float* ln2_b = (const float*)d_in[9];
    const float* fc1_w = (const float*)d_in[10];
    const float* fc1_b = (const float*)d_in[11];
    const float* dw_w  = (const float*)d_in[12];
    const float* dw_b  = (const float*)d_in[13];
    const float* fc2_w = (const float*)d_in[14];
    const float* fc2_b = (const float*)d_in[15];
    float* spine = (float*)d_out;
    char* ws = (char*)d_ws;

    if (ws_size < WS_NEED) {
        diag_k<<<1, 1, 0, stream>>>(spine, (float)ws_size);
        return;
    }

    bf16*  wq   = (bf16*)(ws + OFF_WQ);
    bf16*  w1   = (bf16*)(ws + OFF_W1);
    bf16*  w2r  = (bf16*)(ws + OFF_W2);
    bf16*  cur  = (bf16*)(ws + OFF_CUR);
    bf16*  qkv  = (bf16*)(ws + OFF_QKV);
    bf16*  vc   = (bf16*)(ws + OFF_VC);
    float* ktvp = (float*)(ws + OFF_KTVP);
    float* csp  = (float*)(ws + OFF_CSP);
    bf16*  ktvT = (bf16*)(ws + OFF_KTV);
    bf16*  hg   = (bf16*)(ws + OFF_HG);
    bf16*  h2   = (bf16*)(ws + OFF_H2);

    // weights -> bf16 (w2 repacked half-major)
    f2bf_k<<<(1536 * 512 / 8 + 255) / 256, 256, 0, stream>>>(qkv_w, wq, 1536 * 512);
    f2bf_k<<<(2048 * 512 / 8 + 255) / 256, 256, 0, stream>>>(fc1_w, w1, 2048 * 512);
    f2bf_w2_k<<<512 * 2048 / 8 / 256, 256, 0, stream>>>(fc2_w, w2r);

    // CPE (fp32, 64-ch groups): spine = x + dwconv(x) + cpe_b
    conv4_k<float, float, true, 1><<<32 * 8 * 4, 256, 0, stream>>>(x, 512, 0, cpe_w, cpe_b, spine, 512, 3);

    const int M = 32768;
    // LN1 (full batch)
    ln_k<<<M / 4, 256, 0, stream>>>(spine, ln1_w, ln1_b, cur);
    // qkv: grid (128,6) = 768 blocks
    gemm8p_k<0, 512><<<dim3(128, 6), 512, 0, stream>>>(cur, wq, nullptr, nullptr, qkv, nullptr, M, 1536);
    // ktv partials (1024 blocks) + reduce -> bf16 ktvT (256 blocks)
    ktv_part_k<<<32 * 8 * 4, 256, 0, stream>>>(qkv, ktvp, csp);
    ktv_red_k<<<32 * 8, 256, 0, stream>>>(ktvp, csp, ktvT);
    // crpe conv on v (512 blocks)
    conv4_k<bf16, bf16, false, 2><<<32 * 4 * 4, 256, 0, stream>>>(qkv, 1536, 1024, crpe_w, crpe_b, vc, 512, 2);
    // attention output (MFMA, 1024 blocks), in place on spine
    attnout2_k<<<32 * 8 * 4, 256, 0, stream>>>(spine, qkv, ktvT, vc);
    // LN2
    ln_k<<<M / 4, 256, 0, stream>>>(spine, ln2_w, ln2_b, cur);

    // MLP in two hidden halves of 1024
    for (int h = 0; h < 2; h++) {
        // fc1-half + gelu: grid (128,4) = 512 blocks
        gemm8p_k<1, 512><<<dim3(128, 4), 512, 0, stream>>>(
            cur, w1 + (size_t)h * 1024 * 512, fc1_b + h * 1024, nullptr, hg, nullptr, M, 1024);
        // hidden dwconv residual on the half (1024 blocks, 128-ch groups)
        conv4_k<bf16, bf16, true, 2><<<32 * 8 * 4, 256, 0, stream>>>(
            hg, 1024, 0, dw_w + (size_t)h * 1024 * 9, dw_b + h * 1024, h2, 1024, 3);
        // fc2-half: K=1024, grid (128,2) = 256 blocks; h0: +bias+resid, h1: accumulate
        if (h == 0)
            gemm8p_k<2, 1024><<<dim3(128, 2), 512, 0, stream>>>(
                h2, w2r, fc2_b, spine, nullptr, spine, M, 512);
        else
            gemm8p_k<3, 1024><<<dim3(128, 2), 512, 0, stream>>>(
                h2, w2r + (size_t)1 * 524288, nullptr, spine, nullptr, spine, M, 512);
    }
}

// Round 14
// 510.380 us; speedup vs baseline: 1.6447x; 1.1046x over previous
//
#include <hip/hip_runtime.h>
#include <hip/hip_bf16.h>

using bf16 = __hip_bfloat16;
using s16x4 = __attribute__((ext_vector_type(4))) short;
using s16x8 = __attribute__((ext_vector_type(8))) short;
using f32x4 = __attribute__((ext_vector_type(4))) float;

#define DI __device__ __forceinline__

template <int N> DI void wvm() {
    if constexpr (N == 8) asm volatile("s_waitcnt vmcnt(8)" ::: "memory");
    else if constexpr (N == 4) asm volatile("s_waitcnt vmcnt(4)" ::: "memory");
    else if constexpr (N == 2) asm volatile("s_waitcnt vmcnt(2)" ::: "memory");
    else asm volatile("s_waitcnt vmcnt(0)" ::: "memory");
}

DI float b2f(short s) { union { unsigned u; float f; } z; z.u = ((unsigned)(unsigned short)s) << 16; return z.f; }
DI short f2b(float f) { bf16 t = __float2bfloat16(f); return *(short*)&t; }

// fast gelu: tanh form, |err| ~1e-3 absolute, far under threshold
DI float gelu_f(float x) {
    const float t = 0.7978845608f * x * (1.f + 0.044715f * x * x);
    const float e = __expf(2.f * t);
    const float th = 1.f - 2.f / (e + 1.f);
    return 0.5f * x * (1.f + th);
}

DI void ld8(const bf16* p, float* f) {
    s16x8 x = *(const s16x8*)(const void*)p;
#pragma unroll
    for (int c = 0; c < 8; c++) f[c] = b2f(x[c]);
}
DI void ld8(const float* p, float* f) {
    float4 a = *(const float4*)p, b = *(const float4*)(p + 4);
    f[0]=a.x; f[1]=a.y; f[2]=a.z; f[3]=a.w; f[4]=b.x; f[5]=b.y; f[6]=b.z; f[7]=b.w;
}

typedef const __attribute__((address_space(1))) void* gp_t;
typedef __attribute__((address_space(3))) void* lp_t;
DI void gload_lds16(const void* g, void* l) {
    __builtin_amdgcn_global_load_lds((gp_t)g, (lp_t)l, 16, 0, 0);
}

// ---------------- diagnostic ----------------
__global__ void diag_k(float* out, float v) { out[0] = v; }

// ---------------- fp32 -> bf16 weight conversion (8/thread) ----------------
__global__ void f2bf_k(const float* __restrict__ in, bf16* __restrict__ out, int n) {
    int i = (blockIdx.x * 256 + threadIdx.x) * 8;
    if (i >= n) return;
    float f[8];
    ld8(in + i, f);
    s16x8 o;
#pragma unroll
    for (int c = 0; c < 8; c++) o[c] = f2b(f[c]);
    *(s16x8*)(void*)(out + i) = o;
}

// w2 [512,2048] -> half-major bf16 [2][512][1024]
__global__ void f2bf_w2_k(const float* __restrict__ in, bf16* __restrict__ out) {
    const int i = (blockIdx.x * 256 + threadIdx.x) * 8;   // over 512*2048
    const int n = i >> 11, c = i & 2047;
    const int h = c >> 10, k = c & 1023;
    float f[8];
    ld8(in + i, f);
    s16x8 o;
#pragma unroll
    for (int e = 0; e < 8; e++) o[e] = f2b(f[e]);
    *(s16x8*)(void*)(out + (size_t)h * 524288 + n * 1024 + k) = o;
}

// ---------------- depthwise 3x3 conv v4 ----------------
DI void tap10(const float* r, float w0, float w1, float w2, float* acc) {
#pragma unroll
    for (int i = 0; i < 8; i++)
        acc[i] += w0 * r[i] + w1 * r[i + 1] + w2 * r[i + 2];
}

template <typename TI, typename TO, bool RESID, int CPL>
__global__ __launch_bounds__(256) void conv4_k(
    const TI* in, long rs, long coff,
    const float* __restrict__ w, const float* __restrict__ bias,
    TO* out, long ors, int gshift)
{
    constexpr int CH = 64 * CPL;
    constexpr int ECNT = CH / 8;
    __shared__ float buf[2][CH][33];
    const int t = threadIdx.x;
    const int band = blockIdx.x & 3;
    const int cg = (blockIdx.x >> 2) & ((1 << gshift) - 1);
    const int img = blockIdx.x >> (2 + gshift);
    const int y0 = band * 8;

    const int spx = t >> 3;
    const int sce = (t & 7) * ECNT;
    const TI* gsrc = in + ((long)img << 10) * rs + coff + (long)cg * CH + sce;

    const int c = t & 63;
    const int xb = (t >> 6) * 8;

    float wv9[9][CPL], bw[CPL];
#pragma unroll
    for (int p = 0; p < CPL; p++) {
        const int gch = cg * CH + c * CPL + p;
#pragma unroll
        for (int j = 0; j < 9; j++) wv9[j][p] = w[gch * 9 + j];
        bw[p] = bias[gch];
    }

    auto stage = [&](int row) {
        float f[ECNT];
        ld8(gsrc + (long)(row * 32 + spx) * rs, f);
        if constexpr (ECNT == 16) ld8(gsrc + (long)(row * 32 + spx) * rs + 8, f + 8);
        float* d = &buf[row & 1][0][0];
#pragma unroll
        for (int k = 0; k < ECNT; k++) {
            const int ch = sce + k;
            const int rr = (CPL == 2) ? ((ch & 1) * 64 + (ch >> 1)) : ch;
            d[rr * 33 + spx] = f[k];
        }
    };
    auto slice = [&](int row, float r[CPL][10]) {
#pragma unroll
        for (int p = 0; p < CPL; p++) {
            const float* s = &buf[row & 1][c + p * 64][0];
            r[p][0] = (xb == 0) ? 0.f : s[xb - 1];
#pragma unroll
            for (int i = 0; i < 8; i++) r[p][1 + i] = s[xb + i];
            r[p][9] = (xb + 8 >= 32) ? 0.f : s[xb + 8];
        }
    };
    auto zero = [&](float r[CPL][10]) {
#pragma unroll
        for (int p = 0; p < CPL; p++)
#pragma unroll
            for (int i = 0; i < 10; i++) r[p][i] = 0.f;
    };

    float r0[CPL][10], r1[CPL][10], r2[CPL][10];
    if (y0 > 0) stage(y0 - 1);
    __syncthreads();
    if (y0 > 0) slice(y0 - 1, r0); else zero(r0);
    stage(y0);
    __syncthreads();
    slice(y0, r1);

    for (int y = y0; y < y0 + 8; ++y) {
        const int yn = y + 1;
        if (yn <= 31) stage(yn);
        __syncthreads();
        if (yn <= 31) slice(yn, r2); else zero(r2);
        float acc[CPL][8];
#pragma unroll
        for (int p = 0; p < CPL; p++) {
#pragma unroll
            for (int i = 0; i < 8; i++) acc[p][i] = bw[p];
            tap10(r0[p], wv9[0][p], wv9[1][p], wv9[2][p], acc[p]);
            tap10(r1[p], wv9[3][p], wv9[4][p], wv9[5][p], acc[p]);
            tap10(r2[p], wv9[6][p], wv9[7][p], wv9[8][p], acc[p]);
            if (RESID) {
#pragma unroll
                for (int i = 0; i < 8; i++) acc[p][i] += r1[p][i + 1];
            }
        }
        TO* o = out + ((long)(img * 1024 + y * 32 + xb)) * ors + (long)cg * CH + c * CPL;
#pragma unroll
        for (int i = 0; i < 8; i++) {
            if constexpr (CPL == 2 && sizeof(TO) == 2) {
                const unsigned u = (unsigned)(unsigned short)f2b(acc[0][i]) |
                                   ((unsigned)(unsigned short)f2b(acc[1][i]) << 16);
                *(unsigned*)(void*)(o + (long)i * ors) = u;
            } else {
                o[(long)i * ors] = (TO)acc[0][i];
            }
        }
#pragma unroll
        for (int p = 0; p < CPL; p++)
#pragma unroll
            for (int i = 0; i < 10; i++) { r0[p][i] = r1[p][i]; r1[p][i] = r2[p][i]; }
    }
}

// ---------------- LayerNorm over C=512, fp32 in -> bf16 out ----------------
__global__ __launch_bounds__(256) void ln_k(const float* __restrict__ x,
                                            const float* __restrict__ w,
                                            const float* __restrict__ bp,
                                            bf16* __restrict__ out)
{
    const size_t row = blockIdx.x * 4 + (threadIdx.x >> 6);
    const int t = threadIdx.x & 63;
    const float* xr = x + row * 512;
    alignas(16) float v[8];
    *(float4*)&v[0] = *(const float4*)(xr + t * 8);
    *(float4*)&v[4] = *(const float4*)(xr + t * 8 + 4);
    float s = 0.f;
#pragma unroll
    for (int j = 0; j < 8; j++) s += v[j];
#pragma unroll
    for (int mm = 32; mm; mm >>= 1) s += __shfl_xor(s, mm);
    const float mu = s * (1.f / 512.f);
    float q = 0.f;
#pragma unroll
    for (int j = 0; j < 8; j++) { v[j] -= mu; q += v[j] * v[j]; }
#pragma unroll
    for (int mm = 32; mm; mm >>= 1) q += __shfl_xor(q, mm);
    const float rstd = rsqrtf(q * (1.f / 512.f) + 1e-6f);
    alignas(16) float wv[8], bv[8];
    *(float4*)&wv[0] = *(const float4*)(w + t * 8);
    *(float4*)&wv[4] = *(const float4*)(w + t * 8 + 4);
    *(float4*)&bv[0] = *(const float4*)(bp + t * 8);
    *(float4*)&bv[4] = *(const float4*)(bp + t * 8 + 4);
    alignas(16) bf16 o[8];
#pragma unroll
    for (int j = 0; j < 8; j++) o[j] = __float2bfloat16(v[j] * rstd * wv[j] + bv[j]);
    *(uint4*)(out + row * 512 + t * 8) = *(const uint4*)o;
}

// ---------------- 8-phase 256x256 bf16 MFMA GEMM (K compile-time) -----------
// BK=64, 8 waves 2Mx4N, 128KB LDS. EPI 0: bf16. 1: +bias gelu bf16.
// 2: +bias +resid fp32. 3: +resid fp32 (accumulate pass, no bias).
template <int EPI, int K>
__global__ __launch_bounds__(512) void gemm8p_k(
    const bf16* __restrict__ A, const bf16* __restrict__ Bw,
    const float* __restrict__ bias, const float* resid,
    bf16* __restrict__ outb, float* outf, int M, int Nn)
{
    constexpr int KT = K / 64;
    __shared__ __align__(16) char lds[131072];
    char* ldsA = lds;
    char* ldsB = lds + 65536;
    const int t = threadIdx.x;
    const int lane = t & 63;
    const int w = t >> 6;
    const int wr = w >> 2, wc = w & 3;
    const int m0 = blockIdx.x * 256;
    const int n0 = blockIdx.y * 256;
    const int lr = lane & 15, lg = lane >> 4;

    f32x4 acc[8][4] = {};

    const int srow = lane >> 3;
    const int ssrc = 8 * ((lane & 7) ^ srow);

    auto SA = [&](int b, int kt, int h) {
#pragma unroll
        for (int j = 0; j < 2; j++) {
            const int lrow0 = j * 64 + w * 8;
            const int R0 = j * 128 + h * 64 + (lrow0 & 63);
            gload_lds16(A + (size_t)(m0 + R0 + srow) * K + kt * 64 + ssrc,
                        ldsA + ((b * 2 + h) * 128 + lrow0) * 128);
        }
    };
    auto SB = [&](int b, int kt, int h) {
#pragma unroll
        for (int j = 0; j < 2; j++) {
            const int lrow0 = j * 64 + w * 8;
            const int R0 = (lrow0 >> 5) * 64 + h * 32 + (lrow0 & 31);
            gload_lds16(Bw + (size_t)(n0 + R0 + srow) * K + kt * 64 + ssrc,
                        ldsB + ((b * 2 + h) * 128 + lrow0) * 128);
        }
    };
    auto RA = [&](int b, int h, int m, int ks) -> s16x8 {
        return *(const s16x8*)(ldsA + ((b * 2 + h) * 128 + wr * 64 + m * 16 + lr) * 128
                               + (((ks * 4 + lg) ^ (lr & 7)) << 4));
    };
    auto RB = [&](int b, int h, int n, int ks) -> s16x8 {
        return *(const s16x8*)(ldsB + ((b * 2 + h) * 128 + wc * 32 + n * 16 + lr) * 128
                               + (((ks * 4 + lg) ^ (lr & 7)) << 4));
    };
    auto MM = [&](int mb, int nb, s16x8 (&a)[2][4], s16x8 (&b)[2][2]) {
#pragma unroll
        for (int ks = 0; ks < 2; ks++)
#pragma unroll
            for (int m = 0; m < 4; m++)
#pragma unroll
                for (int n = 0; n < 2; n++)
                    acc[mb + m][nb + n] =
                        __builtin_amdgcn_mfma_f32_16x16x32_bf16(a[ks][m], b[ks][n], acc[mb + m][nb + n], 0, 0, 0);
    };

    SA(0, 0, 0); SB(0, 0, 0); SA(0, 0, 1); SB(0, 0, 1);
    SA(1, 1, 0); SB(1, 1, 0);
    wvm<8>();
    __builtin_amdgcn_s_barrier();

    s16x8 aLo[2][4], aHi[2][4], bLo[2][2], bHi[2][2];
    auto TILE = [&](int kt) {
        const int b = kt & 1;
        // phase 0: (M-lo x N-lo); stage A-hi(kt+1)
#pragma unroll
        for (int ks = 0; ks < 2; ks++) {
#pragma unroll
            for (int m = 0; m < 4; m++) aLo[ks][m] = RA(b, 0, m, ks);
#pragma unroll
            for (int n = 0; n < 2; n++) bLo[ks][n] = RB(b, 0, n, ks);
        }
        if (kt + 1 < KT) SA(b ^ 1, kt + 1, 1);
        __builtin_amdgcn_s_barrier();
        __builtin_amdgcn_s_setprio(1);
        MM(0, 0, aLo, bLo);
        __builtin_amdgcn_s_setprio(0);
        if (kt + 1 < KT) wvm<8>(); else wvm<2>();
        __builtin_amdgcn_s_barrier();
        // phase 1: (M-hi x N-lo); stage B-hi(kt+1)
#pragma unroll
        for (int ks = 0; ks < 2; ks++)
#pragma unroll
            for (int m = 0; m < 4; m++) aHi[ks][m] = RA(b, 1, m, ks);
        if (kt + 1 < KT) SB(b ^ 1, kt + 1, 1);
        __builtin_amdgcn_s_barrier();
        __builtin_amdgcn_s_setprio(1);
        MM(4, 0, aHi, bLo);
        __builtin_amdgcn_s_setprio(0);
        if (kt + 1 < KT) wvm<8>(); else wvm<0>();
        __builtin_amdgcn_s_barrier();
        // phase 2: (M-hi x N-hi); stage A-lo(kt+2)
#pragma unroll
        for (int ks = 0; ks < 2; ks++)
#pragma unroll
            for (int n = 0; n < 2; n++) bHi[ks][n] = RB(b, 1, n, ks);
        if (kt + 2 < KT) SA(b, kt + 2, 0);
        __builtin_amdgcn_s_barrier();
        __builtin_amdgcn_s_setprio(1);
        MM(4, 2, aHi, bHi);
        __builtin_amdgcn_s_setprio(0);
        __builtin_amdgcn_s_barrier();
        // phase 3: (M-lo x N-hi); stage B-lo(kt+2)
        if (kt + 2 < KT) SB(b, kt + 2, 0);
        __builtin_amdgcn_s_barrier();
        __builtin_amdgcn_s_setprio(1);
        MM(0, 2, aLo, bHi);
        __builtin_amdgcn_s_setprio(0);
        if (kt + 2 < KT) { wvm<8>(); __builtin_amdgcn_s_barrier(); }
        else if (kt + 1 < KT) { wvm<4>(); __builtin_amdgcn_s_barrier(); }
    };

    if constexpr (KT <= 8) {
#pragma unroll
        for (int kt = 0; kt < KT; ++kt) TILE(kt);
    } else {
#pragma unroll 2
        for (int kt = 0; kt < KT; ++kt) TILE(kt);
    }

#pragma unroll
    for (int i = 0; i < 8; i++) {
#pragma unroll
        for (int j = 0; j < 4; j++) {
            const int col = n0 + wc * 64 + j * 16 + lr;
            float bcol = 0.f;
            if constexpr (EPI == 1 || EPI == 2) bcol = bias[col];
#pragma unroll
            for (int r = 0; r < 4; r++) {
                const int row = m0 + wr * 128 + i * 16 + lg * 4 + r;
                float v = acc[i][j][r] + bcol;
                const size_t idx = (size_t)row * Nn + col;
                if (EPI >= 2) outf[idx] = v + resid[idx];
                else outb[idx] = __float2bfloat16(EPI == 1 ? gelu_f(v) : v);
            }
        }
    }
}

// ---------------- ktv v2: MFMA over tokens, fused softmax-denominator -------
// block = (b,h), 256 threads (4 waves). Per 64-token tile: load K/V rows
// coalesced, exp(K) in-register, scatter-write P^T[k][n] and V^T[v][n] into
// XOR-swizzled LDS, then MFMA A=V^T B=P^T -> D[v][k] = ktvT. csum[k] from
// vector reads of P^T rows; epilogue scales by 0.125/csum and writes bf16.
__global__ __launch_bounds__(256) void ktv2_k(const bf16* __restrict__ qkv,
                                              bf16* __restrict__ ktvT)
{
    __shared__ __align__(16) char P[64 * 128];    // P^T [k][n] bf16, swizzled
    __shared__ __align__(16) char Vt[64 * 128];   // V^T [v][n] bf16, swizzled
    __shared__ float csl[64 * 5];                 // csum partials [k][q] + final
    const int t = threadIdx.x;
    const int b = blockIdx.x >> 3, hh = blockIdx.x & 7;
    const int lane = t & 63, w = t >> 6;
    const int lr = lane & 15, lg = lane >> 4;

    const int n_r = t >> 2;              // tile row 0..63
    const int k0 = (t & 3) * 16;         // feature base 0..48
    const bf16* kbase = qkv + (size_t)(b * 1024) * 1536 + 512 + hh * 64 + k0;
    const bf16* vbase = kbase + 512;

    const int kq = t & 63, qq = t >> 6;  // csum role: row kq, quarter qq
    float cacc = 0.f;

    f32x4 acc[4] = {};                   // D[v = w*16.., k = j*16..]

    for (int n0 = 0; n0 < 1024; n0 += 64) {
        const uint4 ka = *(const uint4*)(kbase + (size_t)(n0 + n_r) * 1536);
        const uint4 kb2 = *(const uint4*)(kbase + (size_t)(n0 + n_r) * 1536 + 8);
        const uint4 va = *(const uint4*)(vbase + (size_t)(n0 + n_r) * 1536);
        const uint4 vb2 = *(const uint4*)(vbase + (size_t)(n0 + n_r) * 1536 + 8);
        __syncthreads();   // prev tile's LDS reads complete
        {
            const short* ke = (const short*)&ka;
            const short* ke2 = (const short*)&kb2;
            const short* ve = (const short*)&va;
            const short* ve2 = (const short*)&vb2;
            const int nslot = ((n_r >> 3) << 4);
            const int nbyte = (n_r & 7) * 2;
#pragma unroll
            for (int j = 0; j < 16; j++) {
                const int row = k0 + j;
                const short kv = j < 8 ? ke[j] : ke2[j - 8];
                const short vv = j < 8 ? ve[j] : ve2[j - 8];
                const int off = row * 128 + (nslot ^ ((row & 7) << 4)) + nbyte;
                *(short*)(P + off) = f2b(__expf(b2f(kv)));
                *(short*)(Vt + off) = vv;
            }
        }
        __syncthreads();   // writes visible
        // csum partial: row kq, n = qq*16..+15 (slots 2qq, 2qq+1)
        {
            const char* pr = P + kq * 128;
            const int sw = (kq & 7) << 4;
            s16x8 x0 = *(const s16x8*)(pr + (((qq * 2) << 4) ^ sw));
            s16x8 x1 = *(const s16x8*)(pr + (((qq * 2 + 1) << 4) ^ sw));
#pragma unroll
            for (int j = 0; j < 8; j++) cacc += b2f(x0[j]) + b2f(x1[j]);
        }
        // MFMA: contraction over 64 tokens = 2 slices of 32
#pragma unroll
        for (int ks2 = 0; ks2 < 2; ks2++) {
            s16x8 aF = *(const s16x8*)(Vt + (w * 16 + lr) * 128 + (((ks2 * 4 + lg) ^ (lr & 7)) << 4));
            s16x8 bF[4];
#pragma unroll
            for (int j = 0; j < 4; j++)
                bF[j] = *(const s16x8*)(P + (j * 16 + lr) * 128 + (((ks2 * 4 + lg) ^ (lr & 7)) << 4));
#pragma unroll
            for (int j = 0; j < 4; j++)
                acc[j] = __builtin_amdgcn_mfma_f32_16x16x32_bf16(aF, bF[j], acc[j], 0, 0, 0);
        }
    }
    __syncthreads();
    csl[kq * 5 + qq] = cacc;
    __syncthreads();
    if (t < 64) csl[t * 5 + 4] = csl[t * 5] + csl[t * 5 + 1] + csl[t * 5 + 2] + csl[t * 5 + 3];
    __syncthreads();

    bf16* o = ktvT + (size_t)(b * 8 + hh) * 4096;
#pragma unroll
    for (int j = 0; j < 4; j++) {
        const int col = j * 16 + lr;                 // k
        const float sc = 0.125f / csl[col * 5 + 4];
#pragma unroll
        for (int r = 0; r < 4; r++) {
            const int vrow = w * 16 + lg * 4 + r;    // v
            o[vrow * 64 + col] = __float2bfloat16(acc[j][r] * sc);
        }
    }
}

// ---------------- attnout v2: MFMA q@ktvT + fused crpe + residual -----------
__global__ __launch_bounds__(256) void attnout2_k(
    float* xs, const bf16* __restrict__ qkv,
    const bf16* __restrict__ ktvT, const bf16* __restrict__ vc)
{
    __shared__ __align__(16) char qs[256 * 128];
    __shared__ __align__(16) char ks[64 * 128];
    const int t = threadIdx.x;
    const int bid = blockIdx.x;
    const int b = bid >> 5, hh = (bid >> 2) & 7, nc = bid & 3;
    const int n0 = nc * 256;
    const int lane = t & 63, w = t >> 6;
    const int lr = lane & 15, lg = lane >> 4;

    {
        const int r0 = t >> 3, sl = t & 7;
#pragma unroll
        for (int it = 0; it < 8; it++) {
            const int row = it * 32 + r0;
            const uint4 v = *(const uint4*)(qkv + ((size_t)(b * 1024 + n0 + row)) * 1536 + hh * 64 + sl * 8);
            *(uint4*)(qs + row * 128 + ((sl ^ (row & 7)) << 4)) = v;
        }
#pragma unroll
        for (int it = 0; it < 2; it++) {
            const int u = it * 256 + t;
            const int vr = u >> 3, sl2 = u & 7;
            const uint4 vv = *(const uint4*)(ktvT + (size_t)(b * 8 + hh) * 4096 + vr * 64 + sl2 * 8);
            *(uint4*)(ks + vr * 128 + ((sl2 ^ (vr & 7)) << 4)) = vv;
        }
    }
    __syncthreads();

    f32x4 acc[4][4] = {};
    s16x8 aF[2][4], bF[2][4];
#pragma unroll
    for (int ksi = 0; ksi < 2; ksi++) {
#pragma unroll
        for (int m = 0; m < 4; m++) {
            const int row = w * 64 + m * 16 + lr;
            aF[ksi][m] = *(const s16x8*)(qs + row * 128 + (((ksi * 4 + lg) ^ (lr & 7)) << 4));
        }
#pragma unroll
        for (int j = 0; j < 4; j++) {
            const int vr = j * 16 + lr;
            bF[ksi][j] = *(const s16x8*)(ks + vr * 128 + (((ksi * 4 + lg) ^ (lr & 7)) << 4));
        }
    }
#pragma unroll
    for (int ksi = 0; ksi < 2; ksi++)
#pragma unroll
        for (int m = 0; m < 4; m++)
#pragma unroll
            for (int j = 0; j < 4; j++)
                acc[m][j] = __builtin_amdgcn_mfma_f32_16x16x32_bf16(aF[ksi][m], bF[ksi][j], acc[m][j], 0, 0, 0);

#pragma unroll
    for (int m = 0; m < 4; m++) {
#pragma unroll
        for (int j = 0; j < 4; j++) {
#pragma unroll
            for (int r = 0; r < 4; r++) {
                const int lrow = w * 64 + m * 16 + lg * 4 + r;
                const int col = j * 16 + lr;
                const size_t idx = ((size_t)(b * 1024 + n0 + lrow)) * 512 + hh * 64 + col;
                const short qv = *(const short*)(qs + lrow * 128 + ((((col >> 3) ^ (lrow & 7)) << 4)) + (col & 7) * 2);
                xs[idx] = xs[idx] + acc[m][j][r] + b2f(qv) * __bfloat162float(vc[idx]);
            }
        }
    }
}

// ---------------- workspace layout (bytes), full-batch ----------------------
static constexpr size_t OFF_WQ   = 0;           // 1.5MB
static constexpr size_t OFF_W1   = 1572864;     // 2MB
static constexpr size_t OFF_W2   = 3670016;     // 2MB (half-major repack)
static constexpr size_t OFF_CUR  = 5767168;     // bf16 (32,1024,512) 32MB
static constexpr size_t OFF_QKV  = 39321600;    // bf16 (32,1024,1536) 96MB
static constexpr size_t OFF_VC   = 139984896;   // bf16 (32,1024,512) 32MB
static constexpr size_t OFF_KTV  = 173539328;   // bf16 ktvT 512KB
static constexpr size_t WS_NEED  = 194772992;   // known ws >= 215.5MB
static constexpr size_t OFF_HG   = OFF_QKV;             // 64MB over dead qkv[0:64]
static constexpr size_t OFF_H2   = OFF_QKV + 67108864;  // 64MB over qkv[64:96]+vc

extern "C" void kernel_launch(void* const* d_in, const int* in_sizes, int n_in,
                              void* d_out, int out_size, void* d_ws, size_t ws_size,
                              hipStream_t stream)
{
    const float* x     = (const float*)d_in[0];
    const float* cpe_w = (const float*)d_in[1];
    const float* cpe_b = (const float*)d_in[2];
    const float* ln1_w = (const float*)d_in[3];
    const float* ln1_b = (const float*)d_in[4];
    const float* qkv_w = (const float*)d_in[5];
    const float* crpe_w= (const float*)d_in[6];
    const float* crpe_b= (const float*)d_in[7];
    const float* ln2_w = (const float*)d_in[8];
    const float* ln2_b = (const float*)d_in[9];
    const float* fc1_w = (const float*)d_in[10];
    const float* fc1_b = (const float*)d_in[11];
    const float* dw_w  = (const float*)d_in[12];
    const float* dw_b  = (const float*)d_in[13];
    const float* fc2_w = (const float*)d_in[14];
    const float* fc2_b = (const float*)d_in[15];
    float* spine = (float*)d_out;
    char* ws = (char*)d_ws;

    if (ws_size < WS_NEED) {
        diag_k<<<1, 1, 0, stream>>>(spine, (float)ws_size);
        return;
    }

    bf16*  wq   = (bf16*)(ws + OFF_WQ);
    bf16*  w1   = (bf16*)(ws + OFF_W1);
    bf16*  w2r  = (bf16*)(ws + OFF_W2);
    bf16*  cur  = (bf16*)(ws + OFF_CUR);
    bf16*  qkv  = (bf16*)(ws + OFF_QKV);
    bf16*  vc   = (bf16*)(ws + OFF_VC);
    bf16*  ktvT = (bf16*)(ws + OFF_KTV);
    bf16*  hg   = (bf16*)(ws + OFF_HG);
    bf16*  h2   = (bf16*)(ws + OFF_H2);

    // weights -> bf16 (w2 repacked half-major)
    f2bf_k<<<(1536 * 512 / 8 + 255) / 256, 256, 0, stream>>>(qkv_w, wq, 1536 * 512);
    f2bf_k<<<(2048 * 512 / 8 + 255) / 256, 256, 0, stream>>>(fc1_w, w1, 2048 * 512);
    f2bf_w2_k<<<512 * 2048 / 8 / 256, 256, 0, stream>>>(fc2_w, w2r);

    // CPE (fp32, 64-ch groups): spine = x + dwconv(x) + cpe_b
    conv4_k<float, float, true, 1><<<32 * 8 * 4, 256, 0, stream>>>(x, 512, 0, cpe_w, cpe_b, spine, 512, 3);

    const int M = 32768;
    // LN1 (full batch)
    ln_k<<<M / 4, 256, 0, stream>>>(spine, ln1_w, ln1_b, cur);
    // qkv: grid (128,6) = 768 blocks
    gemm8p_k<0, 512><<<dim3(128, 6), 512, 0, stream>>>(cur, wq, nullptr, nullptr, qkv, nullptr, M, 1536);
    // ktv (MFMA, fused denom): 256 blocks
    ktv2_k<<<256, 256, 0, stream>>>(qkv, ktvT);
    // crpe conv on v (512 blocks)
    conv4_k<bf16, bf16, false, 2><<<32 * 4 * 4, 256, 0, stream>>>(qkv, 1536, 1024, crpe_w, crpe_b, vc, 512, 2);
    // attention output (MFMA, 1024 blocks), in place on spine
    attnout2_k<<<32 * 8 * 4, 256, 0, stream>>>(spine, qkv, ktvT, vc);
    // LN2
    ln_k<<<M / 4, 256, 0, stream>>>(spine, ln2_w, ln2_b, cur);

    // MLP in two hidden halves of 1024
    for (int h = 0; h < 2; h++) {
        // fc1-half + gelu: grid (128,4) = 512 blocks
        gemm8p_k<1, 512><<<dim3(128, 4), 512, 0, stream>>>(
            cur, w1 + (size_t)h * 1024 * 512, fc1_b + h * 1024, nullptr, hg, nullptr, M, 1024);
        // hidden dwconv residual on the half (1024 blocks, 128-ch groups)
        conv4_k<bf16, bf16, true, 2><<<32 * 8 * 4, 256, 0, stream>>>(
            hg, 1024, 0, dw_w + (size_t)h * 1024 * 9, dw_b + h * 1024, h2, 1024, 3);
        // fc2-half: K=1024, grid (128,2) = 256 blocks; h0: +bias+resid, h1: accumulate
        if (h == 0)
            gemm8p_k<2, 1024><<<dim3(128, 2), 512, 0, stream>>>(
                h2, w2r, fc2_b, spine, nullptr, spine, M, 512);
        else
            gemm8p_k<3, 1024><<<dim3(128, 2), 512, 0, stream>>>(
                h2, w2r + (size_t)1 * 524288, nullptr, spine, nullptr, spine, M, 512);
    }
}

// Round 15
// 478.341 us; speedup vs baseline: 1.7548x; 1.0670x over previous
//
#include <hip/hip_runtime.h>
#include <hip/hip_bf16.h>

using bf16 = __hip_bfloat16;
using s16x4 = __attribute__((ext_vector_type(4))) short;
using s16x8 = __attribute__((ext_vector_type(8))) short;
using f32x4 = __attribute__((ext_vector_type(4))) float;

#define DI __device__ __forceinline__

template <int N> DI void wvm() {
    if constexpr (N == 8) asm volatile("s_waitcnt vmcnt(8)" ::: "memory");
    else if constexpr (N == 4) asm volatile("s_waitcnt vmcnt(4)" ::: "memory");
    else if constexpr (N == 2) asm volatile("s_waitcnt vmcnt(2)" ::: "memory");
    else asm volatile("s_waitcnt vmcnt(0)" ::: "memory");
}

DI float b2f(short s) { union { unsigned u; float f; } z; z.u = ((unsigned)(unsigned short)s) << 16; return z.f; }
DI short f2b(float f) { bf16 t = __float2bfloat16(f); return *(short*)&t; }

// fast gelu: tanh form, |err| ~1e-3 absolute, far under threshold
DI float gelu_f(float x) {
    const float t = 0.7978845608f * x * (1.f + 0.044715f * x * x);
    const float e = __expf(2.f * t);
    const float th = 1.f - 2.f / (e + 1.f);
    return 0.5f * x * (1.f + th);
}

DI void ld8(const bf16* p, float* f) {
    s16x8 x = *(const s16x8*)(const void*)p;
#pragma unroll
    for (int c = 0; c < 8; c++) f[c] = b2f(x[c]);
}
DI void ld8(const float* p, float* f) {
    float4 a = *(const float4*)p, b = *(const float4*)(p + 4);
    f[0]=a.x; f[1]=a.y; f[2]=a.z; f[3]=a.w; f[4]=b.x; f[5]=b.y; f[6]=b.z; f[7]=b.w;
}

typedef const __attribute__((address_space(1))) void* gp_t;
typedef __attribute__((address_space(3))) void* lp_t;
DI void gload_lds16(const void* g, void* l) {
    __builtin_amdgcn_global_load_lds((gp_t)g, (lp_t)l, 16, 0, 0);
}

// ---------------- diagnostic ----------------
__global__ void diag_k(float* out, float v) { out[0] = v; }

// ---------------- fp32 -> bf16 weight conversion (8/thread) ----------------
__global__ void f2bf_k(const float* __restrict__ in, bf16* __restrict__ out, int n) {
    int i = (blockIdx.x * 256 + threadIdx.x) * 8;
    if (i >= n) return;
    float f[8];
    ld8(in + i, f);
    s16x8 o;
#pragma unroll
    for (int c = 0; c < 8; c++) o[c] = f2b(f[c]);
    *(s16x8*)(void*)(out + i) = o;
}

// ---------------- depthwise 3x3 conv v4 ----------------
DI void tap10(const float* r, float w0, float w1, float w2, float* acc) {
#pragma unroll
    for (int i = 0; i < 8; i++)
        acc[i] += w0 * r[i] + w1 * r[i + 1] + w2 * r[i + 2];
}

template <typename TI, typename TO, bool RESID, int CPL>
__global__ __launch_bounds__(256) void conv4_k(
    const TI* in, long rs, long coff,
    const float* __restrict__ w, const float* __restrict__ bias,
    TO* out, long ors, int gshift)
{
    constexpr int CH = 64 * CPL;
    constexpr int ECNT = CH / 8;
    __shared__ float buf[2][CH][33];
    const int t = threadIdx.x;
    const int band = blockIdx.x & 3;
    const int cg = (blockIdx.x >> 2) & ((1 << gshift) - 1);
    const int img = blockIdx.x >> (2 + gshift);
    const int y0 = band * 8;

    const int spx = t >> 3;
    const int sce = (t & 7) * ECNT;
    const TI* gsrc = in + ((long)img << 10) * rs + coff + (long)cg * CH + sce;

    const int c = t & 63;
    const int xb = (t >> 6) * 8;

    float wv9[9][CPL], bw[CPL];
#pragma unroll
    for (int p = 0; p < CPL; p++) {
        const int gch = cg * CH + c * CPL + p;
#pragma unroll
        for (int j = 0; j < 9; j++) wv9[j][p] = w[gch * 9 + j];
        bw[p] = bias[gch];
    }

    auto stage = [&](int row) {
        float f[ECNT];
        ld8(gsrc + (long)(row * 32 + spx) * rs, f);
        if constexpr (ECNT == 16) ld8(gsrc + (long)(row * 32 + spx) * rs + 8, f + 8);
        float* d = &buf[row & 1][0][0];
#pragma unroll
        for (int k = 0; k < ECNT; k++) {
            const int ch = sce + k;
            const int rr = (CPL == 2) ? ((ch & 1) * 64 + (ch >> 1)) : ch;
            d[rr * 33 + spx] = f[k];
        }
    };
    auto slice = [&](int row, float r[CPL][10]) {
#pragma unroll
        for (int p = 0; p < CPL; p++) {
            const float* s = &buf[row & 1][c + p * 64][0];
            r[p][0] = (xb == 0) ? 0.f : s[xb - 1];
#pragma unroll
            for (int i = 0; i < 8; i++) r[p][1 + i] = s[xb + i];
            r[p][9] = (xb + 8 >= 32) ? 0.f : s[xb + 8];
        }
    };
    auto zero = [&](float r[CPL][10]) {
#pragma unroll
        for (int p = 0; p < CPL; p++)
#pragma unroll
            for (int i = 0; i < 10; i++) r[p][i] = 0.f;
    };

    float r0[CPL][10], r1[CPL][10], r2[CPL][10];
    if (y0 > 0) stage(y0 - 1);
    __syncthreads();
    if (y0 > 0) slice(y0 - 1, r0); else zero(r0);
    stage(y0);
    __syncthreads();
    slice(y0, r1);

    for (int y = y0; y < y0 + 8; ++y) {
        const int yn = y + 1;
        if (yn <= 31) stage(yn);
        __syncthreads();
        if (yn <= 31) slice(yn, r2); else zero(r2);
        float acc[CPL][8];
#pragma unroll
        for (int p = 0; p < CPL; p++) {
#pragma unroll
            for (int i = 0; i < 8; i++) acc[p][i] = bw[p];
            tap10(r0[p], wv9[0][p], wv9[1][p], wv9[2][p], acc[p]);
            tap10(r1[p], wv9[3][p], wv9[4][p], wv9[5][p], acc[p]);
            tap10(r2[p], wv9[6][p], wv9[7][p], wv9[8][p], acc[p]);
            if (RESID) {
#pragma unroll
                for (int i = 0; i < 8; i++) acc[p][i] += r1[p][i + 1];
            }
        }
        TO* o = out + ((long)(img * 1024 + y * 32 + xb)) * ors + (long)cg * CH + c * CPL;
#pragma unroll
        for (int i = 0; i < 8; i++) {
            if constexpr (CPL == 2 && sizeof(TO) == 2) {
                const unsigned u = (unsigned)(unsigned short)f2b(acc[0][i]) |
                                   ((unsigned)(unsigned short)f2b(acc[1][i]) << 16);
                *(unsigned*)(void*)(o + (long)i * ors) = u;
            } else {
                o[(long)i * ors] = (TO)acc[0][i];
            }
        }
#pragma unroll
        for (int p = 0; p < CPL; p++)
#pragma unroll
            for (int i = 0; i < 10; i++) { r0[p][i] = r1[p][i]; r1[p][i] = r2[p][i]; }
    }
}

// ---------------- LayerNorm over C=512, fp32 in -> bf16 out ----------------
__global__ __launch_bounds__(256) void ln_k(const float* __restrict__ x,
                                            const float* __restrict__ w,
                                            const float* __restrict__ bp,
                                            bf16* __restrict__ out)
{
    const size_t row = blockIdx.x * 4 + (threadIdx.x >> 6);
    const int t = threadIdx.x & 63;
    const float* xr = x + row * 512;
    alignas(16) float v[8];
    *(float4*)&v[0] = *(const float4*)(xr + t * 8);
    *(float4*)&v[4] = *(const float4*)(xr + t * 8 + 4);
    float s = 0.f;
#pragma unroll
    for (int j = 0; j < 8; j++) s += v[j];
#pragma unroll
    for (int mm = 32; mm; mm >>= 1) s += __shfl_xor(s, mm);
    const float mu = s * (1.f / 512.f);
    float q = 0.f;
#pragma unroll
    for (int j = 0; j < 8; j++) { v[j] -= mu; q += v[j] * v[j]; }
#pragma unroll
    for (int mm = 32; mm; mm >>= 1) q += __shfl_xor(q, mm);
    const float rstd = rsqrtf(q * (1.f / 512.f) + 1e-6f);
    alignas(16) float wv[8], bv[8];
    *(float4*)&wv[0] = *(const float4*)(w + t * 8);
    *(float4*)&wv[4] = *(const float4*)(w + t * 8 + 4);
    *(float4*)&bv[0] = *(const float4*)(bp + t * 8);
    *(float4*)&bv[4] = *(const float4*)(bp + t * 8 + 4);
    alignas(16) bf16 o[8];
#pragma unroll
    for (int j = 0; j < 8; j++) o[j] = __float2bfloat16(v[j] * rstd * wv[j] + bv[j]);
    *(uint4*)(out + row * 512 + t * 8) = *(const uint4*)o;
}

// ---------------- 8-phase 256x256 bf16 MFMA GEMM -----------------------------
// BK=64, 8 waves 2Mx4N, 128KB LDS. 1D grid = 128*NY blocks, XCD-swizzled so
// blocks sharing an A-panel land on one XCD (L2 reuse). DUAL: A covers K-half
// 0 (lda=K/2), A2 covers K-half 1 (fc2's split hidden buffers).
// EPI 0: bf16. 1: +bias gelu bf16. 2: +bias +resid fp32 (in-place ok).
template <int EPI, int K, int NY, bool DUAL = false>
__global__ __launch_bounds__(512) void gemm8p_k(
    const bf16* __restrict__ A, const bf16* __restrict__ A2,
    const bf16* __restrict__ Bw, const float* __restrict__ bias,
    const float* resid, bf16* __restrict__ outb, float* outf, int M, int Nn)
{
    constexpr int KT = K / 64;
    constexpr int LDA = DUAL ? K / 2 : K;
    __shared__ __align__(16) char lds[131072];
    char* ldsA = lds;
    char* ldsB = lds + 65536;
    const int t = threadIdx.x;
    const int lane = t & 63;
    const int w = t >> 6;
    const int wr = w >> 2, wc = w & 3;
    // XCD swizzle (bijective; gridDim.x = 128*NY, multiple of 8)
    const int nwg = 128 * NY;
    const int swz = (blockIdx.x & 7) * (nwg >> 3) + (blockIdx.x >> 3);
    const int m0 = (swz / NY) * 256;
    const int n0 = (swz % NY) * 256;
    const int lr = lane & 15, lg = lane >> 4;

    f32x4 acc[8][4] = {};

    const int srow = lane >> 3;
    const int ssrc = 8 * ((lane & 7) ^ srow);

    auto SA = [&](int b, int kt, int h) {
        const bf16* Ab = A;
        int ktl = kt;
        if constexpr (DUAL) { if (kt >= KT / 2) { Ab = A2; ktl = kt - KT / 2; } }
#pragma unroll
        for (int j = 0; j < 2; j++) {
            const int lrow0 = j * 64 + w * 8;
            const int R0 = j * 128 + h * 64 + (lrow0 & 63);
            gload_lds16(Ab + (size_t)(m0 + R0 + srow) * LDA + ktl * 64 + ssrc,
                        ldsA + ((b * 2 + h) * 128 + lrow0) * 128);
        }
    };
    auto SB = [&](int b, int kt, int h) {
#pragma unroll
        for (int j = 0; j < 2; j++) {
            const int lrow0 = j * 64 + w * 8;
            const int R0 = (lrow0 >> 5) * 64 + h * 32 + (lrow0 & 31);
            gload_lds16(Bw + (size_t)(n0 + R0 + srow) * K + kt * 64 + ssrc,
                        ldsB + ((b * 2 + h) * 128 + lrow0) * 128);
        }
    };
    auto RA = [&](int b, int h, int m, int ks) -> s16x8 {
        return *(const s16x8*)(ldsA + ((b * 2 + h) * 128 + wr * 64 + m * 16 + lr) * 128
                               + (((ks * 4 + lg) ^ (lr & 7)) << 4));
    };
    auto RB = [&](int b, int h, int n, int ks) -> s16x8 {
        return *(const s16x8*)(ldsB + ((b * 2 + h) * 128 + wc * 32 + n * 16 + lr) * 128
                               + (((ks * 4 + lg) ^ (lr & 7)) << 4));
    };
    auto MM = [&](int mb, int nb, s16x8 (&a)[2][4], s16x8 (&b)[2][2]) {
#pragma unroll
        for (int ks = 0; ks < 2; ks++)
#pragma unroll
            for (int m = 0; m < 4; m++)
#pragma unroll
                for (int n = 0; n < 2; n++)
                    acc[mb + m][nb + n] =
                        __builtin_amdgcn_mfma_f32_16x16x32_bf16(a[ks][m], b[ks][n], acc[mb + m][nb + n], 0, 0, 0);
    };

    SA(0, 0, 0); SB(0, 0, 0); SA(0, 0, 1); SB(0, 0, 1);
    SA(1, 1, 0); SB(1, 1, 0);
    wvm<8>();
    __builtin_amdgcn_s_barrier();

    s16x8 aLo[2][4], aHi[2][4], bLo[2][2], bHi[2][2];
    auto TILE = [&](int kt) {
        const int b = kt & 1;
        // phase 0: (M-lo x N-lo); stage A-hi(kt+1)
#pragma unroll
        for (int ks = 0; ks < 2; ks++) {
#pragma unroll
            for (int m = 0; m < 4; m++) aLo[ks][m] = RA(b, 0, m, ks);
#pragma unroll
            for (int n = 0; n < 2; n++) bLo[ks][n] = RB(b, 0, n, ks);
        }
        if (kt + 1 < KT) SA(b ^ 1, kt + 1, 1);
        __builtin_amdgcn_s_barrier();
        __builtin_amdgcn_s_setprio(1);
        MM(0, 0, aLo, bLo);
        __builtin_amdgcn_s_setprio(0);
        if (kt + 1 < KT) wvm<8>(); else wvm<2>();
        __builtin_amdgcn_s_barrier();
        // phase 1: (M-hi x N-lo); stage B-hi(kt+1)
#pragma unroll
        for (int ks = 0; ks < 2; ks++)
#pragma unroll
            for (int m = 0; m < 4; m++) aHi[ks][m] = RA(b, 1, m, ks);
        if (kt + 1 < KT) SB(b ^ 1, kt + 1, 1);
        __builtin_amdgcn_s_barrier();
        __builtin_amdgcn_s_setprio(1);
        MM(4, 0, aHi, bLo);
        __builtin_amdgcn_s_setprio(0);
        if (kt + 1 < KT) wvm<8>(); else wvm<0>();
        __builtin_amdgcn_s_barrier();
        // phase 2: (M-hi x N-hi); stage A-lo(kt+2)
#pragma unroll
        for (int ks = 0; ks < 2; ks++)
#pragma unroll
            for (int n = 0; n < 2; n++) bHi[ks][n] = RB(b, 1, n, ks);
        if (kt + 2 < KT) SA(b, kt + 2, 0);
        __builtin_amdgcn_s_barrier();
        __builtin_amdgcn_s_setprio(1);
        MM(4, 2, aHi, bHi);
        __builtin_amdgcn_s_setprio(0);
        __builtin_amdgcn_s_barrier();
        // phase 3: (M-lo x N-hi); stage B-lo(kt+2)
        if (kt + 2 < KT) SB(b, kt + 2, 0);
        __builtin_amdgcn_s_barrier();
        __builtin_amdgcn_s_setprio(1);
        MM(0, 2, aLo, bHi);
        __builtin_amdgcn_s_setprio(0);
        if (kt + 2 < KT) { wvm<8>(); __builtin_amdgcn_s_barrier(); }
        else if (kt + 1 < KT) { wvm<4>(); __builtin_amdgcn_s_barrier(); }
    };

    if constexpr (KT <= 8) {
#pragma unroll
        for (int kt = 0; kt < KT; ++kt) TILE(kt);
    } else {
#pragma unroll 2
        for (int kt = 0; kt < KT; ++kt) TILE(kt);
    }

#pragma unroll
    for (int i = 0; i < 8; i++) {
#pragma unroll
        for (int j = 0; j < 4; j++) {
            const int col = n0 + wc * 64 + j * 16 + lr;
            float bcol = 0.f;
            if constexpr (EPI >= 1) bcol = bias[col];
#pragma unroll
            for (int r = 0; r < 4; r++) {
                const int row = m0 + wr * 128 + i * 16 + lg * 4 + r;
                float v = acc[i][j][r] + bcol;
                const size_t idx = (size_t)row * Nn + col;
                if (EPI == 2) outf[idx] = v + resid[idx];
                else outb[idx] = __float2bfloat16(EPI == 1 ? gelu_f(v) : v);
            }
        }
    }
}

// ---------------- ktv v2: MFMA over tokens, fused softmax-denominator -------
__global__ __launch_bounds__(256) void ktv2_k(const bf16* __restrict__ qkv,
                                              bf16* __restrict__ ktvT)
{
    __shared__ __align__(16) char P[64 * 128];
    __shared__ __align__(16) char Vt[64 * 128];
    __shared__ float csl[64 * 5];
    const int t = threadIdx.x;
    const int b = blockIdx.x >> 3, hh = blockIdx.x & 7;
    const int lane = t & 63, w = t >> 6;
    const int lr = lane & 15, lg = lane >> 4;

    const int n_r = t >> 2;
    const int k0 = (t & 3) * 16;
    const bf16* kbase = qkv + (size_t)(b * 1024) * 1536 + 512 + hh * 64 + k0;
    const bf16* vbase = kbase + 512;

    const int kq = t & 63, qq = t >> 6;
    float cacc = 0.f;

    f32x4 acc[4] = {};

    for (int n0 = 0; n0 < 1024; n0 += 64) {
        const uint4 ka = *(const uint4*)(kbase + (size_t)(n0 + n_r) * 1536);
        const uint4 kb2 = *(const uint4*)(kbase + (size_t)(n0 + n_r) * 1536 + 8);
        const uint4 va = *(const uint4*)(vbase + (size_t)(n0 + n_r) * 1536);
        const uint4 vb2 = *(const uint4*)(vbase + (size_t)(n0 + n_r) * 1536 + 8);
        __syncthreads();
        {
            const short* ke = (const short*)&ka;
            const short* ke2 = (const short*)&kb2;
            const short* ve = (const short*)&va;
            const short* ve2 = (const short*)&vb2;
            const int nslot = ((n_r >> 3) << 4);
            const int nbyte = (n_r & 7) * 2;
#pragma unroll
            for (int j = 0; j < 16; j++) {
                const int row = k0 + j;
                const short kv = j < 8 ? ke[j] : ke2[j - 8];
                const short vv = j < 8 ? ve[j] : ve2[j - 8];
                const int off = row * 128 + (nslot ^ ((row & 7) << 4)) + nbyte;
                *(short*)(P + off) = f2b(__expf(b2f(kv)));
                *(short*)(Vt + off) = vv;
            }
        }
        __syncthreads();
        {
            const char* pr = P + kq * 128;
            const int sw = (kq & 7) << 4;
            s16x8 x0 = *(const s16x8*)(pr + (((qq * 2) << 4) ^ sw));
            s16x8 x1 = *(const s16x8*)(pr + (((qq * 2 + 1) << 4) ^ sw));
#pragma unroll
            for (int j = 0; j < 8; j++) cacc += b2f(x0[j]) + b2f(x1[j]);
        }
#pragma unroll
        for (int ks2 = 0; ks2 < 2; ks2++) {
            s16x8 aF = *(const s16x8*)(Vt + (w * 16 + lr) * 128 + (((ks2 * 4 + lg) ^ (lr & 7)) << 4));
            s16x8 bF[4];
#pragma unroll
            for (int j = 0; j < 4; j++)
                bF[j] = *(const s16x8*)(P + (j * 16 + lr) * 128 + (((ks2 * 4 + lg) ^ (lr & 7)) << 4));
#pragma unroll
            for (int j = 0; j < 4; j++)
                acc[j] = __builtin_amdgcn_mfma_f32_16x16x32_bf16(aF, bF[j], acc[j], 0, 0, 0);
        }
    }
    __syncthreads();
    csl[kq * 5 + qq] = cacc;
    __syncthreads();
    if (t < 64) csl[t * 5 + 4] = csl[t * 5] + csl[t * 5 + 1] + csl[t * 5 + 2] + csl[t * 5 + 3];
    __syncthreads();

    bf16* o = ktvT + (size_t)(b * 8 + hh) * 4096;
#pragma unroll
    for (int j = 0; j < 4; j++) {
        const int col = j * 16 + lr;
        const float sc = 0.125f / csl[col * 5 + 4];
#pragma unroll
        for (int r = 0; r < 4; r++) {
            const int vrow = w * 16 + lg * 4 + r;
            o[vrow * 64 + col] = __float2bfloat16(acc[j][r] * sc);
        }
    }
}

// ---------------- attnout v2: MFMA q@ktvT + fused crpe + residual -----------
__global__ __launch_bounds__(256) void attnout2_k(
    float* xs, const bf16* __restrict__ qkv,
    const bf16* __restrict__ ktvT, const bf16* __restrict__ vc)
{
    __shared__ __align__(16) char qs[256 * 128];
    __shared__ __align__(16) char ks[64 * 128];
    const int t = threadIdx.x;
    const int bid = blockIdx.x;
    const int b = bid >> 5, hh = (bid >> 2) & 7, nc = bid & 3;
    const int n0 = nc * 256;
    const int lane = t & 63, w = t >> 6;
    const int lr = lane & 15, lg = lane >> 4;

    {
        const int r0 = t >> 3, sl = t & 7;
#pragma unroll
        for (int it = 0; it < 8; it++) {
            const int row = it * 32 + r0;
            const uint4 v = *(const uint4*)(qkv + ((size_t)(b * 1024 + n0 + row)) * 1536 + hh * 64 + sl * 8);
            *(uint4*)(qs + row * 128 + ((sl ^ (row & 7)) << 4)) = v;
        }
#pragma unroll
        for (int it = 0; it < 2; it++) {
            const int u = it * 256 + t;
            const int vr = u >> 3, sl2 = u & 7;
            const uint4 vv = *(const uint4*)(ktvT + (size_t)(b * 8 + hh) * 4096 + vr * 64 + sl2 * 8);
            *(uint4*)(ks + vr * 128 + ((sl2 ^ (vr & 7)) << 4)) = vv;
        }
    }
    __syncthreads();

    f32x4 acc[4][4] = {};
    s16x8 aF[2][4], bF[2][4];
#pragma unroll
    for (int ksi = 0; ksi < 2; ksi++) {
#pragma unroll
        for (int m = 0; m < 4; m++) {
            const int row = w * 64 + m * 16 + lr;
            aF[ksi][m] = *(const s16x8*)(qs + row * 128 + (((ksi * 4 + lg) ^ (lr & 7)) << 4));
        }
#pragma unroll
        for (int j = 0; j < 4; j++) {
            const int vr = j * 16 + lr;
            bF[ksi][j] = *(const s16x8*)(ks + vr * 128 + (((ksi * 4 + lg) ^ (lr & 7)) << 4));
        }
    }
#pragma unroll
    for (int ksi = 0; ksi < 2; ksi++)
#pragma unroll
        for (int m = 0; m < 4; m++)
#pragma unroll
            for (int j = 0; j < 4; j++)
                acc[m][j] = __builtin_amdgcn_mfma_f32_16x16x32_bf16(aF[ksi][m], bF[ksi][j], acc[m][j], 0, 0, 0);

#pragma unroll
    for (int m = 0; m < 4; m++) {
#pragma unroll
        for (int j = 0; j < 4; j++) {
#pragma unroll
            for (int r = 0; r < 4; r++) {
                const int lrow = w * 64 + m * 16 + lg * 4 + r;
                const int col = j * 16 + lr;
                const size_t idx = ((size_t)(b * 1024 + n0 + lrow)) * 512 + hh * 64 + col;
                const short qv = *(const short*)(qs + lrow * 128 + ((((col >> 3) ^ (lrow & 7)) << 4)) + (col & 7) * 2);
                xs[idx] = xs[idx] + acc[m][j][r] + b2f(qv) * __bfloat162float(vc[idx]);
            }
        }
    }
}

// ---------------- workspace layout (bytes), full-batch ----------------------
// weights 0..5.77MB | cur 5.77..39.3 (inside h2b 5.77..72.9, cur dies first)
// qkv 72.9..173.5 | vc 173.5..207.1 | ktvT 207.1..207.6
// MLP: hg 72.9..140.0 (over dead qkv head), h2a 140.0..207.1 (over qkv tail+vc)
static constexpr size_t OFF_WQ   = 0;
static constexpr size_t OFF_W1   = 1572864;
static constexpr size_t OFF_W2   = 3670016;
static constexpr size_t OFF_CUR  = 5767168;
static constexpr size_t OFF_H2B  = 5767168;
static constexpr size_t OFF_QKV  = 72876032;
static constexpr size_t OFF_HG   = 72876032;
static constexpr size_t OFF_VC   = 173539328;
static constexpr size_t OFF_H2A  = 139984896;
static constexpr size_t OFF_KTV  = 207093760;
static constexpr size_t WS_NEED  = 207618048;   // ~198MB (ws >= 215.5MB confirmed)

extern "C" void kernel_launch(void* const* d_in, const int* in_sizes, int n_in,
                              void* d_out, int out_size, void* d_ws, size_t ws_size,
                              hipStream_t stream)
{
    const float* x     = (const float*)d_in[0];
    const float* cpe_w = (const float*)d_in[1];
    const float* cpe_b = (const float*)d_in[2];
    const float* ln1_w = (const float*)d_in[3];
    const float* ln1_b = (const float*)d_in[4];
    const float* qkv_w = (const float*)d_in[5];
    const float* crpe_w= (const float*)d_in[6];
    const float* crpe_b= (const float*)d_in[7];
    const float* ln2_w = (const float*)d_in[8];
    const float* ln2_b = (const float*)d_in[9];
    const float* fc1_w = (const float*)d_in[10];
    const float* fc1_b = (const float*)d_in[11];
    const float* dw_w  = (const float*)d_in[12];
    const float* dw_b  = (const float*)d_in[13];
    const float* fc2_w = (const float*)d_in[14];
    const float* fc2_b = (const float*)d_in[15];
    float* spine = (float*)d_out;
    char* ws = (char*)d_ws;

    if (ws_size < WS_NEED) {
        diag_k<<<1, 1, 0, stream>>>(spine, (float)ws_size);
        return;
    }

    bf16*  wq   = (bf16*)(ws + OFF_WQ);
    bf16*  w1   = (bf16*)(ws + OFF_W1);
    bf16*  w2b  = (bf16*)(ws + OFF_W2);
    bf16*  cur  = (bf16*)(ws + OFF_CUR);
    bf16*  qkv  = (bf16*)(ws + OFF_QKV);
    bf16*  vc   = (bf16*)(ws + OFF_VC);
    bf16*  ktvT = (bf16*)(ws + OFF_KTV);
    bf16*  hg   = (bf16*)(ws + OFF_HG);
    bf16*  h2a  = (bf16*)(ws + OFF_H2A);
    bf16*  h2b  = (bf16*)(ws + OFF_H2B);

    // weights -> bf16 (w2 native [512][2048] layout works for dual-A fc2)
    f2bf_k<<<(1536 * 512 / 8 + 255) / 256, 256, 0, stream>>>(qkv_w, wq, 1536 * 512);
    f2bf_k<<<(2048 * 512 / 8 + 255) / 256, 256, 0, stream>>>(fc1_w, w1, 2048 * 512);
    f2bf_k<<<(2048 * 512 / 8 + 255) / 256, 256, 0, stream>>>(fc2_w, w2b, 512 * 2048);

    // CPE (fp32, 64-ch groups): spine = x + dwconv(x) + cpe_b
    conv4_k<float, float, true, 1><<<32 * 8 * 4, 256, 0, stream>>>(x, 512, 0, cpe_w, cpe_b, spine, 512, 3);

    const int M = 32768;
    // LN1
    ln_k<<<M / 4, 256, 0, stream>>>(spine, ln1_w, ln1_b, cur);
    // qkv: 768 blocks (XCD-swizzled)
    gemm8p_k<0, 512, 6><<<768, 512, 0, stream>>>(cur, nullptr, wq, nullptr, nullptr, qkv, nullptr, M, 1536);
    // ktv (MFMA, fused denom): 256 blocks
    ktv2_k<<<256, 256, 0, stream>>>(qkv, ktvT);
    // crpe conv on v
    conv4_k<bf16, bf16, false, 2><<<32 * 4 * 4, 256, 0, stream>>>(qkv, 1536, 1024, crpe_w, crpe_b, vc, 512, 2);
    // attention output (MFMA), in place on spine
    attnout2_k<<<32 * 8 * 4, 256, 0, stream>>>(spine, qkv, ktvT, vc);
    // LN2
    ln_k<<<M / 4, 256, 0, stream>>>(spine, ln2_w, ln2_b, cur);

    // MLP: fc1(h0)->conv(h0)->fc1(h1)->conv(h1)->fc2(dual, single pass)
    gemm8p_k<1, 512, 4><<<512, 512, 0, stream>>>(cur, nullptr, w1, fc1_b, nullptr, hg, nullptr, M, 1024);
    conv4_k<bf16, bf16, true, 2><<<32 * 8 * 4, 256, 0, stream>>>(hg, 1024, 0, dw_w, dw_b, h2a, 1024, 3);
    gemm8p_k<1, 512, 4><<<512, 512, 0, stream>>>(cur, nullptr, w1 + (size_t)1024 * 512, fc1_b + 1024, nullptr, hg, nullptr, M, 1024);
    conv4_k<bf16, bf16, true, 2><<<32 * 8 * 4, 256, 0, stream>>>(hg, 1024, 0, dw_w + (size_t)1024 * 9, dw_b + 1024, h2b, 1024, 3);
    // fc2: K=2048 dual-A, 256 blocks; +bias +resid fp32 in place
    gemm8p_k<2, 2048, 2, true><<<256, 512, 0, stream>>>(h2a, h2b, w2b, fc2_b, spine, nullptr, spine, M, 512);
}